// Round 1
// baseline (1300.339 us; speedup 1.0000x reference)
//
#include <hip/hip_runtime.h>

#define SLOPE 0.2f
#define BN_EPS 1e-5f

__device__ __forceinline__ float wave_sum(float v){
  #pragma unroll
  for(int o=32;o;o>>=1) v += __shfl_xor(v,o);
  return v;
}
__device__ __forceinline__ float wave_max(float v){
  #pragma unroll
  for(int o=32;o;o>>=1) v = fmaxf(v,__shfl_xor(v,o));
  return v;
}

// ---------------- GEMM: A[n,K] @ W[K,128] -> out[n,128]  (fp32 vector)
__global__ __launch_bounds__(256) void gemm128(const float* __restrict__ A,
    const float* __restrict__ W, float* __restrict__ out, int n, int K){
  __shared__ float sA[64][33];
  __shared__ float sB[32][128];
  int t = threadIdx.x;
  int tx = t & 15, ty = t >> 4;
  int row0 = blockIdx.x * 64;
  float acc[4][8] = {};
  for(int k0 = 0; k0 < K; k0 += 32){
    for(int i = t; i < 64*32; i += 256){
      int r = i >> 5, kk = i & 31;
      int gr = row0 + r;
      sA[r][kk] = (gr < n) ? A[(size_t)gr*K + k0 + kk] : 0.f;
    }
    for(int i = t; i < 32*128; i += 256){
      int kk = i >> 7, c = i & 127;
      sB[kk][c] = W[(size_t)(k0+kk)*128 + c];
    }
    __syncthreads();
    #pragma unroll
    for(int kk = 0; kk < 32; ++kk){
      float a[4], b[8];
      #pragma unroll
      for(int i=0;i<4;i++) a[i] = sA[ty*4+i][kk];
      #pragma unroll
      for(int j=0;j<8;j++) b[j] = sB[kk][tx*8+j];
      #pragma unroll
      for(int i=0;i<4;i++)
        #pragma unroll
        for(int j=0;j<8;j++) acc[i][j] += a[i]*b[j];
    }
    __syncthreads();
  }
  for(int i=0;i<4;i++){
    int gr = row0 + ty*4 + i;
    if(gr < n)
      for(int j=0;j<8;j++) out[(size_t)gr*128 + tx*8 + j] = acc[i][j];
  }
}

// ---------------- per-node attention terms el/er  (wave per node)
__global__ __launch_bounds__(256) void elr_kernel(const float* __restrict__ feat,
    const float* __restrict__ al, const float* __restrict__ ar,
    float* __restrict__ el, float* __restrict__ er, int n){
  int wid = (blockIdx.x*blockDim.x + threadIdx.x) >> 6;
  int lane = threadIdx.x & 63;
  if(wid >= n) return;
  const float* f = feat + (size_t)wid*128;
  float f0 = f[lane], f1 = f[64+lane];
  float p0 = f0*al[lane], p1 = f1*al[64+lane];
  float q0 = f0*ar[lane], q1 = f1*ar[64+lane];
  p0 = wave_sum(p0); p1 = wave_sum(p1);
  q0 = wave_sum(q0); q1 = wave_sum(q1);
  if(lane == 0){
    el[(size_t)wid*2] = p0; el[(size_t)wid*2+1] = p1;
    er[(size_t)wid*2] = q0; er[(size_t)wid*2+1] = q1;
  }
}

// ---------------- CSR build
__global__ void hist_kernel(const int* __restrict__ dst, int* __restrict__ deg, int E){
  int e = blockIdx.x*blockDim.x + threadIdx.x;
  if(e < E) atomicAdd(&deg[dst[e]], 1);
}

__global__ __launch_bounds__(256) void scan1(const int* __restrict__ deg,
    int* __restrict__ rowptr, int* __restrict__ bsum, int n){
  __shared__ int ls[256];
  int t = threadIdx.x;
  int base = blockIdx.x*1024 + t*4;
  int v0 = (base+0<n)? deg[base+0]:0;
  int v1 = (base+1<n)? deg[base+1]:0;
  int v2 = (base+2<n)? deg[base+2]:0;
  int v3 = (base+3<n)? deg[base+3]:0;
  int c0=v0, c1=c0+v1, c2=c1+v2, c3=c2+v3;
  ls[t]=c3; __syncthreads();
  for(int off=1; off<256; off<<=1){
    int x = (t>=off)? ls[t-off] : 0;
    __syncthreads();
    ls[t] += x;
    __syncthreads();
  }
  int prefix = ls[t] - c3;
  if(base+0<n) rowptr[base+1] = prefix + c0;
  if(base+1<n) rowptr[base+2] = prefix + c1;
  if(base+2<n) rowptr[base+3] = prefix + c2;
  if(base+3<n) rowptr[base+4] = prefix + c3;
  if(t == 255) bsum[blockIdx.x] = ls[255];
}

__global__ __launch_bounds__(128) void scan2(int* __restrict__ bsum, int nb){
  __shared__ int ls[128];
  int t = threadIdx.x;
  int v = (t<nb)? bsum[t] : 0;
  ls[t]=v; __syncthreads();
  for(int off=1; off<128; off<<=1){
    int x = (t>=off)? ls[t-off] : 0;
    __syncthreads();
    ls[t] += x;
    __syncthreads();
  }
  if(t<nb) bsum[t] = ls[t] - v;  // exclusive block offsets
}

__global__ void scan3(int* __restrict__ rowptr, const int* __restrict__ bsum, int n){
  int i = blockIdx.x*blockDim.x + threadIdx.x;
  if(i < n) rowptr[i+1] += bsum[i>>10];
  if(i == 0) rowptr[0] = 0;
}

__global__ void copy_cur(const int* __restrict__ rowptr, int* __restrict__ cur, int n){
  int i = blockIdx.x*blockDim.x + threadIdx.x;
  if(i < n) cur[i] = rowptr[i];
}

__global__ void scatter_kernel(const int* __restrict__ src, const int* __restrict__ dst,
    int* __restrict__ cur, int* __restrict__ esrc, int E){
  int e = blockIdx.x*blockDim.x + threadIdx.x;
  if(e < E){
    int pos = atomicAdd(&cur[dst[e]], 1);
    esrc[pos] = src[e];
  }
}

// ---------------- GAT aggregation: wave per dst node
__global__ __launch_bounds__(256) void agg_kernel(const float* __restrict__ feat,
    const float* __restrict__ el, const float* __restrict__ er,
    const int* __restrict__ rowptr, const int* __restrict__ esrc,
    const float* __restrict__ bias, float* __restrict__ out, int n){
  int wid = (blockIdx.x*blockDim.x + threadIdx.x) >> 6;
  int lane = threadIdx.x & 63;
  if(wid >= n) return;
  int beg = rowptr[wid], end = rowptr[wid+1];
  float er0 = er[(size_t)wid*2], er1 = er[(size_t)wid*2+1];
  // phase 1: denominators (edge-parallel across lanes)
  float d0 = 0.f, d1 = 0.f;
  for(int base = beg; base < end; base += 64){
    int idx = base + lane;
    if(idx < end){
      int s = esrc[idx];
      float e0 = el[(size_t)s*2]   + er0;
      float e1 = el[(size_t)s*2+1] + er1;
      e0 = (e0 >= 0.f) ? e0 : SLOPE*e0;
      e1 = (e1 >= 0.f) ? e1 : SLOPE*e1;
      d0 += __expf(e0) * 0.f + expf(e0);   // keep plain expf (precision)
      d1 += expf(e1);
    }
  }
  d0 = wave_sum(d0); d1 = wave_sum(d1);
  float inv0 = 1.0f / fmaxf(d0, 1e-16f);
  float inv1 = 1.0f / fmaxf(d1, 1e-16f);
  // phase 2: weighted message accumulation (lane = feature dim)
  float a0 = 0.f, a1 = 0.f;
  for(int idx = beg; idx < end; ++idx){
    int s = esrc[idx];
    float e0 = el[(size_t)s*2]   + er0;
    float e1 = el[(size_t)s*2+1] + er1;
    e0 = (e0 >= 0.f) ? e0 : SLOPE*e0;
    e1 = (e1 >= 0.f) ? e1 : SLOPE*e1;
    float w0 = expf(e0) * inv0;
    float w1 = expf(e1) * inv1;
    const float* fs = feat + (size_t)s*128;
    a0 += fs[lane]      * w0;
    a1 += fs[64+lane]   * w1;
  }
  out[(size_t)wid*128 + lane]      = fmaxf(a0 + bias[lane],      0.f);
  out[(size_t)wid*128 + 64 + lane] = fmaxf(a1 + bias[64+lane],   0.f);
}

// ---------------- head: relu(h@Wout+bout) @ Wfc + bfc   (4 rows per block)
__global__ __launch_bounds__(256) void head_kernel(const float* __restrict__ h,
    const float* __restrict__ Wout, const float* __restrict__ bout,
    const float* __restrict__ Wfc, const float* __restrict__ bfc,
    float* __restrict__ hfc, int n){
  __shared__ float sW[128*64];
  __shared__ float sF[64*64];
  __shared__ float sR[4][128];
  __shared__ float sO[4][64];
  int t = threadIdx.x;
  for(int i=t; i<128*64; i+=256) sW[i] = Wout[i];
  for(int i=t; i<64*64;  i+=256) sF[i] = Wfc[i];
  int r0 = blockIdx.x*4;
  for(int i=t; i<4*128; i+=256){
    int r = i>>7, c = i&127;
    sR[r][c] = (r0+r < n) ? h[(size_t)(r0+r)*128 + c] : 0.f;
  }
  __syncthreads();
  int lr = t>>6, c = t&63;
  float acc = bout[c];
  #pragma unroll 8
  for(int k=0;k<128;k++) acc += sR[lr][k]*sW[k*64+c];
  sO[lr][c] = fmaxf(acc, 0.f);
  __syncthreads();
  float acc2 = bfc[c];
  #pragma unroll 8
  for(int k=0;k<64;k++) acc2 += sO[lr][k]*sF[k*64+c];
  if(r0+lr < n) hfc[(size_t)(r0+lr)*64 + c] = acc2;
}

// ---------------- BN stats (two-stage, deterministic)
__global__ __launch_bounds__(256) void bn_stats(const float* __restrict__ hfc,
    float* __restrict__ psum, float* __restrict__ psum2, int n){
  int t = threadIdx.x; int c = t & 63; int g = t >> 6;
  int rpb = (n + gridDim.x - 1) / gridDim.x;
  int r0 = blockIdx.x * rpb;
  int r1 = min(n, r0 + rpb);
  float s = 0.f, s2 = 0.f;
  for(int r = r0 + g; r < r1; r += 4){
    float v = hfc[(size_t)r*64 + c];
    s += v; s2 += v*v;
  }
  __shared__ float ls[256], ls2[256];
  ls[t]=s; ls2[t]=s2; __syncthreads();
  if(t < 64){
    s  = ls[t]+ls[t+64]+ls[t+128]+ls[t+192];
    s2 = ls2[t]+ls2[t+64]+ls2[t+128]+ls2[t+192];
    psum[blockIdx.x*64 + t]  = s;
    psum2[blockIdx.x*64 + t] = s2;
  }
}

__global__ __launch_bounds__(64) void bn_fin(const float* __restrict__ psum,
    const float* __restrict__ psum2, const float* __restrict__ gamma,
    const float* __restrict__ beta, float* __restrict__ scsh, int n, int nb){
  int c = threadIdx.x;
  float s=0.f, s2=0.f;
  for(int b=0;b<nb;b++){ s += psum[b*64+c]; s2 += psum2[b*64+c]; }
  float mu  = s / n;
  float var = s2 / n - mu*mu;
  float scale = rsqrtf(var + BN_EPS) * gamma[c];
  scsh[c]    = scale;
  scsh[64+c] = beta[c] - mu*scale;
}

// ---------------- BN apply + row softmax -> p
__global__ __launch_bounds__(256) void bn_softmax(const float* __restrict__ hfc,
    const float* __restrict__ scsh, float* __restrict__ p, int n){
  int wid = (blockIdx.x*blockDim.x + threadIdx.x) >> 6;
  int lane = threadIdx.x & 63;
  if(wid >= n) return;
  float y = hfc[(size_t)wid*64 + lane]*scsh[lane] + scsh[64+lane];
  float m = wave_max(y);
  float e = expf(y - m);
  float s = wave_sum(e);
  p[(size_t)wid*64 + lane] = e / s;
}

// ---------------- loss
__global__ __launch_bounds__(256) void loss1(const float* __restrict__ p,
    const int* __restrict__ train, const int* __restrict__ label,
    float* __restrict__ part, int ntrain){
  int lane = threadIdx.x & 63; int w = threadIdx.x >> 6;
  int gw = blockIdx.x*4 + w; int nw = gridDim.x*4;
  float acc = 0.f;
  for(int t = gw; t < ntrain; t += nw){
    int node = train[t];
    float v = p[(size_t)node*64 + lane];
    float m = wave_max(v);
    float e = expf(v - m);
    float s = wave_sum(e);
    float logp = (v - m) - logf(s);
    int lab = label[node];
    if(lane == lab) acc += logp;
  }
  acc = wave_sum(acc);
  __shared__ float ls[4];
  if(lane == 0) ls[w] = acc;
  __syncthreads();
  if(threadIdx.x == 0) part[blockIdx.x] = ls[0]+ls[1]+ls[2]+ls[3];
}

__global__ void loss2(const float* __restrict__ part, float* __restrict__ out,
                      int nb, int ntrain){
  if(threadIdx.x == 0){
    float s = 0.f;
    for(int i=0;i<nb;i++) s += part[i];
    out[0] = -s / (float)ntrain;
  }
}

extern "C" void kernel_launch(void* const* d_in, const int* in_sizes, int n_in,
                              void* d_out, int out_size, void* d_ws, size_t ws_size,
                              hipStream_t stream){
  const float* feature = (const float*)d_in[0];
  const int*   label   = (const int*)d_in[1];
  const int*   train   = (const int*)d_in[2];
  const int*   src     = (const int*)d_in[3];
  const int*   dst     = (const int*)d_in[4];
  const float* W0   = (const float*)d_in[5];
  const float* al0  = (const float*)d_in[6];
  const float* ar0  = (const float*)d_in[7];
  const float* b0   = (const float*)d_in[8];
  const float* W1   = (const float*)d_in[9];
  const float* al1  = (const float*)d_in[10];
  const float* ar1  = (const float*)d_in[11];
  const float* b1   = (const float*)d_in[12];
  const float* Wout = (const float*)d_in[13];
  const float* bout = (const float*)d_in[14];
  const float* Wfc  = (const float*)d_in[15];
  const float* bfc  = (const float*)d_in[16];
  const float* gamma= (const float*)d_in[17];
  const float* beta = (const float*)d_in[18];

  const int N  = in_sizes[1];
  const int NT = in_sizes[2];
  const int E  = in_sizes[3];

  // workspace carve-up
  size_t off = 0;
  auto alloc = [&](size_t bytes)->void*{
    void* pp = (char*)d_ws + off;
    off += (bytes + 255) & ~(size_t)255;
    return pp;
  };
  float* featbuf = (float*)alloc((size_t)N*128*4);   // feat (layer in use)
  float* hbuf    = (float*)alloc((size_t)N*128*4);   // layer output
  float* el      = (float*)alloc((size_t)N*2*4);
  float* er      = (float*)alloc((size_t)N*2*4);
  int*   deg     = (int*)alloc((size_t)N*4);
  int*   rowptr  = (int*)alloc((size_t)(N+1)*4);
  int*   cur     = (int*)alloc((size_t)N*4);
  int*   esrc    = (int*)alloc((size_t)E*4);
  int*   bsum    = (int*)alloc(512*4);
  float* psum    = (float*)alloc((size_t)256*64*4);
  float* psum2   = (float*)alloc((size_t)256*64*4);
  float* scsh    = (float*)alloc(128*4);
  float* lpart   = (float*)alloc(256*4);
  float* hfc     = featbuf;  // reuse (N*64 <= N*128) after feat no longer needed

  float* p_out   = (float*)d_out;
  float* loss_out= (float*)d_out + (size_t)N*64;

  const int nwaveblk = (N + 3) / 4;          // wave-per-node kernels
  const int egrid    = (E + 255) / 256;
  const int nb1      = (N + 1023) / 1024;    // scan blocks (<=128)

  // ---- CSR build (per call; graph is static but no cross-call caching allowed)
  hipMemsetAsync(deg, 0, (size_t)N*4, stream);
  hist_kernel<<<egrid, 256, 0, stream>>>(dst, deg, E);
  scan1<<<nb1, 256, 0, stream>>>(deg, rowptr, bsum, N);
  scan2<<<1, 128, 0, stream>>>(bsum, nb1);
  scan3<<<(N+255)/256, 256, 0, stream>>>(rowptr, bsum, N);
  copy_cur<<<(N+255)/256, 256, 0, stream>>>(rowptr, cur, N);
  scatter_kernel<<<egrid, 256, 0, stream>>>(src, dst, cur, esrc, E);

  // ---- layer 0
  gemm128<<<(N+63)/64, 256, 0, stream>>>(feature, W0, featbuf, N, 256);
  elr_kernel<<<nwaveblk, 256, 0, stream>>>(featbuf, al0, ar0, el, er, N);
  agg_kernel<<<nwaveblk, 256, 0, stream>>>(featbuf, el, er, rowptr, esrc, b0, hbuf, N);

  // ---- layer 1
  gemm128<<<(N+63)/64, 256, 0, stream>>>(hbuf, W1, featbuf, N, 128);
  elr_kernel<<<nwaveblk, 256, 0, stream>>>(featbuf, al1, ar1, el, er, N);
  agg_kernel<<<nwaveblk, 256, 0, stream>>>(featbuf, el, er, rowptr, esrc, b1, hbuf, N);

  // ---- dense head
  head_kernel<<<(N+3)/4, 256, 0, stream>>>(hbuf, Wout, bout, Wfc, bfc, hfc, N);

  // ---- batchnorm (training-mode batch stats)
  bn_stats<<<256, 256, 0, stream>>>(hfc, psum, psum2, N);
  bn_fin<<<1, 64, 0, stream>>>(psum, psum2, gamma, beta, scsh, N, 256);
  bn_softmax<<<nwaveblk, 256, 0, stream>>>(hfc, scsh, p_out, N);

  // ---- loss
  loss1<<<40, 256, 0, stream>>>(p_out, train, label, lpart, NT);
  loss2<<<1, 64, 0, stream>>>(lpart, loss_out, 40, NT);
}

// Round 2
// 1121.788 us; speedup vs baseline: 1.1592x; 1.1592x over previous
//
#include <hip/hip_runtime.h>

#define SLOPE 0.2f
#define BN_EPS 1e-5f

__device__ __forceinline__ float wave_sum(float v){
  #pragma unroll
  for(int o=32;o;o>>=1) v += __shfl_xor(v,o);
  return v;
}
__device__ __forceinline__ float wave_max(float v){
  #pragma unroll
  for(int o=32;o;o>>=1) v = fmaxf(v,__shfl_xor(v,o));
  return v;
}

// ---------------- GEMM: A[n,K] @ W[K,128] -> out[n,128]  (fp32 vector, conflict-free LDS)
// 128x128 block tile, 8x8 per-thread micro-tile, A transposed in LDS.
__global__ __launch_bounds__(256) void gemm128(const float* __restrict__ A,
    const float* __restrict__ W, float* __restrict__ out, int n, int K){
  __shared__ float sAT[32][132];   // sAT[k][r]  (132 pad: staging writes spread banks)
  __shared__ float sB [32][132];   // sB[k][c]
  int t = threadIdx.x;
  int cx = t & 15;                 // col group: cols cx*8 .. cx*8+7
  int ry = t >> 4;                 // row group: rows ry*8 .. ry*8+7
  int row0 = blockIdx.x * 128;

  // staging coords
  int ar = t >> 1;                 // A row 0..127
  int akc = (t & 1) * 16;          // A k-offset within tile
  int bkr = t >> 3;                // B k 0..31
  int bc0 = (t & 7) * 16;          // B col offset

  float acc[8][8] = {};

  for(int k0 = 0; k0 < K; k0 += 32){
    // stage A tile (128 rows x 32 k), transposed into sAT
    {
      int gr = row0 + ar;
      const float* ap = A + (size_t)gr*K + k0 + akc;
      #pragma unroll
      for(int i=0;i<4;i++){
        float4 v = make_float4(0.f,0.f,0.f,0.f);
        if(gr < n) v = *(const float4*)(ap + i*4);
        sAT[akc+i*4+0][ar] = v.x;
        sAT[akc+i*4+1][ar] = v.y;
        sAT[akc+i*4+2][ar] = v.z;
        sAT[akc+i*4+3][ar] = v.w;
      }
    }
    // stage B tile (32 k x 128 cols)
    {
      const float* wp = W + (size_t)(k0+bkr)*128 + bc0;
      #pragma unroll
      for(int i=0;i<4;i++){
        *(float4*)&sB[bkr][bc0+i*4] = *(const float4*)(wp + i*4);
      }
    }
    __syncthreads();
    #pragma unroll 8
    for(int kk = 0; kk < 32; ++kk){
      float4 a0 = *(const float4*)&sAT[kk][ry*8];
      float4 a1 = *(const float4*)&sAT[kk][ry*8+4];
      float4 b0 = *(const float4*)&sB [kk][cx*8];
      float4 b1 = *(const float4*)&sB [kk][cx*8+4];
      float a[8] = {a0.x,a0.y,a0.z,a0.w,a1.x,a1.y,a1.z,a1.w};
      float b[8] = {b0.x,b0.y,b0.z,b0.w,b1.x,b1.y,b1.z,b1.w};
      #pragma unroll
      for(int i=0;i<8;i++)
        #pragma unroll
        for(int j=0;j<8;j++) acc[i][j] += a[i]*b[j];
    }
    __syncthreads();
  }
  // write out: 8 rows x 8 cols per thread, float4 stores
  #pragma unroll
  for(int i=0;i<8;i++){
    int gr = row0 + ry*8 + i;
    if(gr < n){
      float4 o0 = make_float4(acc[i][0],acc[i][1],acc[i][2],acc[i][3]);
      float4 o1 = make_float4(acc[i][4],acc[i][5],acc[i][6],acc[i][7]);
      *(float4*)&out[(size_t)gr*128 + cx*8]     = o0;
      *(float4*)&out[(size_t)gr*128 + cx*8 + 4] = o1;
    }
  }
}

// ---------------- per-node attention terms el/er  (wave per node)
__global__ __launch_bounds__(256) void elr_kernel(const float* __restrict__ feat,
    const float* __restrict__ al, const float* __restrict__ ar,
    float* __restrict__ el, float* __restrict__ er, int n){
  int wid = (blockIdx.x*blockDim.x + threadIdx.x) >> 6;
  int lane = threadIdx.x & 63;
  if(wid >= n) return;
  const float* f = feat + (size_t)wid*128;
  float f0 = f[lane], f1 = f[64+lane];
  float p0 = f0*al[lane], p1 = f1*al[64+lane];
  float q0 = f0*ar[lane], q1 = f1*ar[64+lane];
  p0 = wave_sum(p0); p1 = wave_sum(p1);
  q0 = wave_sum(q0); q1 = wave_sum(q1);
  if(lane == 0){
    el[(size_t)wid*2] = p0; el[(size_t)wid*2+1] = p1;
    er[(size_t)wid*2] = q0; er[(size_t)wid*2+1] = q1;
  }
}

// ---------------- CSR build
__global__ void hist_kernel(const int* __restrict__ dst, int* __restrict__ deg, int E){
  int e = blockIdx.x*blockDim.x + threadIdx.x;
  if(e < E) atomicAdd(&deg[dst[e]], 1);
}

__global__ __launch_bounds__(256) void scan1(const int* __restrict__ deg,
    int* __restrict__ rowptr, int* __restrict__ bsum, int n){
  __shared__ int ls[256];
  int t = threadIdx.x;
  int base = blockIdx.x*1024 + t*4;
  int v0 = (base+0<n)? deg[base+0]:0;
  int v1 = (base+1<n)? deg[base+1]:0;
  int v2 = (base+2<n)? deg[base+2]:0;
  int v3 = (base+3<n)? deg[base+3]:0;
  int c0=v0, c1=c0+v1, c2=c1+v2, c3=c2+v3;
  ls[t]=c3; __syncthreads();
  for(int off=1; off<256; off<<=1){
    int x = (t>=off)? ls[t-off] : 0;
    __syncthreads();
    ls[t] += x;
    __syncthreads();
  }
  int prefix = ls[t] - c3;
  if(base+0<n) rowptr[base+1] = prefix + c0;
  if(base+1<n) rowptr[base+2] = prefix + c1;
  if(base+2<n) rowptr[base+3] = prefix + c2;
  if(base+3<n) rowptr[base+4] = prefix + c3;
  if(t == 255) bsum[blockIdx.x] = ls[255];
}

__global__ __launch_bounds__(128) void scan2(int* __restrict__ bsum, int nb){
  __shared__ int ls[128];
  int t = threadIdx.x;
  int v = (t<nb)? bsum[t] : 0;
  ls[t]=v; __syncthreads();
  for(int off=1; off<128; off<<=1){
    int x = (t>=off)? ls[t-off] : 0;
    __syncthreads();
    ls[t] += x;
    __syncthreads();
  }
  if(t<nb) bsum[t] = ls[t] - v;  // exclusive block offsets
}

__global__ void scan3(int* __restrict__ rowptr, const int* __restrict__ bsum, int n){
  int i = blockIdx.x*blockDim.x + threadIdx.x;
  if(i < n) rowptr[i+1] += bsum[i>>10];
  if(i == 0) rowptr[0] = 0;
}

__global__ void copy_cur(const int* __restrict__ rowptr, int* __restrict__ cur, int n){
  int i = blockIdx.x*blockDim.x + threadIdx.x;
  if(i < n) cur[i] = rowptr[i];
}

__global__ void scatter_kernel(const int* __restrict__ src, const int* __restrict__ dst,
    int* __restrict__ cur, int* __restrict__ esrc, int E){
  int e = blockIdx.x*blockDim.x + threadIdx.x;
  if(e < E){
    int pos = atomicAdd(&cur[dst[e]], 1);
    esrc[pos] = src[e];
  }
}

// ---------------- GAT aggregation: wave per dst node
__global__ __launch_bounds__(256) void agg_kernel(const float* __restrict__ feat,
    const float* __restrict__ el, const float* __restrict__ er,
    const int* __restrict__ rowptr, const int* __restrict__ esrc,
    const float* __restrict__ bias, float* __restrict__ out, int n){
  int wid = (blockIdx.x*blockDim.x + threadIdx.x) >> 6;
  int lane = threadIdx.x & 63;
  if(wid >= n) return;
  int beg = rowptr[wid], end = rowptr[wid+1];
  float er0 = er[(size_t)wid*2], er1 = er[(size_t)wid*2+1];
  // phase 1: denominators (edge-parallel across lanes)
  float d0 = 0.f, d1 = 0.f;
  for(int base = beg; base < end; base += 64){
    int idx = base + lane;
    if(idx < end){
      int s = esrc[idx];
      float e0 = el[(size_t)s*2]   + er0;
      float e1 = el[(size_t)s*2+1] + er1;
      e0 = (e0 >= 0.f) ? e0 : SLOPE*e0;
      e1 = (e1 >= 0.f) ? e1 : SLOPE*e1;
      d0 += expf(e0);
      d1 += expf(e1);
    }
  }
  d0 = wave_sum(d0); d1 = wave_sum(d1);
  float inv0 = 1.0f / fmaxf(d0, 1e-16f);
  float inv1 = 1.0f / fmaxf(d1, 1e-16f);
  // phase 2: weighted message accumulation (lane = feature dim)
  float a0 = 0.f, a1 = 0.f;
  for(int idx = beg; idx < end; ++idx){
    int s = esrc[idx];
    float e0 = el[(size_t)s*2]   + er0;
    float e1 = el[(size_t)s*2+1] + er1;
    e0 = (e0 >= 0.f) ? e0 : SLOPE*e0;
    e1 = (e1 >= 0.f) ? e1 : SLOPE*e1;
    float w0 = expf(e0) * inv0;
    float w1 = expf(e1) * inv1;
    const float* fs = feat + (size_t)s*128;
    a0 += fs[lane]      * w0;
    a1 += fs[64+lane]   * w1;
  }
  out[(size_t)wid*128 + lane]      = fmaxf(a0 + bias[lane],      0.f);
  out[(size_t)wid*128 + 64 + lane] = fmaxf(a1 + bias[64+lane],   0.f);
}

// ---------------- head: relu(h@Wout+bout) @ Wfc + bfc   (32 rows per block)
__global__ __launch_bounds__(256) void head_kernel(const float* __restrict__ h,
    const float* __restrict__ Wout, const float* __restrict__ bout,
    const float* __restrict__ Wfc, const float* __restrict__ bfc,
    float* __restrict__ hfc, int n){
  __shared__ float sW[128*64];   // 32KB
  __shared__ float sF[64*64];    // 16KB
  __shared__ float sR[32][129];  // rows in
  __shared__ float sO[32][65];   // relu intermediate
  int t = threadIdx.x;
  for(int i=t; i<128*64; i+=256) sW[i] = Wout[i];
  for(int i=t; i<64*64;  i+=256) sF[i] = Wfc[i];
  int r0 = blockIdx.x*32;
  {
    int r = t >> 3;            // 0..31
    int c = (t & 7) * 16;      // 0..112
    int gr = r0 + r;
    #pragma unroll
    for(int i=0;i<4;i++){
      float4 v = make_float4(0.f,0.f,0.f,0.f);
      if(gr < n) v = *(const float4*)&h[(size_t)gr*128 + c + i*4];
      *(float4*)&sR[r][c+i*4] = v;
    }
  }
  __syncthreads();
  int g = t >> 6, c = t & 63;
  #pragma unroll
  for(int rr=0; rr<8; ++rr){
    int r = g + rr*4;
    float acc = bout[c];
    #pragma unroll 8
    for(int k=0;k<128;k++) acc += sR[r][k]*sW[k*64+c];
    sO[r][c] = fmaxf(acc, 0.f);
  }
  __syncthreads();
  #pragma unroll
  for(int rr=0; rr<8; ++rr){
    int r = g + rr*4;
    float acc2 = bfc[c];
    #pragma unroll 8
    for(int k=0;k<64;k++) acc2 += sO[r][k]*sF[k*64+c];
    if(r0+r < n) hfc[(size_t)(r0+r)*64 + c] = acc2;
  }
}

// ---------------- BN stats (two-stage, deterministic)
__global__ __launch_bounds__(256) void bn_stats(const float* __restrict__ hfc,
    float* __restrict__ psum, float* __restrict__ psum2, int n){
  int t = threadIdx.x; int c = t & 63; int g = t >> 6;
  int rpb = (n + gridDim.x - 1) / gridDim.x;
  int r0 = blockIdx.x * rpb;
  int r1 = min(n, r0 + rpb);
  float s = 0.f, s2 = 0.f;
  for(int r = r0 + g; r < r1; r += 4){
    float v = hfc[(size_t)r*64 + c];
    s += v; s2 += v*v;
  }
  __shared__ float ls[256], ls2[256];
  ls[t]=s; ls2[t]=s2; __syncthreads();
  if(t < 64){
    s  = ls[t]+ls[t+64]+ls[t+128]+ls[t+192];
    s2 = ls2[t]+ls2[t+64]+ls2[t+128]+ls2[t+192];
    psum[blockIdx.x*64 + t]  = s;
    psum2[blockIdx.x*64 + t] = s2;
  }
}

__global__ __launch_bounds__(64) void bn_fin(const float* __restrict__ psum,
    const float* __restrict__ psum2, const float* __restrict__ gamma,
    const float* __restrict__ beta, float* __restrict__ scsh, int n, int nb){
  int c = threadIdx.x;
  float s=0.f, s2=0.f;
  for(int b=0;b<nb;b++){ s += psum[b*64+c]; s2 += psum2[b*64+c]; }
  float mu  = s / n;
  float var = s2 / n - mu*mu;
  float scale = rsqrtf(var + BN_EPS) * gamma[c];
  scsh[c]    = scale;
  scsh[64+c] = beta[c] - mu*scale;
}

// ---------------- BN apply + row softmax -> p
__global__ __launch_bounds__(256) void bn_softmax(const float* __restrict__ hfc,
    const float* __restrict__ scsh, float* __restrict__ p, int n){
  int wid = (blockIdx.x*blockDim.x + threadIdx.x) >> 6;
  int lane = threadIdx.x & 63;
  if(wid >= n) return;
  float y = hfc[(size_t)wid*64 + lane]*scsh[lane] + scsh[64+lane];
  float m = wave_max(y);
  float e = expf(y - m);
  float s = wave_sum(e);
  p[(size_t)wid*64 + lane] = e / s;
}

// ---------------- loss
__global__ __launch_bounds__(256) void loss1(const float* __restrict__ p,
    const int* __restrict__ train, const int* __restrict__ label,
    float* __restrict__ part, int ntrain){
  int lane = threadIdx.x & 63; int w = threadIdx.x >> 6;
  int gw = blockIdx.x*4 + w; int nw = gridDim.x*4;
  float acc = 0.f;
  for(int t = gw; t < ntrain; t += nw){
    int node = train[t];
    float v = p[(size_t)node*64 + lane];
    float m = wave_max(v);
    float e = expf(v - m);
    float s = wave_sum(e);
    float logp = (v - m) - logf(s);
    int lab = label[node];
    if(lane == lab) acc += logp;
  }
  acc = wave_sum(acc);
  __shared__ float ls[4];
  if(lane == 0) ls[w] = acc;
  __syncthreads();
  if(threadIdx.x == 0) part[blockIdx.x] = ls[0]+ls[1]+ls[2]+ls[3];
}

__global__ void loss2(const float* __restrict__ part, float* __restrict__ out,
                      int nb, int ntrain){
  if(threadIdx.x == 0){
    float s = 0.f;
    for(int i=0;i<nb;i++) s += part[i];
    out[0] = -s / (float)ntrain;
  }
}

extern "C" void kernel_launch(void* const* d_in, const int* in_sizes, int n_in,
                              void* d_out, int out_size, void* d_ws, size_t ws_size,
                              hipStream_t stream){
  const float* feature = (const float*)d_in[0];
  const int*   label   = (const int*)d_in[1];
  const int*   train   = (const int*)d_in[2];
  const int*   src     = (const int*)d_in[3];
  const int*   dst     = (const int*)d_in[4];
  const float* W0   = (const float*)d_in[5];
  const float* al0  = (const float*)d_in[6];
  const float* ar0  = (const float*)d_in[7];
  const float* b0   = (const float*)d_in[8];
  const float* W1   = (const float*)d_in[9];
  const float* al1  = (const float*)d_in[10];
  const float* ar1  = (const float*)d_in[11];
  const float* b1   = (const float*)d_in[12];
  const float* Wout = (const float*)d_in[13];
  const float* bout = (const float*)d_in[14];
  const float* Wfc  = (const float*)d_in[15];
  const float* bfc  = (const float*)d_in[16];
  const float* gamma= (const float*)d_in[17];
  const float* beta = (const float*)d_in[18];

  const int N  = in_sizes[1];
  const int NT = in_sizes[2];
  const int E  = in_sizes[3];

  // workspace carve-up
  size_t off = 0;
  auto alloc = [&](size_t bytes)->void*{
    void* pp = (char*)d_ws + off;
    off += (bytes + 255) & ~(size_t)255;
    return pp;
  };
  float* featbuf = (float*)alloc((size_t)N*128*4);   // feat (layer in use)
  float* hbuf    = (float*)alloc((size_t)N*128*4);   // layer output
  float* el      = (float*)alloc((size_t)N*2*4);
  float* er      = (float*)alloc((size_t)N*2*4);
  int*   deg     = (int*)alloc((size_t)N*4);
  int*   rowptr  = (int*)alloc((size_t)(N+1)*4);
  int*   cur     = (int*)alloc((size_t)N*4);
  int*   esrc    = (int*)alloc((size_t)E*4);
  int*   bsum    = (int*)alloc(512*4);
  float* psum    = (float*)alloc((size_t)256*64*4);
  float* psum2   = (float*)alloc((size_t)256*64*4);
  float* scsh    = (float*)alloc(128*4);
  float* lpart   = (float*)alloc(256*4);
  float* hfc     = featbuf;  // reuse (N*64 <= N*128) after feat no longer needed

  float* p_out   = (float*)d_out;
  float* loss_out= (float*)d_out + (size_t)N*64;

  const int nwaveblk = (N + 3) / 4;          // wave-per-node kernels
  const int egrid    = (E + 255) / 256;
  const int nb1      = (N + 1023) / 1024;    // scan blocks (<=128)

  // ---- CSR build (per call; graph is static but no cross-call caching allowed)
  hipMemsetAsync(deg, 0, (size_t)N*4, stream);
  hist_kernel<<<egrid, 256, 0, stream>>>(dst, deg, E);
  scan1<<<nb1, 256, 0, stream>>>(deg, rowptr, bsum, N);
  scan2<<<1, 128, 0, stream>>>(bsum, nb1);
  scan3<<<(N+255)/256, 256, 0, stream>>>(rowptr, bsum, N);
  copy_cur<<<(N+255)/256, 256, 0, stream>>>(rowptr, cur, N);
  scatter_kernel<<<egrid, 256, 0, stream>>>(src, dst, cur, esrc, E);

  // ---- layer 0
  gemm128<<<(N+127)/128, 256, 0, stream>>>(feature, W0, featbuf, N, 256);
  elr_kernel<<<nwaveblk, 256, 0, stream>>>(featbuf, al0, ar0, el, er, N);
  agg_kernel<<<nwaveblk, 256, 0, stream>>>(featbuf, el, er, rowptr, esrc, b0, hbuf, N);

  // ---- layer 1
  gemm128<<<(N+127)/128, 256, 0, stream>>>(hbuf, W1, featbuf, N, 128);
  elr_kernel<<<nwaveblk, 256, 0, stream>>>(featbuf, al1, ar1, el, er, N);
  agg_kernel<<<nwaveblk, 256, 0, stream>>>(featbuf, el, er, rowptr, esrc, b1, hbuf, N);

  // ---- dense head
  head_kernel<<<(N+31)/32, 256, 0, stream>>>(hbuf, Wout, bout, Wfc, bfc, hfc, N);

  // ---- batchnorm (training-mode batch stats)
  bn_stats<<<256, 256, 0, stream>>>(hfc, psum, psum2, N);
  bn_fin<<<1, 64, 0, stream>>>(psum, psum2, gamma, beta, scsh, N, 256);
  bn_softmax<<<nwaveblk, 256, 0, stream>>>(hfc, scsh, p_out, N);

  // ---- loss
  loss1<<<40, 256, 0, stream>>>(p_out, train, label, lpart, NT);
  loss2<<<1, 64, 0, stream>>>(lpart, loss_out, 40, NT);
}

// Round 3
// 967.140 us; speedup vs baseline: 1.3445x; 1.1599x over previous
//
#include <hip/hip_runtime.h>

#define SLOPE 0.2f
#define BN_EPS 1e-5f

__device__ __forceinline__ float wave_sum(float v){
  #pragma unroll
  for(int o=32;o;o>>=1) v += __shfl_xor(v,o);
  return v;
}
__device__ __forceinline__ float wave_max(float v){
  #pragma unroll
  for(int o=32;o;o>>=1) v = fmaxf(v,__shfl_xor(v,o));
  return v;
}
__device__ __forceinline__ float half_sum(float v){   // reduce within 32-lane half
  #pragma unroll
  for(int o=16;o;o>>=1) v += __shfl_xor(v,o);
  return v;
}
__device__ __forceinline__ unsigned pack_bf16(float a, float b){
  unsigned ua=__float_as_uint(a), ub=__float_as_uint(b);
  ua += 0x7fffu + ((ua>>16)&1u);
  ub += 0x7fffu + ((ub>>16)&1u);
  return (ua>>16) | (ub & 0xffff0000u);
}

// ---------------- GEMM: A[n,K] @ W[K,128] -> bf16-packed out[n][64 uints]
// 128x128 block tile, 8x8 per-thread micro-tile, A transposed in LDS.
__global__ __launch_bounds__(256) void gemm128(const float* __restrict__ A,
    const float* __restrict__ W, unsigned* __restrict__ outb, int n, int K){
  __shared__ float sAT[32][132];   // sAT[k][r]
  __shared__ float sB [32][132];   // sB[k][c]
  int t = threadIdx.x;
  int cx = t & 15;                 // col group: cols cx*8 .. cx*8+7
  int ry = t >> 4;                 // row group: rows ry*8 .. ry*8+7
  int row0 = blockIdx.x * 128;

  int ar = t >> 1;                 // A row 0..127
  int akc = (t & 1) * 16;          // A k-offset within tile
  int bkr = t >> 3;                // B k 0..31
  int bc0 = (t & 7) * 16;          // B col offset

  float acc[8][8] = {};

  for(int k0 = 0; k0 < K; k0 += 32){
    {
      int gr = row0 + ar;
      const float* ap = A + (size_t)gr*K + k0 + akc;
      #pragma unroll
      for(int i=0;i<4;i++){
        float4 v = make_float4(0.f,0.f,0.f,0.f);
        if(gr < n) v = *(const float4*)(ap + i*4);
        sAT[akc+i*4+0][ar] = v.x;
        sAT[akc+i*4+1][ar] = v.y;
        sAT[akc+i*4+2][ar] = v.z;
        sAT[akc+i*4+3][ar] = v.w;
      }
    }
    {
      const float* wp = W + (size_t)(k0+bkr)*128 + bc0;
      #pragma unroll
      for(int i=0;i<4;i++){
        *(float4*)&sB[bkr][bc0+i*4] = *(const float4*)(wp + i*4);
      }
    }
    __syncthreads();
    #pragma unroll 8
    for(int kk = 0; kk < 32; ++kk){
      float4 a0 = *(const float4*)&sAT[kk][ry*8];
      float4 a1 = *(const float4*)&sAT[kk][ry*8+4];
      float4 b0 = *(const float4*)&sB [kk][cx*8];
      float4 b1 = *(const float4*)&sB [kk][cx*8+4];
      float a[8] = {a0.x,a0.y,a0.z,a0.w,a1.x,a1.y,a1.z,a1.w};
      float b[8] = {b0.x,b0.y,b0.z,b0.w,b1.x,b1.y,b1.z,b1.w};
      #pragma unroll
      for(int i=0;i<8;i++)
        #pragma unroll
        for(int j=0;j<8;j++) acc[i][j] += a[i]*b[j];
    }
    __syncthreads();
  }
  #pragma unroll
  for(int i=0;i<8;i++){
    int gr = row0 + ry*8 + i;
    if(gr < n){
      uint4 o;
      o.x = pack_bf16(acc[i][0],acc[i][1]);
      o.y = pack_bf16(acc[i][2],acc[i][3]);
      o.z = pack_bf16(acc[i][4],acc[i][5]);
      o.w = pack_bf16(acc[i][6],acc[i][7]);
      *(uint4*)&outb[(size_t)gr*64 + cx*4] = o;
    }
  }
}

// ---------------- per-node attention terms el/er from bf16 feat (wave per node)
__global__ __launch_bounds__(256) void elr_kernel(const unsigned* __restrict__ featb,
    const float* __restrict__ al, const float* __restrict__ ar,
    float* __restrict__ el, float* __restrict__ er, int n){
  int wid = (blockIdx.x*blockDim.x + threadIdx.x) >> 6;
  int lane = threadIdx.x & 63;
  if(wid >= n) return;
  unsigned v = featb[(size_t)wid*64 + lane];
  float flo = __uint_as_float(v << 16);
  float fhi = __uint_as_float(v & 0xffff0000u);
  float a0 = al[2*lane], a1 = al[2*lane+1];
  float r0 = ar[2*lane], r1 = ar[2*lane+1];
  float pe = flo*a0 + fhi*a1;     // el partial
  float qe = flo*r0 + fhi*r1;     // er partial
  pe = half_sum(pe); qe = half_sum(qe);
  float el0 = __shfl(pe, 0),  el1 = __shfl(pe, 32);
  float er0 = __shfl(qe, 0),  er1 = __shfl(qe, 32);
  if(lane == 0){
    *(float2*)&el[(size_t)wid*2] = make_float2(el0, el1);
    *(float2*)&er[(size_t)wid*2] = make_float2(er0, er1);
  }
}

// ---------------- CSR build
__global__ void hist_kernel(const int* __restrict__ dst, int* __restrict__ deg, int E){
  int e = blockIdx.x*blockDim.x + threadIdx.x;
  if(e < E) atomicAdd(&deg[dst[e]], 1);
}

__global__ __launch_bounds__(256) void scan1(const int* __restrict__ deg,
    int* __restrict__ rowptr, int* __restrict__ bsum, int n){
  __shared__ int ls[256];
  int t = threadIdx.x;
  int base = blockIdx.x*1024 + t*4;
  int v0 = (base+0<n)? deg[base+0]:0;
  int v1 = (base+1<n)? deg[base+1]:0;
  int v2 = (base+2<n)? deg[base+2]:0;
  int v3 = (base+3<n)? deg[base+3]:0;
  int c0=v0, c1=c0+v1, c2=c1+v2, c3=c2+v3;
  ls[t]=c3; __syncthreads();
  for(int off=1; off<256; off<<=1){
    int x = (t>=off)? ls[t-off] : 0;
    __syncthreads();
    ls[t] += x;
    __syncthreads();
  }
  int prefix = ls[t] - c3;
  if(base+0<n) rowptr[base+1] = prefix + c0;
  if(base+1<n) rowptr[base+2] = prefix + c1;
  if(base+2<n) rowptr[base+3] = prefix + c2;
  if(base+3<n) rowptr[base+4] = prefix + c3;
  if(t == 255) bsum[blockIdx.x] = ls[255];
}

__global__ __launch_bounds__(128) void scan2(int* __restrict__ bsum, int nb){
  __shared__ int ls[128];
  int t = threadIdx.x;
  int v = (t<nb)? bsum[t] : 0;
  ls[t]=v; __syncthreads();
  for(int off=1; off<128; off<<=1){
    int x = (t>=off)? ls[t-off] : 0;
    __syncthreads();
    ls[t] += x;
    __syncthreads();
  }
  if(t<nb) bsum[t] = ls[t] - v;  // exclusive block offsets
}

__global__ void scan3(int* __restrict__ rowptr, const int* __restrict__ bsum, int n){
  int i = blockIdx.x*blockDim.x + threadIdx.x;
  if(i < n) rowptr[i+1] += bsum[i>>10];
  if(i == 0) rowptr[0] = 0;
}

__global__ void copy_cur(const int* __restrict__ rowptr, int* __restrict__ cur, int n){
  int i = blockIdx.x*blockDim.x + threadIdx.x;
  if(i < n) cur[i] = rowptr[i];
}

__global__ void scatter_kernel(const int* __restrict__ src, const int* __restrict__ dst,
    int* __restrict__ cur, int* __restrict__ esrc, int E){
  int e = blockIdx.x*blockDim.x + threadIdx.x;
  if(e < E){
    int pos = atomicAdd(&cur[dst[e]], 1);
    esrc[pos] = src[e];
  }
}

// ---------------- GAT aggregation: wave per dst node, bf16 gather
// Lane l accumulates feature dims (2l, 2l+1): lanes 0-31 = head0, 32-63 = head1.
__global__ __launch_bounds__(256) void agg_kernel(const unsigned* __restrict__ featb,
    const float* __restrict__ el, const float* __restrict__ er,
    const int* __restrict__ rowptr, const int* __restrict__ esrc,
    const float* __restrict__ bias, float* __restrict__ out, int n){
  int wid = (blockIdx.x*blockDim.x + threadIdx.x) >> 6;
  int lane = threadIdx.x & 63;
  if(wid >= n) return;
  int beg = rowptr[wid], end = rowptr[wid+1];
  float2 erd = *(const float2*)&er[(size_t)wid*2];

  // pass 1: denominators, one edge per lane
  float d0 = 0.f, d1 = 0.f;
  for(int base = beg; base < end; base += 64){
    int idx = base + lane;
    int s = (idx < end) ? esrc[idx] : 0;
    float2 elv = *(const float2*)&el[(size_t)s*2];
    float e0 = elv.x + erd.x, e1 = elv.y + erd.y;
    e0 = (e0 >= 0.f) ? e0 : SLOPE*e0;
    e1 = (e1 >= 0.f) ? e1 : SLOPE*e1;
    float p0 = __expf(e0), p1 = __expf(e1);
    if(idx >= end){ p0 = 0.f; p1 = 0.f; }
    d0 += p0; d1 += p1;
  }
  d0 = wave_sum(d0); d1 = wave_sum(d1);
  float inv0 = 1.0f / fmaxf(d0, 1e-16f);
  float inv1 = 1.0f / fmaxf(d1, 1e-16f);

  // pass 2: weights per chunk (edge-parallel), then shfl-broadcast accumulation
  float acc0 = 0.f, acc1 = 0.f;
  const unsigned* fb = featb + lane;
  for(int base = beg; base < end; base += 64){
    int idx = base + lane;
    int s = (idx < end) ? esrc[idx] : 0;
    float2 elv = *(const float2*)&el[(size_t)s*2];
    float e0 = elv.x + erd.x, e1 = elv.y + erd.y;
    e0 = (e0 >= 0.f) ? e0 : SLOPE*e0;
    e1 = (e1 >= 0.f) ? e1 : SLOPE*e1;
    float w0 = __expf(e0) * inv0;
    float w1 = __expf(e1) * inv1;
    int nval = min(64, end - base);
    for(int e = 0; e < nval; ++e){
      int   se  = __shfl(s,  e);
      float w0e = __shfl(w0, e);
      float w1e = __shfl(w1, e);
      float w   = (lane < 32) ? w0e : w1e;
      unsigned v = fb[(size_t)se*64];
      float flo = __uint_as_float(v << 16);
      float fhi = __uint_as_float(v & 0xffff0000u);
      acc0 += flo * w;
      acc1 += fhi * w;
    }
  }
  float2 bb = *(const float2*)&bias[2*lane];
  float2 o;
  o.x = fmaxf(acc0 + bb.x, 0.f);
  o.y = fmaxf(acc1 + bb.y, 0.f);
  *(float2*)&out[(size_t)wid*128 + 2*lane] = o;
}

// ---------------- head: relu(h@Wout+bout) @ Wfc + bfc   (32 rows per block)
__global__ __launch_bounds__(256) void head_kernel(const float* __restrict__ h,
    const float* __restrict__ Wout, const float* __restrict__ bout,
    const float* __restrict__ Wfc, const float* __restrict__ bfc,
    float* __restrict__ hfc, int n){
  __shared__ float sW[128*64];   // 32KB
  __shared__ float sF[64*64];    // 16KB
  __shared__ float sR[32][129];
  __shared__ float sO[32][65];
  int t = threadIdx.x;
  for(int i=t; i<128*64; i+=256) sW[i] = Wout[i];
  for(int i=t; i<64*64;  i+=256) sF[i] = Wfc[i];
  int r0 = blockIdx.x*32;
  {
    int r = t >> 3;
    int c = (t & 7) * 16;
    int gr = r0 + r;
    #pragma unroll
    for(int i=0;i<4;i++){
      float4 v = make_float4(0.f,0.f,0.f,0.f);
      if(gr < n) v = *(const float4*)&h[(size_t)gr*128 + c + i*4];
      *(float4*)&sR[r][c+i*4] = v;
    }
  }
  __syncthreads();
  int g = t >> 6, c = t & 63;
  #pragma unroll
  for(int rr=0; rr<8; ++rr){
    int r = g + rr*4;
    float acc = bout[c];
    #pragma unroll 8
    for(int k=0;k<128;k++) acc += sR[r][k]*sW[k*64+c];
    sO[r][c] = fmaxf(acc, 0.f);
  }
  __syncthreads();
  #pragma unroll
  for(int rr=0; rr<8; ++rr){
    int r = g + rr*4;
    float acc2 = bfc[c];
    #pragma unroll 8
    for(int k=0;k<64;k++) acc2 += sO[r][k]*sF[k*64+c];
    if(r0+r < n) hfc[(size_t)(r0+r)*64 + c] = acc2;
  }
}

// ---------------- BN stats (two-stage, deterministic)
__global__ __launch_bounds__(256) void bn_stats(const float* __restrict__ hfc,
    float* __restrict__ psum, float* __restrict__ psum2, int n){
  int t = threadIdx.x; int c = t & 63; int g = t >> 6;
  int rpb = (n + gridDim.x - 1) / gridDim.x;
  int r0 = blockIdx.x * rpb;
  int r1 = min(n, r0 + rpb);
  float s = 0.f, s2 = 0.f;
  for(int r = r0 + g; r < r1; r += 4){
    float v = hfc[(size_t)r*64 + c];
    s += v; s2 += v*v;
  }
  __shared__ float ls[256], ls2[256];
  ls[t]=s; ls2[t]=s2; __syncthreads();
  if(t < 64){
    s  = ls[t]+ls[t+64]+ls[t+128]+ls[t+192];
    s2 = ls2[t]+ls2[t+64]+ls2[t+128]+ls2[t+192];
    psum[blockIdx.x*64 + t]  = s;
    psum2[blockIdx.x*64 + t] = s2;
  }
}

__global__ __launch_bounds__(64) void bn_fin(const float* __restrict__ psum,
    const float* __restrict__ psum2, const float* __restrict__ gamma,
    const float* __restrict__ beta, float* __restrict__ scsh, int n, int nb){
  int c = threadIdx.x;
  float s=0.f, s2=0.f;
  for(int b=0;b<nb;b++){ s += psum[b*64+c]; s2 += psum2[b*64+c]; }
  float mu  = s / n;
  float var = s2 / n - mu*mu;
  float scale = rsqrtf(var + BN_EPS) * gamma[c];
  scsh[c]    = scale;
  scsh[64+c] = beta[c] - mu*scale;
}

// ---------------- BN apply + row softmax -> p
__global__ __launch_bounds__(256) void bn_softmax(const float* __restrict__ hfc,
    const float* __restrict__ scsh, float* __restrict__ p, int n){
  int wid = (blockIdx.x*blockDim.x + threadIdx.x) >> 6;
  int lane = threadIdx.x & 63;
  if(wid >= n) return;
  float y = hfc[(size_t)wid*64 + lane]*scsh[lane] + scsh[64+lane];
  float m = wave_max(y);
  float e = expf(y - m);
  float s = wave_sum(e);
  p[(size_t)wid*64 + lane] = e / s;
}

// ---------------- loss
__global__ __launch_bounds__(256) void loss1(const float* __restrict__ p,
    const int* __restrict__ train, const int* __restrict__ label,
    float* __restrict__ part, int ntrain){
  int lane = threadIdx.x & 63; int w = threadIdx.x >> 6;
  int gw = blockIdx.x*4 + w; int nw = gridDim.x*4;
  float acc = 0.f;
  for(int t = gw; t < ntrain; t += nw){
    int node = train[t];
    float v = p[(size_t)node*64 + lane];
    float m = wave_max(v);
    float e = expf(v - m);
    float s = wave_sum(e);
    float logp = (v - m) - logf(s);
    int lab = label[node];
    if(lane == lab) acc += logp;
  }
  acc = wave_sum(acc);
  __shared__ float ls[4];
  if(lane == 0) ls[w] = acc;
  __syncthreads();
  if(threadIdx.x == 0) part[blockIdx.x] = ls[0]+ls[1]+ls[2]+ls[3];
}

__global__ void loss2(const float* __restrict__ part, float* __restrict__ out,
                      int nb, int ntrain){
  if(threadIdx.x == 0){
    float s = 0.f;
    for(int i=0;i<nb;i++) s += part[i];
    out[0] = -s / (float)ntrain;
  }
}

extern "C" void kernel_launch(void* const* d_in, const int* in_sizes, int n_in,
                              void* d_out, int out_size, void* d_ws, size_t ws_size,
                              hipStream_t stream){
  const float* feature = (const float*)d_in[0];
  const int*   label   = (const int*)d_in[1];
  const int*   train   = (const int*)d_in[2];
  const int*   src     = (const int*)d_in[3];
  const int*   dst     = (const int*)d_in[4];
  const float* W0   = (const float*)d_in[5];
  const float* al0  = (const float*)d_in[6];
  const float* ar0  = (const float*)d_in[7];
  const float* b0   = (const float*)d_in[8];
  const float* W1   = (const float*)d_in[9];
  const float* al1  = (const float*)d_in[10];
  const float* ar1  = (const float*)d_in[11];
  const float* b1   = (const float*)d_in[12];
  const float* Wout = (const float*)d_in[13];
  const float* bout = (const float*)d_in[14];
  const float* Wfc  = (const float*)d_in[15];
  const float* bfc  = (const float*)d_in[16];
  const float* gamma= (const float*)d_in[17];
  const float* beta = (const float*)d_in[18];

  const int N  = in_sizes[1];
  const int NT = in_sizes[2];
  const int E  = in_sizes[3];

  size_t off = 0;
  auto alloc = [&](size_t bytes)->void*{
    void* pp = (char*)d_ws + off;
    off += (bytes + 255) & ~(size_t)255;
    return pp;
  };
  unsigned* featb16 = (unsigned*)alloc((size_t)N*64*4);  // bf16-packed features
  float* hbuf    = (float*)alloc((size_t)N*128*4);       // layer output (f32)
  float* el      = (float*)alloc((size_t)N*2*4);
  float* er      = (float*)alloc((size_t)N*2*4);
  int*   deg     = (int*)alloc((size_t)N*4);
  int*   rowptr  = (int*)alloc((size_t)(N+1)*4);
  int*   cur     = (int*)alloc((size_t)N*4);
  int*   esrc    = (int*)alloc((size_t)E*4);
  int*   bsum    = (int*)alloc(512*4);
  float* psum    = (float*)alloc((size_t)256*64*4);
  float* psum2   = (float*)alloc((size_t)256*64*4);
  float* scsh    = (float*)alloc(128*4);
  float* lpart   = (float*)alloc(256*4);
  float* hfc     = (float*)featb16;  // reuse: featb16 dead after agg L1; sizes equal

  float* p_out   = (float*)d_out;
  float* loss_out= (float*)d_out + (size_t)N*64;

  const int nwaveblk = (N + 3) / 4;
  const int egrid    = (E + 255) / 256;
  const int nb1      = (N + 1023) / 1024;

  // ---- CSR build
  hipMemsetAsync(deg, 0, (size_t)N*4, stream);
  hist_kernel<<<egrid, 256, 0, stream>>>(dst, deg, E);
  scan1<<<nb1, 256, 0, stream>>>(deg, rowptr, bsum, N);
  scan2<<<1, 128, 0, stream>>>(bsum, nb1);
  scan3<<<(N+255)/256, 256, 0, stream>>>(rowptr, bsum, N);
  copy_cur<<<(N+255)/256, 256, 0, stream>>>(rowptr, cur, N);
  scatter_kernel<<<egrid, 256, 0, stream>>>(src, dst, cur, esrc, E);

  // ---- layer 0
  gemm128<<<(N+127)/128, 256, 0, stream>>>(feature, W0, featb16, N, 256);
  elr_kernel<<<nwaveblk, 256, 0, stream>>>(featb16, al0, ar0, el, er, N);
  agg_kernel<<<nwaveblk, 256, 0, stream>>>(featb16, el, er, rowptr, esrc, b0, hbuf, N);

  // ---- layer 1
  gemm128<<<(N+127)/128, 256, 0, stream>>>(hbuf, W1, featb16, N, 128);
  elr_kernel<<<nwaveblk, 256, 0, stream>>>(featb16, al1, ar1, el, er, N);
  agg_kernel<<<nwaveblk, 256, 0, stream>>>(featb16, el, er, rowptr, esrc, b1, hbuf, N);

  // ---- dense head
  head_kernel<<<(N+31)/32, 256, 0, stream>>>(hbuf, Wout, bout, Wfc, bfc, hfc, N);

  // ---- batchnorm
  bn_stats<<<256, 256, 0, stream>>>(hfc, psum, psum2, N);
  bn_fin<<<1, 64, 0, stream>>>(psum, psum2, gamma, beta, scsh, N, 256);
  bn_softmax<<<nwaveblk, 256, 0, stream>>>(hfc, scsh, p_out, N);

  // ---- loss
  loss1<<<40, 256, 0, stream>>>(p_out, train, label, lpart, NT);
  loss2<<<1, 64, 0, stream>>>(lpart, loss_out, 40, NT);
}

// Round 4
// 837.404 us; speedup vs baseline: 1.5528x; 1.1549x over previous
//
#include <hip/hip_runtime.h>

#define SLOPE 0.2f
#define BN_EPS 1e-5f

__device__ __forceinline__ float wave_sum(float v){
  #pragma unroll
  for(int o=32;o;o>>=1) v += __shfl_xor(v,o);
  return v;
}
__device__ __forceinline__ float wave_max(float v){
  #pragma unroll
  for(int o=32;o;o>>=1) v = fmaxf(v,__shfl_xor(v,o));
  return v;
}
__device__ __forceinline__ float half_sum(float v){   // reduce within 32-lane half
  #pragma unroll
  for(int o=16;o;o>>=1) v += __shfl_xor(v,o);
  return v;
}
__device__ __forceinline__ unsigned pack_bf16(float a, float b){
  unsigned ua=__float_as_uint(a), ub=__float_as_uint(b);
  ua += 0x7fffu + ((ua>>16)&1u);
  ub += 0x7fffu + ((ub>>16)&1u);
  return (ua>>16) | (ub & 0xffff0000u);
}

// ---------------- GEMM: A[n,K] @ W[K,128] -> bf16-packed out[n][64 uints]
__global__ __launch_bounds__(256) void gemm128(const float* __restrict__ A,
    const float* __restrict__ W, unsigned* __restrict__ outb, int n, int K){
  __shared__ float sAT[32][132];   // sAT[k][r]
  __shared__ float sB [32][132];   // sB[k][c]
  int t = threadIdx.x;
  int cx = t & 15;
  int ry = t >> 4;
  int row0 = blockIdx.x * 128;

  int ar = t >> 1;
  int akc = (t & 1) * 16;
  int bkr = t >> 3;
  int bc0 = (t & 7) * 16;

  float acc[8][8] = {};

  for(int k0 = 0; k0 < K; k0 += 32){
    {
      int gr = row0 + ar;
      const float* ap = A + (size_t)gr*K + k0 + akc;
      #pragma unroll
      for(int i=0;i<4;i++){
        float4 v = make_float4(0.f,0.f,0.f,0.f);
        if(gr < n) v = *(const float4*)(ap + i*4);
        sAT[akc+i*4+0][ar] = v.x;
        sAT[akc+i*4+1][ar] = v.y;
        sAT[akc+i*4+2][ar] = v.z;
        sAT[akc+i*4+3][ar] = v.w;
      }
    }
    {
      const float* wp = W + (size_t)(k0+bkr)*128 + bc0;
      #pragma unroll
      for(int i=0;i<4;i++){
        *(float4*)&sB[bkr][bc0+i*4] = *(const float4*)(wp + i*4);
      }
    }
    __syncthreads();
    #pragma unroll 8
    for(int kk = 0; kk < 32; ++kk){
      float4 a0 = *(const float4*)&sAT[kk][ry*8];
      float4 a1 = *(const float4*)&sAT[kk][ry*8+4];
      float4 b0 = *(const float4*)&sB [kk][cx*8];
      float4 b1 = *(const float4*)&sB [kk][cx*8+4];
      float a[8] = {a0.x,a0.y,a0.z,a0.w,a1.x,a1.y,a1.z,a1.w};
      float b[8] = {b0.x,b0.y,b0.z,b0.w,b1.x,b1.y,b1.z,b1.w};
      #pragma unroll
      for(int i=0;i<8;i++)
        #pragma unroll
        for(int j=0;j<8;j++) acc[i][j] += a[i]*b[j];
    }
    __syncthreads();
  }
  #pragma unroll
  for(int i=0;i<8;i++){
    int gr = row0 + ry*8 + i;
    if(gr < n){
      uint4 o;
      o.x = pack_bf16(acc[i][0],acc[i][1]);
      o.y = pack_bf16(acc[i][2],acc[i][3]);
      o.z = pack_bf16(acc[i][4],acc[i][5]);
      o.w = pack_bf16(acc[i][6],acc[i][7]);
      *(uint4*)&outb[(size_t)gr*64 + cx*4] = o;
    }
  }
}

// ---------------- per-node attention terms el/er from bf16 feat (wave per node)
__global__ __launch_bounds__(256) void elr_kernel(const unsigned* __restrict__ featb,
    const float* __restrict__ al, const float* __restrict__ ar,
    float* __restrict__ el, float* __restrict__ er, int n){
  int wid = (blockIdx.x*blockDim.x + threadIdx.x) >> 6;
  int lane = threadIdx.x & 63;
  if(wid >= n) return;
  unsigned v = featb[(size_t)wid*64 + lane];
  float flo = __uint_as_float(v << 16);
  float fhi = __uint_as_float(v & 0xffff0000u);
  float a0 = al[2*lane], a1 = al[2*lane+1];
  float r0 = ar[2*lane], r1 = ar[2*lane+1];
  float pe = flo*a0 + fhi*a1;
  float qe = flo*r0 + fhi*r1;
  pe = half_sum(pe); qe = half_sum(qe);
  float el0 = __shfl(pe, 0),  el1 = __shfl(pe, 32);
  float er0 = __shfl(qe, 0),  er1 = __shfl(qe, 32);
  if(lane == 0){
    *(float2*)&el[(size_t)wid*2] = make_float2(el0, el1);
    *(float2*)&er[(size_t)wid*2] = make_float2(er0, er1);
  }
}

// ---------------- CSR build
__global__ void hist_kernel(const int* __restrict__ dst, int* __restrict__ deg, int E){
  int e = blockIdx.x*blockDim.x + threadIdx.x;
  if(e < E) atomicAdd(&deg[dst[e]], 1);
}

__global__ __launch_bounds__(256) void scan1(const int* __restrict__ deg,
    int* __restrict__ rowptr, int* __restrict__ bsum, int n){
  __shared__ int ls[256];
  int t = threadIdx.x;
  int base = blockIdx.x*1024 + t*4;
  int v0 = (base+0<n)? deg[base+0]:0;
  int v1 = (base+1<n)? deg[base+1]:0;
  int v2 = (base+2<n)? deg[base+2]:0;
  int v3 = (base+3<n)? deg[base+3]:0;
  int c0=v0, c1=c0+v1, c2=c1+v2, c3=c2+v3;
  ls[t]=c3; __syncthreads();
  for(int off=1; off<256; off<<=1){
    int x = (t>=off)? ls[t-off] : 0;
    __syncthreads();
    ls[t] += x;
    __syncthreads();
  }
  int prefix = ls[t] - c3;
  if(base+0<n) rowptr[base+1] = prefix + c0;
  if(base+1<n) rowptr[base+2] = prefix + c1;
  if(base+2<n) rowptr[base+3] = prefix + c2;
  if(base+3<n) rowptr[base+4] = prefix + c3;
  if(t == 255) bsum[blockIdx.x] = ls[255];
}

__global__ __launch_bounds__(128) void scan2(int* __restrict__ bsum, int nb){
  __shared__ int ls[128];
  int t = threadIdx.x;
  int v = (t<nb)? bsum[t] : 0;
  ls[t]=v; __syncthreads();
  for(int off=1; off<128; off<<=1){
    int x = (t>=off)? ls[t-off] : 0;
    __syncthreads();
    ls[t] += x;
    __syncthreads();
  }
  if(t<nb) bsum[t] = ls[t] - v;
}

__global__ void scan3(int* __restrict__ rowptr, const int* __restrict__ bsum, int n){
  int i = blockIdx.x*blockDim.x + threadIdx.x;
  if(i < n) rowptr[i+1] += bsum[i>>10];
  if(i == 0) rowptr[0] = 0;
}

__global__ void copy_cur(const int* __restrict__ rowptr, int* __restrict__ cur, int n){
  int i = blockIdx.x*blockDim.x + threadIdx.x;
  if(i < n) cur[i] = rowptr[i];
}

__global__ void scatter_kernel(const int* __restrict__ src, const int* __restrict__ dst,
    int* __restrict__ cur, int* __restrict__ esrc, int E){
  int e = blockIdx.x*blockDim.x + threadIdx.x;
  if(e < E){
    int pos = atomicAdd(&cur[dst[e]], 1);
    esrc[pos] = src[e];
  }
}

// ---------------- GAT aggregation: wave per dst node, bf16 gather
__global__ __launch_bounds__(256) void agg_kernel(const unsigned* __restrict__ featb,
    const float* __restrict__ el, const float* __restrict__ er,
    const int* __restrict__ rowptr, const int* __restrict__ esrc,
    const float* __restrict__ bias, float* __restrict__ out, int n){
  int wid = (blockIdx.x*blockDim.x + threadIdx.x) >> 6;
  int lane = threadIdx.x & 63;
  if(wid >= n) return;
  int beg = rowptr[wid], end = rowptr[wid+1];
  float2 erd = *(const float2*)&er[(size_t)wid*2];

  float d0 = 0.f, d1 = 0.f;
  for(int base = beg; base < end; base += 64){
    int idx = base + lane;
    int s = (idx < end) ? esrc[idx] : 0;
    float2 elv = *(const float2*)&el[(size_t)s*2];
    float e0 = elv.x + erd.x, e1 = elv.y + erd.y;
    e0 = (e0 >= 0.f) ? e0 : SLOPE*e0;
    e1 = (e1 >= 0.f) ? e1 : SLOPE*e1;
    float p0 = __expf(e0), p1 = __expf(e1);
    if(idx >= end){ p0 = 0.f; p1 = 0.f; }
    d0 += p0; d1 += p1;
  }
  d0 = wave_sum(d0); d1 = wave_sum(d1);
  float inv0 = 1.0f / fmaxf(d0, 1e-16f);
  float inv1 = 1.0f / fmaxf(d1, 1e-16f);

  float acc0 = 0.f, acc1 = 0.f;
  const unsigned* fb = featb + lane;
  for(int base = beg; base < end; base += 64){
    int idx = base + lane;
    int s = (idx < end) ? esrc[idx] : 0;
    float2 elv = *(const float2*)&el[(size_t)s*2];
    float e0 = elv.x + erd.x, e1 = elv.y + erd.y;
    e0 = (e0 >= 0.f) ? e0 : SLOPE*e0;
    e1 = (e1 >= 0.f) ? e1 : SLOPE*e1;
    float w0 = __expf(e0) * inv0;
    float w1 = __expf(e1) * inv1;
    int nval = min(64, end - base);
    for(int e = 0; e < nval; ++e){
      int   se  = __shfl(s,  e);
      float w0e = __shfl(w0, e);
      float w1e = __shfl(w1, e);
      float w   = (lane < 32) ? w0e : w1e;
      unsigned v = fb[(size_t)se*64];
      float flo = __uint_as_float(v << 16);
      float fhi = __uint_as_float(v & 0xffff0000u);
      acc0 += flo * w;
      acc1 += fhi * w;
    }
  }
  float2 bb = *(const float2*)&bias[2*lane];
  float2 o;
  o.x = fmaxf(acc0 + bb.x, 0.f);
  o.y = fmaxf(acc1 + bb.y, 0.f);
  *(float2*)&out[(size_t)wid*128 + 2*lane] = o;
}

// ---------------- head: relu(h@Wout+bout) @ Wfc + bfc
// 64 rows/block, 4x4 micro-tile, k-major LDS tiles, float4 LDS reads.
__global__ __launch_bounds__(256) void head_kernel(const float* __restrict__ h,
    const float* __restrict__ Wout, const float* __restrict__ bout,
    const float* __restrict__ Wfc, const float* __restrict__ bfc,
    float* __restrict__ hfc, int n){
  __shared__ float sAT[32][68];   // A^T chunk: [k][row]   8.7KB
  __shared__ float sWo[32][68];   // Wout chunk: [k][col]  8.7KB
  __shared__ float sOT[64][68];   // relu intermediate^T: [k][row] 17.4KB
  __shared__ float sF [64][68];   // Wfc: [k][col]         17.4KB
  int t = threadIdx.x;
  int cx = t & 15;                // col group: cols cx*4..cx*4+3
  int ry = t >> 4;                // row group: rows ry*4..ry*4+3
  int row0 = blockIdx.x * 64;

  // stage Wfc once (64x64): 4 float4 per thread
  {
    int kr = t >> 4;              // 0..15
    int c0 = (t & 15) * 4;
    #pragma unroll
    for(int i=0;i<4;i++)
      *(float4*)&sF[kr+i*16][c0] = *(const float4*)&Wfc[(size_t)(kr+i*16)*64 + c0];
  }

  float acc[4][4] = {};
  // ---- stage 1: A[64x128] @ Wout[128x64], k in 4 chunks of 32
  for(int k0 = 0; k0 < 128; k0 += 32){
    // stage A^T: 64 rows x 32 k = 512 float4, 2 per thread
    #pragma unroll
    for(int u=0;u<2;u++){
      int f4 = t*2 + u;
      int r  = f4 >> 3;           // 0..63
      int kc = (f4 & 7) * 4;      // 0..28
      int gr = row0 + r;
      float4 v = make_float4(0.f,0.f,0.f,0.f);
      if(gr < n) v = *(const float4*)&h[(size_t)gr*128 + k0 + kc];
      sAT[kc+0][r] = v.x;
      sAT[kc+1][r] = v.y;
      sAT[kc+2][r] = v.z;
      sAT[kc+3][r] = v.w;
    }
    // stage Wout chunk: 32 k x 64 c = 512 float4, 2 per thread
    #pragma unroll
    for(int u=0;u<2;u++){
      int f4 = t*2 + u;
      int kr = f4 >> 4;           // 0..31
      int c0 = (f4 & 15) * 4;
      *(float4*)&sWo[kr][c0] = *(const float4*)&Wout[(size_t)(k0+kr)*64 + c0];
    }
    __syncthreads();
    #pragma unroll 8
    for(int kk = 0; kk < 32; ++kk){
      float4 a4 = *(const float4*)&sAT[kk][ry*4];
      float4 b4 = *(const float4*)&sWo[kk][cx*4];
      float a[4] = {a4.x,a4.y,a4.z,a4.w};
      float b[4] = {b4.x,b4.y,b4.z,b4.w};
      #pragma unroll
      for(int i=0;i<4;i++)
        #pragma unroll
        for(int j=0;j<4;j++) acc[i][j] += a[i]*b[j];
    }
    __syncthreads();
  }
  // relu + bias, write transposed into sOT[k][row]
  {
    float4 bb = *(const float4*)&bout[cx*4];
    float bv[4] = {bb.x,bb.y,bb.z,bb.w};
    #pragma unroll
    for(int i=0;i<4;i++)
      #pragma unroll
      for(int j=0;j<4;j++)
        sOT[cx*4+j][ry*4+i] = fmaxf(acc[i][j] + bv[j], 0.f);
  }
  __syncthreads();
  // ---- stage 2: relu1[64x64] @ Wfc[64x64]
  float acc2[4][4] = {};
  #pragma unroll 8
  for(int kk = 0; kk < 64; ++kk){
    float4 a4 = *(const float4*)&sOT[kk][ry*4];
    float4 b4 = *(const float4*)&sF [kk][cx*4];
    float a[4] = {a4.x,a4.y,a4.z,a4.w};
    float b[4] = {b4.x,b4.y,b4.z,b4.w};
    #pragma unroll
    for(int i=0;i<4;i++)
      #pragma unroll
      for(int j=0;j<4;j++) acc2[i][j] += a[i]*b[j];
  }
  {
    float4 bb = *(const float4*)&bfc[cx*4];
    #pragma unroll
    for(int i=0;i<4;i++){
      int gr = row0 + ry*4 + i;
      if(gr < n){
        float4 o = make_float4(acc2[i][0]+bb.x, acc2[i][1]+bb.y,
                               acc2[i][2]+bb.z, acc2[i][3]+bb.w);
        *(float4*)&hfc[(size_t)gr*64 + cx*4] = o;
      }
    }
  }
}

// ---------------- BN stats (two-stage, deterministic)
__global__ __launch_bounds__(256) void bn_stats(const float* __restrict__ hfc,
    float* __restrict__ psum, float* __restrict__ psum2, int n){
  int t = threadIdx.x; int c = t & 63; int g = t >> 6;
  int rpb = (n + gridDim.x - 1) / gridDim.x;
  int r0 = blockIdx.x * rpb;
  int r1 = min(n, r0 + rpb);
  float s = 0.f, s2 = 0.f;
  for(int r = r0 + g; r < r1; r += 4){
    float v = hfc[(size_t)r*64 + c];
    s += v; s2 += v*v;
  }
  __shared__ float ls[256], ls2[256];
  ls[t]=s; ls2[t]=s2; __syncthreads();
  if(t < 64){
    s  = ls[t]+ls[t+64]+ls[t+128]+ls[t+192];
    s2 = ls2[t]+ls2[t+64]+ls2[t+128]+ls2[t+192];
    psum[blockIdx.x*64 + t]  = s;
    psum2[blockIdx.x*64 + t] = s2;
  }
}

__global__ __launch_bounds__(64) void bn_fin(const float* __restrict__ psum,
    const float* __restrict__ psum2, const float* __restrict__ gamma,
    const float* __restrict__ beta, float* __restrict__ scsh, int n, int nb){
  int c = threadIdx.x;
  float s=0.f, s2=0.f;
  for(int b=0;b<nb;b++){ s += psum[b*64+c]; s2 += psum2[b*64+c]; }
  float mu  = s / n;
  float var = s2 / n - mu*mu;
  float scale = rsqrtf(var + BN_EPS) * gamma[c];
  scsh[c]    = scale;
  scsh[64+c] = beta[c] - mu*scale;
}

// ---------------- BN apply + row softmax -> p
__global__ __launch_bounds__(256) void bn_softmax(const float* __restrict__ hfc,
    const float* __restrict__ scsh, float* __restrict__ p, int n){
  int wid = (blockIdx.x*blockDim.x + threadIdx.x) >> 6;
  int lane = threadIdx.x & 63;
  if(wid >= n) return;
  float y = hfc[(size_t)wid*64 + lane]*scsh[lane] + scsh[64+lane];
  float m = wave_max(y);
  float e = expf(y - m);
  float s = wave_sum(e);
  p[(size_t)wid*64 + lane] = e / s;
}

// ---------------- loss
__global__ __launch_bounds__(256) void loss1(const float* __restrict__ p,
    const int* __restrict__ train, const int* __restrict__ label,
    float* __restrict__ part, int ntrain){
  int lane = threadIdx.x & 63; int w = threadIdx.x >> 6;
  int gw = blockIdx.x*4 + w; int nw = gridDim.x*4;
  float acc = 0.f;
  for(int t = gw; t < ntrain; t += nw){
    int node = train[t];
    float v = p[(size_t)node*64 + lane];
    float m = wave_max(v);
    float e = expf(v - m);
    float s = wave_sum(e);
    float logp = (v - m) - logf(s);
    int lab = label[node];
    if(lane == lab) acc += logp;
  }
  acc = wave_sum(acc);
  __shared__ float ls[4];
  if(lane == 0) ls[w] = acc;
  __syncthreads();
  if(threadIdx.x == 0) part[blockIdx.x] = ls[0]+ls[1]+ls[2]+ls[3];
}

__global__ void loss2(const float* __restrict__ part, float* __restrict__ out,
                      int nb, int ntrain){
  if(threadIdx.x == 0){
    float s = 0.f;
    for(int i=0;i<nb;i++) s += part[i];
    out[0] = -s / (float)ntrain;
  }
}

extern "C" void kernel_launch(void* const* d_in, const int* in_sizes, int n_in,
                              void* d_out, int out_size, void* d_ws, size_t ws_size,
                              hipStream_t stream){
  const float* feature = (const float*)d_in[0];
  const int*   label   = (const int*)d_in[1];
  const int*   train   = (const int*)d_in[2];
  const int*   src     = (const int*)d_in[3];
  const int*   dst     = (const int*)d_in[4];
  const float* W0   = (const float*)d_in[5];
  const float* al0  = (const float*)d_in[6];
  const float* ar0  = (const float*)d_in[7];
  const float* b0   = (const float*)d_in[8];
  const float* W1   = (const float*)d_in[9];
  const float* al1  = (const float*)d_in[10];
  const float* ar1  = (const float*)d_in[11];
  const float* b1   = (const float*)d_in[12];
  const float* Wout = (const float*)d_in[13];
  const float* bout = (const float*)d_in[14];
  const float* Wfc  = (const float*)d_in[15];
  const float* bfc  = (const float*)d_in[16];
  const float* gamma= (const float*)d_in[17];
  const float* beta = (const float*)d_in[18];

  const int N  = in_sizes[1];
  const int NT = in_sizes[2];
  const int E  = in_sizes[3];

  size_t off = 0;
  auto alloc = [&](size_t bytes)->void*{
    void* pp = (char*)d_ws + off;
    off += (bytes + 255) & ~(size_t)255;
    return pp;
  };
  unsigned* featb16 = (unsigned*)alloc((size_t)N*64*4);
  float* hbuf    = (float*)alloc((size_t)N*128*4);
  float* el      = (float*)alloc((size_t)N*2*4);
  float* er      = (float*)alloc((size_t)N*2*4);
  int*   deg     = (int*)alloc((size_t)N*4);
  int*   rowptr  = (int*)alloc((size_t)(N+1)*4);
  int*   cur     = (int*)alloc((size_t)N*4);
  int*   esrc    = (int*)alloc((size_t)E*4);
  int*   bsum    = (int*)alloc(512*4);
  float* psum    = (float*)alloc((size_t)256*64*4);
  float* psum2   = (float*)alloc((size_t)256*64*4);
  float* scsh    = (float*)alloc(128*4);
  float* lpart   = (float*)alloc(256*4);
  float* hfc     = (float*)featb16;  // reuse: featb16 dead after agg L1

  float* p_out   = (float*)d_out;
  float* loss_out= (float*)d_out + (size_t)N*64;

  const int nwaveblk = (N + 3) / 4;
  const int egrid    = (E + 255) / 256;
  const int nb1      = (N + 1023) / 1024;

  // ---- CSR build
  hipMemsetAsync(deg, 0, (size_t)N*4, stream);
  hist_kernel<<<egrid, 256, 0, stream>>>(dst, deg, E);
  scan1<<<nb1, 256, 0, stream>>>(deg, rowptr, bsum, N);
  scan2<<<1, 128, 0, stream>>>(bsum, nb1);
  scan3<<<(N+255)/256, 256, 0, stream>>>(rowptr, bsum, N);
  copy_cur<<<(N+255)/256, 256, 0, stream>>>(rowptr, cur, N);
  scatter_kernel<<<egrid, 256, 0, stream>>>(src, dst, cur, esrc, E);

  // ---- layer 0
  gemm128<<<(N+127)/128, 256, 0, stream>>>(feature, W0, featb16, N, 256);
  elr_kernel<<<nwaveblk, 256, 0, stream>>>(featb16, al0, ar0, el, er, N);
  agg_kernel<<<nwaveblk, 256, 0, stream>>>(featb16, el, er, rowptr, esrc, b0, hbuf, N);

  // ---- layer 1
  gemm128<<<(N+127)/128, 256, 0, stream>>>(hbuf, W1, featb16, N, 128);
  elr_kernel<<<nwaveblk, 256, 0, stream>>>(featb16, al1, ar1, el, er, N);
  agg_kernel<<<nwaveblk, 256, 0, stream>>>(featb16, el, er, rowptr, esrc, b1, hbuf, N);

  // ---- dense head
  head_kernel<<<(N+63)/64, 256, 0, stream>>>(hbuf, Wout, bout, Wfc, bfc, hfc, N);

  // ---- batchnorm
  bn_stats<<<256, 256, 0, stream>>>(hfc, psum, psum2, N);
  bn_fin<<<1, 64, 0, stream>>>(psum, psum2, gamma, beta, scsh, N, 256);
  bn_softmax<<<nwaveblk, 256, 0, stream>>>(hfc, scsh, p_out, N);

  // ---- loss
  loss1<<<40, 256, 0, stream>>>(p_out, train, label, lpart, NT);
  loss2<<<1, 64, 0, stream>>>(lpart, loss_out, 40, NT);
}

// Round 5
// 678.070 us; speedup vs baseline: 1.9177x; 1.2350x over previous
//
#include <hip/hip_runtime.h>

#define SLOPE 0.2f
#define BN_EPS 1e-5f

#define CSR_TILE 4096       // edges per tile (phase A/C)
#define NBUCK_SH 9          // bucket = dst >> 9  (512 nodes per bucket)

__device__ __forceinline__ float wave_sum(float v){
  #pragma unroll
  for(int o=32;o;o>>=1) v += __shfl_xor(v,o);
  return v;
}
__device__ __forceinline__ float wave_max(float v){
  #pragma unroll
  for(int o=32;o;o>>=1) v = fmaxf(v,__shfl_xor(v,o));
  return v;
}
__device__ __forceinline__ float half_sum(float v){
  #pragma unroll
  for(int o=16;o;o>>=1) v += __shfl_xor(v,o);
  return v;
}
__device__ __forceinline__ unsigned pack_bf16(float a, float b){
  unsigned ua=__float_as_uint(a), ub=__float_as_uint(b);
  ua += 0x7fffu + ((ua>>16)&1u);
  ub += 0x7fffu + ((ub>>16)&1u);
  return (ua>>16) | (ub & 0xffff0000u);
}

// ---------------- GEMM: A[n,K] @ W[K,128] -> bf16-packed out[n][64 uints]
__global__ __launch_bounds__(256) void gemm128(const float* __restrict__ A,
    const float* __restrict__ W, unsigned* __restrict__ outb, int n, int K){
  __shared__ float sAT[32][132];
  __shared__ float sB [32][132];
  int t = threadIdx.x;
  int cx = t & 15;
  int ry = t >> 4;
  int row0 = blockIdx.x * 128;

  int ar = t >> 1;
  int akc = (t & 1) * 16;
  int bkr = t >> 3;
  int bc0 = (t & 7) * 16;

  float acc[8][8] = {};

  for(int k0 = 0; k0 < K; k0 += 32){
    {
      int gr = row0 + ar;
      const float* ap = A + (size_t)gr*K + k0 + akc;
      #pragma unroll
      for(int i=0;i<4;i++){
        float4 v = make_float4(0.f,0.f,0.f,0.f);
        if(gr < n) v = *(const float4*)(ap + i*4);
        sAT[akc+i*4+0][ar] = v.x;
        sAT[akc+i*4+1][ar] = v.y;
        sAT[akc+i*4+2][ar] = v.z;
        sAT[akc+i*4+3][ar] = v.w;
      }
    }
    {
      const float* wp = W + (size_t)(k0+bkr)*128 + bc0;
      #pragma unroll
      for(int i=0;i<4;i++){
        *(float4*)&sB[bkr][bc0+i*4] = *(const float4*)(wp + i*4);
      }
    }
    __syncthreads();
    #pragma unroll 8
    for(int kk = 0; kk < 32; ++kk){
      float4 a0 = *(const float4*)&sAT[kk][ry*8];
      float4 a1 = *(const float4*)&sAT[kk][ry*8+4];
      float4 b0 = *(const float4*)&sB [kk][cx*8];
      float4 b1 = *(const float4*)&sB [kk][cx*8+4];
      float a[8] = {a0.x,a0.y,a0.z,a0.w,a1.x,a1.y,a1.z,a1.w};
      float b[8] = {b0.x,b0.y,b0.z,b0.w,b1.x,b1.y,b1.z,b1.w};
      #pragma unroll
      for(int i=0;i<8;i++)
        #pragma unroll
        for(int j=0;j<8;j++) acc[i][j] += a[i]*b[j];
    }
    __syncthreads();
  }
  #pragma unroll
  for(int i=0;i<8;i++){
    int gr = row0 + ry*8 + i;
    if(gr < n){
      uint4 o;
      o.x = pack_bf16(acc[i][0],acc[i][1]);
      o.y = pack_bf16(acc[i][2],acc[i][3]);
      o.z = pack_bf16(acc[i][4],acc[i][5]);
      o.w = pack_bf16(acc[i][6],acc[i][7]);
      *(uint4*)&outb[(size_t)gr*64 + cx*4] = o;
    }
  }
}

// ---------------- per-node attention terms el/er from bf16 feat (wave per node)
__global__ __launch_bounds__(256) void elr_kernel(const unsigned* __restrict__ featb,
    const float* __restrict__ al, const float* __restrict__ ar,
    float* __restrict__ el, float* __restrict__ er, int n){
  int wid = (blockIdx.x*blockDim.x + threadIdx.x) >> 6;
  int lane = threadIdx.x & 63;
  if(wid >= n) return;
  unsigned v = featb[(size_t)wid*64 + lane];
  float flo = __uint_as_float(v << 16);
  float fhi = __uint_as_float(v & 0xffff0000u);
  float a0 = al[2*lane], a1 = al[2*lane+1];
  float r0 = ar[2*lane], r1 = ar[2*lane+1];
  float pe = flo*a0 + fhi*a1;
  float qe = flo*r0 + fhi*r1;
  pe = half_sum(pe); qe = half_sum(qe);
  float el0 = __shfl(pe, 0),  el1 = __shfl(pe, 32);
  float er0 = __shfl(qe, 0),  er1 = __shfl(qe, 32);
  if(lane == 0){
    *(float2*)&el[(size_t)wid*2] = make_float2(el0, el1);
    *(float2*)&er[(size_t)wid*2] = make_float2(er0, er1);
  }
}

// ================= CSR build: two-level counting sort =================
// A: per-tile histogram over coarse buckets
__global__ __launch_bounds__(256) void csrA(const int* __restrict__ dst,
    int* __restrict__ thist, int E, int nbuck, int ntiles){
  __shared__ int h[512];
  int t = threadIdx.x;
  if(t < nbuck) h[t] = 0;
  __syncthreads();
  int base = blockIdx.x * CSR_TILE;
  for(int k = 0; k < CSR_TILE/256; ++k){
    int e = base + k*256 + t;
    if(e < E) atomicAdd(&h[dst[e] >> NBUCK_SH], 1);
  }
  __syncthreads();
  if(t < nbuck) thist[blockIdx.x*nbuck + t] = h[t];
}

// B1: per bucket, scan tile-hists -> off[b][tile], total[b]
__global__ __launch_bounds__(512) void csrB1(const int* __restrict__ thist,
    int* __restrict__ off, int* __restrict__ btotal, int nbuck, int ntiles){
  __shared__ int ls[512];
  int t = threadIdx.x;
  int b = blockIdx.x;
  int v = (t < ntiles) ? thist[(size_t)t*nbuck + b] : 0;
  ls[t] = v; __syncthreads();
  for(int o=1;o<512;o<<=1){
    int x = (t>=o) ? ls[t-o] : 0;
    __syncthreads();
    ls[t] += x;
    __syncthreads();
  }
  if(t < ntiles) off[(size_t)b*ntiles + t] = ls[t] - v;
  if(t == 511) btotal[b] = ls[511];
}

// B2: scan bucket totals -> bbase
__global__ __launch_bounds__(256) void csrB2(const int* __restrict__ btotal,
    int* __restrict__ bbase, int nbuck, int E){
  __shared__ int ls[256];
  int t = threadIdx.x;
  int v = (t < nbuck) ? btotal[t] : 0;
  ls[t] = v; __syncthreads();
  for(int o=1;o<256;o<<=1){
    int x = (t>=o) ? ls[t-o] : 0;
    __syncthreads();
    ls[t] += x;
    __syncthreads();
  }
  if(t < nbuck) bbase[t] = ls[t] - v;
  if(t == 0) bbase[nbuck] = E;
}

// C: scatter packed (src | dst_local<<17) into bucket-major tmp.
// Runs per (bucket,tile) are contiguous -> lines owned by one block.
__global__ __launch_bounds__(256) void csrC(const int* __restrict__ src,
    const int* __restrict__ dst, const int* __restrict__ off,
    const int* __restrict__ bbase, unsigned* __restrict__ tmp,
    int E, int nbuck, int ntiles){
  __shared__ int basel[512];
  __shared__ int cnt[512];
  int t = threadIdx.x;
  int tile = blockIdx.x;
  if(t < nbuck){
    basel[t] = bbase[t] + off[(size_t)t*ntiles + tile];
    cnt[t] = 0;
  }
  __syncthreads();
  int base = tile * CSR_TILE;
  for(int k = 0; k < CSR_TILE/256; ++k){
    int e = base + k*256 + t;
    if(e < E){
      int d = dst[e];
      int s = src[e];
      int b = d >> NBUCK_SH;
      int r = atomicAdd(&cnt[b], 1);
      tmp[basel[b] + r] = (unsigned)s | ((unsigned)(d & ((1<<NBUCK_SH)-1)) << 17);
    }
  }
}

// D: per bucket: local hist+scan -> rowptr, then scatter src ids -> esrc.
__global__ __launch_bounds__(512) void csrD(const unsigned* __restrict__ tmp,
    const int* __restrict__ bbase, int* __restrict__ rowptr,
    int* __restrict__ esrc, int N, int E, int nbuck){
  __shared__ int hist[512];
  __shared__ int ls[512];
  int t = threadIdx.x;
  int b = blockIdx.x;
  int base = bbase[b];
  int cnt  = bbase[b+1] - base;
  int n0   = b << NBUCK_SH;
  int nn   = min(512, N - n0);
  hist[t] = 0;
  __syncthreads();
  for(int i = t; i < cnt; i += 512)
    atomicAdd(&hist[tmp[base+i] >> 17], 1);
  __syncthreads();
  int v = hist[t];
  ls[t] = v; __syncthreads();
  for(int o=1;o<512;o<<=1){
    int x = (t>=o) ? ls[t-o] : 0;
    __syncthreads();
    ls[t] += x;
    __syncthreads();
  }
  int rp = ls[t] - v;               // exclusive prefix within bucket
  if(t < nn) rowptr[n0 + t] = base + rp;
  if(b == nbuck-1 && t == 0) rowptr[N] = E;
  __syncthreads();
  hist[t] = rp;                     // reuse as running cursor
  __syncthreads();
  for(int i = t; i < cnt; i += 512){
    unsigned v2 = tmp[base+i];
    int dl = v2 >> 17;
    int s  = v2 & 0x1FFFF;
    int r  = atomicAdd(&hist[dl], 1);
    esrc[base + r] = s;
  }
}

// ---------------- GAT aggregation: wave per dst node, bf16 gather
__global__ __launch_bounds__(256) void agg_kernel(const unsigned* __restrict__ featb,
    const float* __restrict__ el, const float* __restrict__ er,
    const int* __restrict__ rowptr, const int* __restrict__ esrc,
    const float* __restrict__ bias, float* __restrict__ out, int n){
  int wid = (blockIdx.x*blockDim.x + threadIdx.x) >> 6;
  int lane = threadIdx.x & 63;
  if(wid >= n) return;
  int beg = rowptr[wid], end = rowptr[wid+1];
  float2 erd = *(const float2*)&er[(size_t)wid*2];

  float d0 = 0.f, d1 = 0.f;
  for(int base = beg; base < end; base += 64){
    int idx = base + lane;
    int s = (idx < end) ? esrc[idx] : 0;
    float2 elv = *(const float2*)&el[(size_t)s*2];
    float e0 = elv.x + erd.x, e1 = elv.y + erd.y;
    e0 = (e0 >= 0.f) ? e0 : SLOPE*e0;
    e1 = (e1 >= 0.f) ? e1 : SLOPE*e1;
    float p0 = __expf(e0), p1 = __expf(e1);
    if(idx >= end){ p0 = 0.f; p1 = 0.f; }
    d0 += p0; d1 += p1;
  }
  d0 = wave_sum(d0); d1 = wave_sum(d1);
  float inv0 = 1.0f / fmaxf(d0, 1e-16f);
  float inv1 = 1.0f / fmaxf(d1, 1e-16f);

  float acc0 = 0.f, acc1 = 0.f;
  const unsigned* fb = featb + lane;
  for(int base = beg; base < end; base += 64){
    int idx = base + lane;
    int s = (idx < end) ? esrc[idx] : 0;
    float2 elv = *(const float2*)&el[(size_t)s*2];
    float e0 = elv.x + erd.x, e1 = elv.y + erd.y;
    e0 = (e0 >= 0.f) ? e0 : SLOPE*e0;
    e1 = (e1 >= 0.f) ? e1 : SLOPE*e1;
    float w0 = __expf(e0) * inv0;
    float w1 = __expf(e1) * inv1;
    int nval = min(64, end - base);
    for(int e = 0; e < nval; ++e){
      int   se  = __shfl(s,  e);
      float w0e = __shfl(w0, e);
      float w1e = __shfl(w1, e);
      float w   = (lane < 32) ? w0e : w1e;
      unsigned v = fb[(size_t)se*64];
      float flo = __uint_as_float(v << 16);
      float fhi = __uint_as_float(v & 0xffff0000u);
      acc0 += flo * w;
      acc1 += fhi * w;
    }
  }
  float2 bb = *(const float2*)&bias[2*lane];
  float2 o;
  o.x = fmaxf(acc0 + bb.x, 0.f);
  o.y = fmaxf(acc1 + bb.y, 0.f);
  *(float2*)&out[(size_t)wid*128 + 2*lane] = o;
}

// ---------------- head: relu(h@Wout+bout) @ Wfc + bfc
__global__ __launch_bounds__(256) void head_kernel(const float* __restrict__ h,
    const float* __restrict__ Wout, const float* __restrict__ bout,
    const float* __restrict__ Wfc, const float* __restrict__ bfc,
    float* __restrict__ hfc, int n){
  __shared__ float sAT[32][68];
  __shared__ float sWo[32][68];
  __shared__ float sOT[64][68];
  __shared__ float sF [64][68];
  int t = threadIdx.x;
  int cx = t & 15;
  int ry = t >> 4;
  int row0 = blockIdx.x * 64;

  {
    int kr = t >> 4;
    int c0 = (t & 15) * 4;
    #pragma unroll
    for(int i=0;i<4;i++)
      *(float4*)&sF[kr+i*16][c0] = *(const float4*)&Wfc[(size_t)(kr+i*16)*64 + c0];
  }

  float acc[4][4] = {};
  for(int k0 = 0; k0 < 128; k0 += 32){
    #pragma unroll
    for(int u=0;u<2;u++){
      int f4 = t*2 + u;
      int r  = f4 >> 3;
      int kc = (f4 & 7) * 4;
      int gr = row0 + r;
      float4 v = make_float4(0.f,0.f,0.f,0.f);
      if(gr < n) v = *(const float4*)&h[(size_t)gr*128 + k0 + kc];
      sAT[kc+0][r] = v.x;
      sAT[kc+1][r] = v.y;
      sAT[kc+2][r] = v.z;
      sAT[kc+3][r] = v.w;
    }
    #pragma unroll
    for(int u=0;u<2;u++){
      int f4 = t*2 + u;
      int kr = f4 >> 4;
      int c0 = (f4 & 15) * 4;
      *(float4*)&sWo[kr][c0] = *(const float4*)&Wout[(size_t)(k0+kr)*64 + c0];
    }
    __syncthreads();
    #pragma unroll 8
    for(int kk = 0; kk < 32; ++kk){
      float4 a4 = *(const float4*)&sAT[kk][ry*4];
      float4 b4 = *(const float4*)&sWo[kk][cx*4];
      float a[4] = {a4.x,a4.y,a4.z,a4.w};
      float b[4] = {b4.x,b4.y,b4.z,b4.w};
      #pragma unroll
      for(int i=0;i<4;i++)
        #pragma unroll
        for(int j=0;j<4;j++) acc[i][j] += a[i]*b[j];
    }
    __syncthreads();
  }
  {
    float4 bb = *(const float4*)&bout[cx*4];
    float bv[4] = {bb.x,bb.y,bb.z,bb.w};
    #pragma unroll
    for(int i=0;i<4;i++)
      #pragma unroll
      for(int j=0;j<4;j++)
        sOT[cx*4+j][ry*4+i] = fmaxf(acc[i][j] + bv[j], 0.f);
  }
  __syncthreads();
  float acc2[4][4] = {};
  #pragma unroll 8
  for(int kk = 0; kk < 64; ++kk){
    float4 a4 = *(const float4*)&sOT[kk][ry*4];
    float4 b4 = *(const float4*)&sF [kk][cx*4];
    float a[4] = {a4.x,a4.y,a4.z,a4.w};
    float b[4] = {b4.x,b4.y,b4.z,b4.w};
    #pragma unroll
    for(int i=0;i<4;i++)
      #pragma unroll
      for(int j=0;j<4;j++) acc2[i][j] += a[i]*b[j];
  }
  {
    float4 bb = *(const float4*)&bfc[cx*4];
    #pragma unroll
    for(int i=0;i<4;i++){
      int gr = row0 + ry*4 + i;
      if(gr < n){
        float4 o = make_float4(acc2[i][0]+bb.x, acc2[i][1]+bb.y,
                               acc2[i][2]+bb.z, acc2[i][3]+bb.w);
        *(float4*)&hfc[(size_t)gr*64 + cx*4] = o;
      }
    }
  }
}

// ---------------- BN stats (two-stage, deterministic)
__global__ __launch_bounds__(256) void bn_stats(const float* __restrict__ hfc,
    float* __restrict__ psum, float* __restrict__ psum2, int n){
  int t = threadIdx.x; int c = t & 63; int g = t >> 6;
  int rpb = (n + gridDim.x - 1) / gridDim.x;
  int r0 = blockIdx.x * rpb;
  int r1 = min(n, r0 + rpb);
  float s = 0.f, s2 = 0.f;
  for(int r = r0 + g; r < r1; r += 4){
    float v = hfc[(size_t)r*64 + c];
    s += v; s2 += v*v;
  }
  __shared__ float ls[256], ls2[256];
  ls[t]=s; ls2[t]=s2; __syncthreads();
  if(t < 64){
    s  = ls[t]+ls[t+64]+ls[t+128]+ls[t+192];
    s2 = ls2[t]+ls2[t+64]+ls2[t+128]+ls2[t+192];
    psum[blockIdx.x*64 + t]  = s;
    psum2[blockIdx.x*64 + t] = s2;
  }
}

__global__ __launch_bounds__(64) void bn_fin(const float* __restrict__ psum,
    const float* __restrict__ psum2, const float* __restrict__ gamma,
    const float* __restrict__ beta, float* __restrict__ scsh, int n, int nb){
  int c = threadIdx.x;
  float s=0.f, s2=0.f;
  for(int b=0;b<nb;b++){ s += psum[b*64+c]; s2 += psum2[b*64+c]; }
  float mu  = s / n;
  float var = s2 / n - mu*mu;
  float scale = rsqrtf(var + BN_EPS) * gamma[c];
  scsh[c]    = scale;
  scsh[64+c] = beta[c] - mu*scale;
}

// ---------------- BN apply + row softmax -> p
__global__ __launch_bounds__(256) void bn_softmax(const float* __restrict__ hfc,
    const float* __restrict__ scsh, float* __restrict__ p, int n){
  int wid = (blockIdx.x*blockDim.x + threadIdx.x) >> 6;
  int lane = threadIdx.x & 63;
  if(wid >= n) return;
  float y = hfc[(size_t)wid*64 + lane]*scsh[lane] + scsh[64+lane];
  float m = wave_max(y);
  float e = expf(y - m);
  float s = wave_sum(e);
  p[(size_t)wid*64 + lane] = e / s;
}

// ---------------- loss
__global__ __launch_bounds__(256) void loss1(const float* __restrict__ p,
    const int* __restrict__ train, const int* __restrict__ label,
    float* __restrict__ part, int ntrain){
  int lane = threadIdx.x & 63; int w = threadIdx.x >> 6;
  int gw = blockIdx.x*4 + w; int nw = gridDim.x*4;
  float acc = 0.f;
  for(int t = gw; t < ntrain; t += nw){
    int node = train[t];
    float v = p[(size_t)node*64 + lane];
    float m = wave_max(v);
    float e = expf(v - m);
    float s = wave_sum(e);
    float logp = (v - m) - logf(s);
    int lab = label[node];
    if(lane == lab) acc += logp;
  }
  acc = wave_sum(acc);
  __shared__ float ls[4];
  if(lane == 0) ls[w] = acc;
  __syncthreads();
  if(threadIdx.x == 0) part[blockIdx.x] = ls[0]+ls[1]+ls[2]+ls[3];
}

__global__ void loss2(const float* __restrict__ part, float* __restrict__ out,
                      int nb, int ntrain){
  if(threadIdx.x == 0){
    float s = 0.f;
    for(int i=0;i<nb;i++) s += part[i];
    out[0] = -s / (float)ntrain;
  }
}

extern "C" void kernel_launch(void* const* d_in, const int* in_sizes, int n_in,
                              void* d_out, int out_size, void* d_ws, size_t ws_size,
                              hipStream_t stream){
  const float* feature = (const float*)d_in[0];
  const int*   label   = (const int*)d_in[1];
  const int*   train   = (const int*)d_in[2];
  const int*   src     = (const int*)d_in[3];
  const int*   dst     = (const int*)d_in[4];
  const float* W0   = (const float*)d_in[5];
  const float* al0  = (const float*)d_in[6];
  const float* ar0  = (const float*)d_in[7];
  const float* b0   = (const float*)d_in[8];
  const float* W1   = (const float*)d_in[9];
  const float* al1  = (const float*)d_in[10];
  const float* ar1  = (const float*)d_in[11];
  const float* b1   = (const float*)d_in[12];
  const float* Wout = (const float*)d_in[13];
  const float* bout = (const float*)d_in[14];
  const float* Wfc  = (const float*)d_in[15];
  const float* bfc  = (const float*)d_in[16];
  const float* gamma= (const float*)d_in[17];
  const float* beta = (const float*)d_in[18];

  const int N  = in_sizes[1];
  const int NT = in_sizes[2];
  const int E  = in_sizes[3];

  const int nbuck  = (N + (1<<NBUCK_SH) - 1) >> NBUCK_SH;   // 196
  const int ntiles = (E + CSR_TILE - 1) / CSR_TILE;         // 391

  size_t off = 0;
  auto alloc = [&](size_t bytes)->void*{
    void* pp = (char*)d_ws + off;
    off += (bytes + 255) & ~(size_t)255;
    return pp;
  };
  unsigned* featb16 = (unsigned*)alloc((size_t)N*64*4);
  float* hbuf    = (float*)alloc((size_t)N*128*4);
  float* el      = (float*)alloc((size_t)N*2*4);
  float* er      = (float*)alloc((size_t)N*2*4);
  int*   rowptr  = (int*)alloc((size_t)(N+1)*4);
  int*   esrc    = (int*)alloc((size_t)E*4);
  int*   thist   = (int*)alloc((size_t)ntiles*nbuck*4);
  int*   offarr  = (int*)alloc((size_t)nbuck*ntiles*4);
  int*   btotal  = (int*)alloc((size_t)nbuck*4);
  int*   bbase   = (int*)alloc((size_t)(nbuck+1)*4);
  float* psum    = (float*)alloc((size_t)256*64*4);
  float* psum2   = (float*)alloc((size_t)256*64*4);
  float* scsh    = (float*)alloc(128*4);
  float* lpart   = (float*)alloc(256*4);
  float* hfc     = (float*)featb16;         // reuse: featb16 dead after agg L1
  unsigned* tmp  = (unsigned*)hbuf;         // reuse: hbuf first written by agg L0 (after csrD)

  float* p_out   = (float*)d_out;
  float* loss_out= (float*)d_out + (size_t)N*64;

  const int nwaveblk = (N + 3) / 4;

  // ---- CSR build (two-level counting sort; line-ownership-friendly writes)
  csrA<<<ntiles, 256, 0, stream>>>(dst, thist, E, nbuck, ntiles);
  csrB1<<<nbuck, 512, 0, stream>>>(thist, offarr, btotal, nbuck, ntiles);
  csrB2<<<1, 256, 0, stream>>>(btotal, bbase, nbuck, E);
  csrC<<<ntiles, 256, 0, stream>>>(src, dst, offarr, bbase, tmp, E, nbuck, ntiles);
  csrD<<<nbuck, 512, 0, stream>>>(tmp, bbase, rowptr, esrc, N, E, nbuck);

  // ---- layer 0
  gemm128<<<(N+127)/128, 256, 0, stream>>>(feature, W0, featb16, N, 256);
  elr_kernel<<<nwaveblk, 256, 0, stream>>>(featb16, al0, ar0, el, er, N);
  agg_kernel<<<nwaveblk, 256, 0, stream>>>(featb16, el, er, rowptr, esrc, b0, hbuf, N);

  // ---- layer 1
  gemm128<<<(N+127)/128, 256, 0, stream>>>(hbuf, W1, featb16, N, 128);
  elr_kernel<<<nwaveblk, 256, 0, stream>>>(featb16, al1, ar1, el, er, N);
  agg_kernel<<<nwaveblk, 256, 0, stream>>>(featb16, el, er, rowptr, esrc, b1, hbuf, N);

  // ---- dense head
  head_kernel<<<(N+63)/64, 256, 0, stream>>>(hbuf, Wout, bout, Wfc, bfc, hfc, N);

  // ---- batchnorm
  bn_stats<<<256, 256, 0, stream>>>(hfc, psum, psum2, N);
  bn_fin<<<1, 64, 0, stream>>>(psum, psum2, gamma, beta, scsh, N, 256);
  bn_softmax<<<nwaveblk, 256, 0, stream>>>(hfc, scsh, p_out, N);

  // ---- loss
  loss1<<<40, 256, 0, stream>>>(p_out, train, label, lpart, NT);
  loss2<<<1, 64, 0, stream>>>(lpart, loss_out, 40, NT);
}

// Round 6
// 605.999 us; speedup vs baseline: 2.1458x; 1.1189x over previous
//
#include <hip/hip_runtime.h>

#define SLOPE 0.2f
#define BN_EPS 1e-5f

#define CSR_TILE 4096       // edges per tile (phase A/C)
#define NBUCK_SH 9          // bucket = dst >> 9  (512 nodes per bucket)

typedef __attribute__((ext_vector_type(8))) short bf16x8;
typedef __attribute__((ext_vector_type(4))) float f32x4;

__device__ __forceinline__ float wave_sum(float v){
  #pragma unroll
  for(int o=32;o;o>>=1) v += __shfl_xor(v,o);
  return v;
}
__device__ __forceinline__ float wave_max(float v){
  #pragma unroll
  for(int o=32;o;o>>=1) v = fmaxf(v,__shfl_xor(v,o));
  return v;
}
__device__ __forceinline__ float half_sum(float v){
  #pragma unroll
  for(int o=16;o;o>>=1) v += __shfl_xor(v,o);
  return v;
}
__device__ __forceinline__ unsigned pack_bf16(float a, float b){
  unsigned ua=__float_as_uint(a), ub=__float_as_uint(b);
  ua += 0x7fffu + ((ua>>16)&1u);
  ub += 0x7fffu + ((ub>>16)&1u);
  return (ua>>16) | (ub & 0xffff0000u);
}
__device__ __forceinline__ float bf_lo(unsigned u){ return __uint_as_float(u<<16); }
__device__ __forceinline__ float bf_hi(unsigned u){ return __uint_as_float(u & 0xffff0000u); }

// ---------------- W -> bf16, transposed: Wt[c][kp] = pack(W[2kp][c], W[2kp+1][c])
__global__ __launch_bounds__(256) void wtrans(const float* __restrict__ W,
    unsigned* __restrict__ Wt, int K2, int klog){
  int idx = blockIdx.x*256 + threadIdx.x;
  int c  = idx >> klog;
  int kp = idx & (K2-1);
  if(c < 128){
    float a = W[(size_t)(2*kp)*128 + c];
    float b = W[(size_t)(2*kp+1)*128 + c];
    Wt[(size_t)c*K2 + kp] = pack_bf16(a, b);
  }
}

// ---------------- MFMA GEMM: A[n,K] @ W[K,128] -> bf16-packed out[n][64 uints]
// 128x128 tile, 4 waves, each wave 64x64 via 4x4 frags of 16x16x32 bf16 MFMA.
// AF32=1: A is f32 row-major. AF32=0: A is bf16-packed uint [n][K/2].
template<int AF32>
__global__ __launch_bounds__(256) void gemm_mfma(const void* __restrict__ Aptr,
    const unsigned* __restrict__ Wt, unsigned* __restrict__ outb, int n, int K){
  __shared__ unsigned sA[128][36];   // [row][kpair], 16B pad per row
  __shared__ unsigned sB[128][36];   // [col][kpair]
  int t = threadIdx.x;
  int w = t >> 6, l = t & 63;
  int wr = (w >> 1) * 64, wc = (w & 1) * 64;
  int row0 = blockIdx.x * 128;
  int K2 = K >> 1;

  f32x4 zero4 = {0.f,0.f,0.f,0.f};
  f32x4 acc[4][4];
  #pragma unroll
  for(int i=0;i<4;i++)
    #pragma unroll
    for(int j=0;j<4;j++) acc[i][j] = zero4;

  int sr = t >> 1;            // staging row/col 0..127
  int uh = (t & 1) * 16;      // uint-offset half

  int ktiles = K >> 6;
  for(int kt = 0; kt < ktiles; ++kt){
    // stage A (128 rows x 64 k)
    if(AF32){
      const float* A = (const float*)Aptr;
      int gr = row0 + sr;
      const float* ap = A + (size_t)gr*K + kt*64 + uh*2;
      #pragma unroll
      for(int i=0;i<8;i++){
        float4 v = make_float4(0.f,0.f,0.f,0.f);
        if(gr < n) v = *(const float4*)(ap + i*4);
        sA[sr][uh + i*2]   = pack_bf16(v.x, v.y);
        sA[sr][uh + i*2+1] = pack_bf16(v.z, v.w);
      }
    } else {
      const unsigned* A = (const unsigned*)Aptr;
      int gr = row0 + sr;
      const unsigned* ap = A + (size_t)gr*K2 + kt*32 + uh;
      #pragma unroll
      for(int i=0;i<4;i++){
        uint4 v = make_uint4(0,0,0,0);
        if(gr < n) v = *(const uint4*)(ap + i*4);
        *(uint4*)&sA[sr][uh + i*4] = v;
      }
    }
    // stage B (128 cols x 64 k) from Wt
    {
      const unsigned* wp = Wt + (size_t)sr*K2 + kt*32 + uh;
      #pragma unroll
      for(int i=0;i<4;i++)
        *(uint4*)&sB[sr][uh + i*4] = *(const uint4*)(wp + i*4);
    }
    __syncthreads();
    #pragma unroll
    for(int ks=0; ks<2; ++ks){
      int koff = ks*16 + (l>>4)*4;
      int rl = l & 15;
      bf16x8 a[4], b[4];
      #pragma unroll
      for(int f=0; f<4; f++){
        a[f] = *(const bf16x8*)&sA[wr + f*16 + rl][koff];
        b[f] = *(const bf16x8*)&sB[wc + f*16 + rl][koff];
      }
      #pragma unroll
      for(int i=0;i<4;i++)
        #pragma unroll
        for(int j=0;j<4;j++)
          acc[i][j] = __builtin_amdgcn_mfma_f32_16x16x32_bf16(a[i], b[j], acc[i][j], 0, 0, 0);
    }
    __syncthreads();
  }

  // epilogue: C/D layout col=lane&15, row=(lane>>4)*4+reg; pack col pairs via shfl
  #pragma unroll
  for(int i=0;i<4;i++){
    #pragma unroll
    for(int j=0;j<4;j++){
      #pragma unroll
      for(int g=0;g<4;g++){
        float v  = acc[i][j][g];
        float vp = __shfl_xor(v, 1);
        if(!(l & 1)){
          unsigned pv = pack_bf16(v, vp);
          int grow = row0 + wr + i*16 + (l>>4)*4 + g;
          int gcol = wc + j*16 + (l&15);
          if(grow < n) outb[(size_t)grow*64 + (gcol>>1)] = pv;
        }
      }
    }
  }
}

// ---------------- per-node attention terms el/er from bf16 feat (wave per node)
__global__ __launch_bounds__(256) void elr_kernel(const unsigned* __restrict__ featb,
    const float* __restrict__ al, const float* __restrict__ ar,
    float* __restrict__ el, float* __restrict__ er, int n){
  int wid = (blockIdx.x*blockDim.x + threadIdx.x) >> 6;
  int lane = threadIdx.x & 63;
  if(wid >= n) return;
  unsigned v = featb[(size_t)wid*64 + lane];
  float flo = bf_lo(v);
  float fhi = bf_hi(v);
  float a0 = al[2*lane], a1 = al[2*lane+1];
  float r0 = ar[2*lane], r1 = ar[2*lane+1];
  float pe = flo*a0 + fhi*a1;
  float qe = flo*r0 + fhi*r1;
  pe = half_sum(pe); qe = half_sum(qe);
  float el0 = __shfl(pe, 0),  el1 = __shfl(pe, 32);
  float er0 = __shfl(qe, 0),  er1 = __shfl(qe, 32);
  if(lane == 0){
    *(float2*)&el[(size_t)wid*2] = make_float2(el0, el1);
    *(float2*)&er[(size_t)wid*2] = make_float2(er0, er1);
  }
}

// ================= CSR build: two-level counting sort =================
__global__ __launch_bounds__(256) void csrA(const int* __restrict__ dst,
    int* __restrict__ thist, int E, int nbuck, int ntiles){
  __shared__ int h[512];
  int t = threadIdx.x;
  if(t < nbuck) h[t] = 0;
  __syncthreads();
  int base = blockIdx.x * CSR_TILE;
  for(int k = 0; k < CSR_TILE/256; ++k){
    int e = base + k*256 + t;
    if(e < E) atomicAdd(&h[dst[e] >> NBUCK_SH], 1);
  }
  __syncthreads();
  if(t < nbuck) thist[blockIdx.x*nbuck + t] = h[t];
}

__global__ __launch_bounds__(512) void csrB1(const int* __restrict__ thist,
    int* __restrict__ off, int* __restrict__ btotal, int nbuck, int ntiles){
  __shared__ int ls[512];
  int t = threadIdx.x;
  int b = blockIdx.x;
  int v = (t < ntiles) ? thist[(size_t)t*nbuck + b] : 0;
  ls[t] = v; __syncthreads();
  for(int o=1;o<512;o<<=1){
    int x = (t>=o) ? ls[t-o] : 0;
    __syncthreads();
    ls[t] += x;
    __syncthreads();
  }
  if(t < ntiles) off[(size_t)b*ntiles + t] = ls[t] - v;
  if(t == 511) btotal[b] = ls[511];
}

__global__ __launch_bounds__(256) void csrB2(const int* __restrict__ btotal,
    int* __restrict__ bbase, int nbuck, int E){
  __shared__ int ls[256];
  int t = threadIdx.x;
  int v = (t < nbuck) ? btotal[t] : 0;
  ls[t] = v; __syncthreads();
  for(int o=1;o<256;o<<=1){
    int x = (t>=o) ? ls[t-o] : 0;
    __syncthreads();
    ls[t] += x;
    __syncthreads();
  }
  if(t < nbuck) bbase[t] = ls[t] - v;
  if(t == 0) bbase[nbuck] = E;
}

__global__ __launch_bounds__(256) void csrC(const int* __restrict__ src,
    const int* __restrict__ dst, const int* __restrict__ off,
    const int* __restrict__ bbase, unsigned* __restrict__ tmp,
    int E, int nbuck, int ntiles){
  __shared__ int basel[512];
  __shared__ int cnt[512];
  int t = threadIdx.x;
  int tile = blockIdx.x;
  if(t < nbuck){
    basel[t] = bbase[t] + off[(size_t)t*ntiles + tile];
    cnt[t] = 0;
  }
  __syncthreads();
  int base = tile * CSR_TILE;
  for(int k = 0; k < CSR_TILE/256; ++k){
    int e = base + k*256 + t;
    if(e < E){
      int d = dst[e];
      int s = src[e];
      int b = d >> NBUCK_SH;
      int r = atomicAdd(&cnt[b], 1);
      tmp[basel[b] + r] = (unsigned)s | ((unsigned)(d & ((1<<NBUCK_SH)-1)) << 17);
    }
  }
}

__global__ __launch_bounds__(512) void csrD(const unsigned* __restrict__ tmp,
    const int* __restrict__ bbase, int* __restrict__ rowptr,
    int* __restrict__ esrc, int N, int E, int nbuck){
  __shared__ int hist[512];
  __shared__ int ls[512];
  int t = threadIdx.x;
  int b = blockIdx.x;
  int base = bbase[b];
  int cnt  = bbase[b+1] - base;
  int n0   = b << NBUCK_SH;
  int nn   = min(512, N - n0);
  hist[t] = 0;
  __syncthreads();
  for(int i = t; i < cnt; i += 512)
    atomicAdd(&hist[tmp[base+i] >> 17], 1);
  __syncthreads();
  int v = hist[t];
  ls[t] = v; __syncthreads();
  for(int o=1;o<512;o<<=1){
    int x = (t>=o) ? ls[t-o] : 0;
    __syncthreads();
    ls[t] += x;
    __syncthreads();
  }
  int rp = ls[t] - v;
  if(t < nn) rowptr[n0 + t] = base + rp;
  if(b == nbuck-1 && t == 0) rowptr[N] = E;
  __syncthreads();
  hist[t] = rp;
  __syncthreads();
  for(int i = t; i < cnt; i += 512){
    unsigned v2 = tmp[base+i];
    int dl = v2 >> 17;
    int s  = v2 & 0x1FFFF;
    int r  = atomicAdd(&hist[dl], 1);
    esrc[base + r] = s;
  }
}

// ---------------- GAT aggregation: wave per dst node, bf16 gather -> bf16 out
__global__ __launch_bounds__(256) void agg_kernel(const unsigned* __restrict__ featb,
    const float* __restrict__ el, const float* __restrict__ er,
    const int* __restrict__ rowptr, const int* __restrict__ esrc,
    const float* __restrict__ bias, unsigned* __restrict__ outp, int n){
  int wid = (blockIdx.x*blockDim.x + threadIdx.x) >> 6;
  int lane = threadIdx.x & 63;
  if(wid >= n) return;
  int beg = rowptr[wid], end = rowptr[wid+1];
  float2 erd = *(const float2*)&er[(size_t)wid*2];

  float d0 = 0.f, d1 = 0.f;
  for(int base = beg; base < end; base += 64){
    int idx = base + lane;
    int s = (idx < end) ? esrc[idx] : 0;
    float2 elv = *(const float2*)&el[(size_t)s*2];
    float e0 = elv.x + erd.x, e1 = elv.y + erd.y;
    e0 = (e0 >= 0.f) ? e0 : SLOPE*e0;
    e1 = (e1 >= 0.f) ? e1 : SLOPE*e1;
    float p0 = __expf(e0), p1 = __expf(e1);
    if(idx >= end){ p0 = 0.f; p1 = 0.f; }
    d0 += p0; d1 += p1;
  }
  d0 = wave_sum(d0); d1 = wave_sum(d1);
  float inv0 = 1.0f / fmaxf(d0, 1e-16f);
  float inv1 = 1.0f / fmaxf(d1, 1e-16f);

  float acc0 = 0.f, acc1 = 0.f;
  const unsigned* fb = featb + lane;
  for(int base = beg; base < end; base += 64){
    int idx = base + lane;
    int s = (idx < end) ? esrc[idx] : 0;
    float2 elv = *(const float2*)&el[(size_t)s*2];
    float e0 = elv.x + erd.x, e1 = elv.y + erd.y;
    e0 = (e0 >= 0.f) ? e0 : SLOPE*e0;
    e1 = (e1 >= 0.f) ? e1 : SLOPE*e1;
    float w0 = __expf(e0) * inv0;
    float w1 = __expf(e1) * inv1;
    int nval = min(64, end - base);
    for(int e = 0; e < nval; ++e){
      int   se  = __shfl(s,  e);
      float w0e = __shfl(w0, e);
      float w1e = __shfl(w1, e);
      float w   = (lane < 32) ? w0e : w1e;
      unsigned v = fb[(size_t)se*64];
      acc0 += bf_lo(v) * w;
      acc1 += bf_hi(v) * w;
    }
  }
  float2 bb = *(const float2*)&bias[2*lane];
  outp[(size_t)wid*64 + lane] =
      pack_bf16(fmaxf(acc0 + bb.x, 0.f), fmaxf(acc1 + bb.y, 0.f));
}

// ---------------- head: relu(h@Wout+bout) @ Wfc + bfc   (h is bf16-packed)
__global__ __launch_bounds__(256) void head_kernel(const unsigned* __restrict__ h,
    const float* __restrict__ Wout, const float* __restrict__ bout,
    const float* __restrict__ Wfc, const float* __restrict__ bfc,
    float* __restrict__ hfc, int n){
  __shared__ float sAT[32][68];
  __shared__ float sWo[32][68];
  __shared__ float sOT[64][68];
  __shared__ float sF [64][68];
  int t = threadIdx.x;
  int cx = t & 15;
  int ry = t >> 4;
  int row0 = blockIdx.x * 64;

  {
    int kr = t >> 4;
    int c0 = (t & 15) * 4;
    #pragma unroll
    for(int i=0;i<4;i++)
      *(float4*)&sF[kr+i*16][c0] = *(const float4*)&Wfc[(size_t)(kr+i*16)*64 + c0];
  }

  float acc[4][4] = {};
  for(int k0 = 0; k0 < 128; k0 += 32){
    #pragma unroll
    for(int u=0;u<2;u++){
      int f4 = t*2 + u;
      int r  = f4 >> 3;
      int kc = (f4 & 7) * 4;
      int gr = row0 + r;
      uint2 v = make_uint2(0,0);
      if(gr < n) v = *(const uint2*)&h[(size_t)gr*64 + ((k0+kc)>>1)];
      sAT[kc+0][r] = bf_lo(v.x);
      sAT[kc+1][r] = bf_hi(v.x);
      sAT[kc+2][r] = bf_lo(v.y);
      sAT[kc+3][r] = bf_hi(v.y);
    }
    #pragma unroll
    for(int u=0;u<2;u++){
      int f4 = t*2 + u;
      int kr = f4 >> 4;
      int c0 = (f4 & 15) * 4;
      *(float4*)&sWo[kr][c0] = *(const float4*)&Wout[(size_t)(k0+kr)*64 + c0];
    }
    __syncthreads();
    #pragma unroll 8
    for(int kk = 0; kk < 32; ++kk){
      float4 a4 = *(const float4*)&sAT[kk][ry*4];
      float4 b4 = *(const float4*)&sWo[kk][cx*4];
      float a[4] = {a4.x,a4.y,a4.z,a4.w};
      float b[4] = {b4.x,b4.y,b4.z,b4.w};
      #pragma unroll
      for(int i=0;i<4;i++)
        #pragma unroll
        for(int j=0;j<4;j++) acc[i][j] += a[i]*b[j];
    }
    __syncthreads();
  }
  {
    float4 bb = *(const float4*)&bout[cx*4];
    float bv[4] = {bb.x,bb.y,bb.z,bb.w};
    #pragma unroll
    for(int i=0;i<4;i++)
      #pragma unroll
      for(int j=0;j<4;j++)
        sOT[cx*4+j][ry*4+i] = fmaxf(acc[i][j] + bv[j], 0.f);
  }
  __syncthreads();
  float acc2[4][4] = {};
  #pragma unroll 8
  for(int kk = 0; kk < 64; ++kk){
    float4 a4 = *(const float4*)&sOT[kk][ry*4];
    float4 b4 = *(const float4*)&sF [kk][cx*4];
    float a[4] = {a4.x,a4.y,a4.z,a4.w};
    float b[4] = {b4.x,b4.y,b4.z,b4.w};
    #pragma unroll
    for(int i=0;i<4;i++)
      #pragma unroll
      for(int j=0;j<4;j++) acc2[i][j] += a[i]*b[j];
  }
  {
    float4 bb = *(const float4*)&bfc[cx*4];
    #pragma unroll
    for(int i=0;i<4;i++){
      int gr = row0 + ry*4 + i;
      if(gr < n){
        float4 o = make_float4(acc2[i][0]+bb.x, acc2[i][1]+bb.y,
                               acc2[i][2]+bb.z, acc2[i][3]+bb.w);
        *(float4*)&hfc[(size_t)gr*64 + cx*4] = o;
      }
    }
  }
}

// ---------------- BN stats (two-stage, deterministic)
__global__ __launch_bounds__(256) void bn_stats(const float* __restrict__ hfc,
    float* __restrict__ psum, float* __restrict__ psum2, int n){
  int t = threadIdx.x; int c = t & 63; int g = t >> 6;
  int rpb = (n + gridDim.x - 1) / gridDim.x;
  int r0 = blockIdx.x * rpb;
  int r1 = min(n, r0 + rpb);
  float s = 0.f, s2 = 0.f;
  for(int r = r0 + g; r < r1; r += 4){
    float v = hfc[(size_t)r*64 + c];
    s += v; s2 += v*v;
  }
  __shared__ float ls[256], ls2[256];
  ls[t]=s; ls2[t]=s2; __syncthreads();
  if(t < 64){
    s  = ls[t]+ls[t+64]+ls[t+128]+ls[t+192];
    s2 = ls2[t]+ls2[t+64]+ls2[t+128]+ls2[t+192];
    psum[blockIdx.x*64 + t]  = s;
    psum2[blockIdx.x*64 + t] = s2;
  }
}

__global__ __launch_bounds__(64) void bn_fin(const float* __restrict__ psum,
    const float* __restrict__ psum2, const float* __restrict__ gamma,
    const float* __restrict__ beta, float* __restrict__ scsh, int n, int nb){
  int c = threadIdx.x;
  float s=0.f, s2=0.f;
  for(int b=0;b<nb;b++){ s += psum[b*64+c]; s2 += psum2[b*64+c]; }
  float mu  = s / n;
  float var = s2 / n - mu*mu;
  float scale = rsqrtf(var + BN_EPS) * gamma[c];
  scsh[c]    = scale;
  scsh[64+c] = beta[c] - mu*scale;
}

// ---------------- BN apply + row softmax -> p
__global__ __launch_bounds__(256) void bn_softmax(const float* __restrict__ hfc,
    const float* __restrict__ scsh, float* __restrict__ p, int n){
  int wid = (blockIdx.x*blockDim.x + threadIdx.x) >> 6;
  int lane = threadIdx.x & 63;
  if(wid >= n) return;
  float y = hfc[(size_t)wid*64 + lane]*scsh[lane] + scsh[64+lane];
  float m = wave_max(y);
  float e = expf(y - m);
  float s = wave_sum(e);
  p[(size_t)wid*64 + lane] = e / s;
}

// ---------------- loss
__global__ __launch_bounds__(256) void loss1(const float* __restrict__ p,
    const int* __restrict__ train, const int* __restrict__ label,
    float* __restrict__ part, int ntrain){
  int lane = threadIdx.x & 63; int w = threadIdx.x >> 6;
  int gw = blockIdx.x*4 + w; int nw = gridDim.x*4;
  float acc = 0.f;
  for(int t = gw; t < ntrain; t += nw){
    int node = train[t];
    float v = p[(size_t)node*64 + lane];
    float m = wave_max(v);
    float e = expf(v - m);
    float s = wave_sum(e);
    float logp = (v - m) - logf(s);
    int lab = label[node];
    if(lane == lab) acc += logp;
  }
  acc = wave_sum(acc);
  __shared__ float ls[4];
  if(lane == 0) ls[w] = acc;
  __syncthreads();
  if(threadIdx.x == 0) part[blockIdx.x] = ls[0]+ls[1]+ls[2]+ls[3];
}

__global__ void loss2(const float* __restrict__ part, float* __restrict__ out,
                      int nb, int ntrain){
  if(threadIdx.x == 0){
    float s = 0.f;
    for(int i=0;i<nb;i++) s += part[i];
    out[0] = -s / (float)ntrain;
  }
}

extern "C" void kernel_launch(void* const* d_in, const int* in_sizes, int n_in,
                              void* d_out, int out_size, void* d_ws, size_t ws_size,
                              hipStream_t stream){
  const float* feature = (const float*)d_in[0];
  const int*   label   = (const int*)d_in[1];
  const int*   train   = (const int*)d_in[2];
  const int*   src     = (const int*)d_in[3];
  const int*   dst     = (const int*)d_in[4];
  const float* W0   = (const float*)d_in[5];
  const float* al0  = (const float*)d_in[6];
  const float* ar0  = (const float*)d_in[7];
  const float* b0   = (const float*)d_in[8];
  const float* W1   = (const float*)d_in[9];
  const float* al1  = (const float*)d_in[10];
  const float* ar1  = (const float*)d_in[11];
  const float* b1   = (const float*)d_in[12];
  const float* Wout = (const float*)d_in[13];
  const float* bout = (const float*)d_in[14];
  const float* Wfc  = (const float*)d_in[15];
  const float* bfc  = (const float*)d_in[16];
  const float* gamma= (const float*)d_in[17];
  const float* beta = (const float*)d_in[18];

  const int N  = in_sizes[1];
  const int NT = in_sizes[2];
  const int E  = in_sizes[3];

  const int nbuck  = (N + (1<<NBUCK_SH) - 1) >> NBUCK_SH;
  const int ntiles = (E + CSR_TILE - 1) / CSR_TILE;

  size_t off = 0;
  auto alloc = [&](size_t bytes)->void*{
    void* pp = (char*)d_ws + off;
    off += (bytes + 255) & ~(size_t)255;
    return pp;
  };
  unsigned* featb16 = (unsigned*)alloc((size_t)N*64*4);  // gemm outputs (bf16 packed)
  unsigned* hbuf2   = (unsigned*)alloc((size_t)N*64*4);  // agg outputs (bf16 packed)
  float* el      = (float*)alloc((size_t)N*2*4);
  float* er      = (float*)alloc((size_t)N*2*4);
  int*   rowptr  = (int*)alloc((size_t)(N+1)*4);
  int*   esrc    = (int*)alloc((size_t)E*4);
  int*   thist   = (int*)alloc((size_t)ntiles*nbuck*4);
  int*   offarr  = (int*)alloc((size_t)nbuck*ntiles*4);
  int*   btotal  = (int*)alloc((size_t)nbuck*4);
  int*   bbase   = (int*)alloc((size_t)(nbuck+1)*4);
  unsigned* Wt0  = (unsigned*)alloc((size_t)128*128*4);
  unsigned* Wt1  = (unsigned*)alloc((size_t)128*64*4);
  float* psum    = (float*)alloc((size_t)256*64*4);
  float* psum2   = (float*)alloc((size_t)256*64*4);
  float* scsh    = (float*)alloc(128*4);
  float* lpart   = (float*)alloc(256*4);
  float* hfc     = (float*)featb16;   // reuse: featb16 dead after agg L1
  unsigned* tmp  = hbuf2;             // reuse: hbuf2 first written by agg L0 (after csrD)

  float* p_out   = (float*)d_out;
  float* loss_out= (float*)d_out + (size_t)N*64;

  const int nwaveblk = (N + 3) / 4;

  // ---- weight prep (bf16, transposed)
  wtrans<<<64, 256, 0, stream>>>(W0, Wt0, 128, 7);
  wtrans<<<32, 256, 0, stream>>>(W1, Wt1, 64, 6);

  // ---- CSR build (two-level counting sort)
  csrA<<<ntiles, 256, 0, stream>>>(dst, thist, E, nbuck, ntiles);
  csrB1<<<nbuck, 512, 0, stream>>>(thist, offarr, btotal, nbuck, ntiles);
  csrB2<<<1, 256, 0, stream>>>(btotal, bbase, nbuck, E);
  csrC<<<ntiles, 256, 0, stream>>>(src, dst, offarr, bbase, tmp, E, nbuck, ntiles);
  csrD<<<nbuck, 512, 0, stream>>>(tmp, bbase, rowptr, esrc, N, E, nbuck);

  // ---- layer 0
  gemm_mfma<1><<<(N+127)/128, 256, 0, stream>>>(feature, Wt0, featb16, N, 256);
  elr_kernel<<<nwaveblk, 256, 0, stream>>>(featb16, al0, ar0, el, er, N);
  agg_kernel<<<nwaveblk, 256, 0, stream>>>(featb16, el, er, rowptr, esrc, b0, hbuf2, N);

  // ---- layer 1
  gemm_mfma<0><<<(N+127)/128, 256, 0, stream>>>(hbuf2, Wt1, featb16, N, 128);
  elr_kernel<<<nwaveblk, 256, 0, stream>>>(featb16, al1, ar1, el, er, N);
  agg_kernel<<<nwaveblk, 256, 0, stream>>>(featb16, el, er, rowptr, esrc, b1, hbuf2, N);

  // ---- dense head
  head_kernel<<<(N+63)/64, 256, 0, stream>>>(hbuf2, Wout, bout, Wfc, bfc, hfc, N);

  // ---- batchnorm
  bn_stats<<<256, 256, 0, stream>>>(hfc, psum, psum2, N);
  bn_fin<<<1, 64, 0, stream>>>(psum, psum2, gamma, beta, scsh, N, 256);
  bn_softmax<<<nwaveblk, 256, 0, stream>>>(hfc, scsh, p_out, N);

  // ---- loss
  loss1<<<40, 256, 0, stream>>>(p_out, train, label, lpart, NT);
  loss2<<<1, 64, 0, stream>>>(lpart, loss_out, 40, NT);
}

// Round 7
// 500.295 us; speedup vs baseline: 2.5991x; 1.2113x over previous
//
#include <hip/hip_runtime.h>

#define SLOPE 0.2f
#define BN_EPS 1e-5f

#define CSR_TILE 4096       // edges per tile (phase A/C)
#define NBUCK_SH 9          // bucket = dst >> 9  (512 nodes per bucket)

typedef __attribute__((ext_vector_type(8))) short bf16x8;
typedef __attribute__((ext_vector_type(4))) float f32x4;

__device__ __forceinline__ float wave_sum(float v){
  #pragma unroll
  for(int o=32;o;o>>=1) v += __shfl_xor(v,o);
  return v;
}
__device__ __forceinline__ float wave_max(float v){
  #pragma unroll
  for(int o=32;o;o>>=1) v = fmaxf(v,__shfl_xor(v,o));
  return v;
}
__device__ __forceinline__ float half_sum(float v){
  #pragma unroll
  for(int o=16;o;o>>=1) v += __shfl_xor(v,o);
  return v;
}
__device__ __forceinline__ unsigned pack_bf16(float a, float b){
  unsigned ua=__float_as_uint(a), ub=__float_as_uint(b);
  ua += 0x7fffu + ((ua>>16)&1u);
  ub += 0x7fffu + ((ub>>16)&1u);
  return (ua>>16) | (ub & 0xffff0000u);
}
__device__ __forceinline__ float bf_lo(unsigned u){ return __uint_as_float(u<<16); }
__device__ __forceinline__ float bf_hi(unsigned u){ return __uint_as_float(u & 0xffff0000u); }

// ---------------- W -> bf16, transposed: Wt[c][kp] = pack(W[2kp][c], W[2kp+1][c])
__global__ __launch_bounds__(256) void wtrans(const float* __restrict__ W,
    unsigned* __restrict__ Wt, int K2, int klog){
  int idx = blockIdx.x*256 + threadIdx.x;
  int c  = idx >> klog;
  int kp = idx & (K2-1);
  if(c < 128){
    float a = W[(size_t)(2*kp)*128 + c];
    float b = W[(size_t)(2*kp+1)*128 + c];
    Wt[(size_t)c*K2 + kp] = pack_bf16(a, b);
  }
}

// ---------------- MFMA GEMM: A[n,K] @ W[K,128] -> bf16-packed out[n][64 uints]
template<int AF32>
__global__ __launch_bounds__(256) void gemm_mfma(const void* __restrict__ Aptr,
    const unsigned* __restrict__ Wt, unsigned* __restrict__ outb, int n, int K){
  __shared__ unsigned sA[128][36];   // [row][kpair], 16B pad per row
  __shared__ unsigned sB[128][36];   // [col][kpair]
  int t = threadIdx.x;
  int w = t >> 6, l = t & 63;
  int wr = (w >> 1) * 64, wc = (w & 1) * 64;
  int row0 = blockIdx.x * 128;
  int K2 = K >> 1;

  f32x4 zero4 = {0.f,0.f,0.f,0.f};
  f32x4 acc[4][4];
  #pragma unroll
  for(int i=0;i<4;i++)
    #pragma unroll
    for(int j=0;j<4;j++) acc[i][j] = zero4;

  int sr = t >> 1;
  int uh = (t & 1) * 16;

  int ktiles = K >> 6;
  for(int kt = 0; kt < ktiles; ++kt){
    if(AF32){
      const float* A = (const float*)Aptr;
      int gr = row0 + sr;
      const float* ap = A + (size_t)gr*K + kt*64 + uh*2;
      #pragma unroll
      for(int i=0;i<8;i++){
        float4 v = make_float4(0.f,0.f,0.f,0.f);
        if(gr < n) v = *(const float4*)(ap + i*4);
        sA[sr][uh + i*2]   = pack_bf16(v.x, v.y);
        sA[sr][uh + i*2+1] = pack_bf16(v.z, v.w);
      }
    } else {
      const unsigned* A = (const unsigned*)Aptr;
      int gr = row0 + sr;
      const unsigned* ap = A + (size_t)gr*K2 + kt*32 + uh;
      #pragma unroll
      for(int i=0;i<4;i++){
        uint4 v = make_uint4(0,0,0,0);
        if(gr < n) v = *(const uint4*)(ap + i*4);
        *(uint4*)&sA[sr][uh + i*4] = v;
      }
    }
    {
      const unsigned* wp = Wt + (size_t)sr*K2 + kt*32 + uh;
      #pragma unroll
      for(int i=0;i<4;i++)
        *(uint4*)&sB[sr][uh + i*4] = *(const uint4*)(wp + i*4);
    }
    __syncthreads();
    #pragma unroll
    for(int ks=0; ks<2; ++ks){
      int koff = ks*16 + (l>>4)*4;
      int rl = l & 15;
      bf16x8 a[4], b[4];
      #pragma unroll
      for(int f=0; f<4; f++){
        a[f] = *(const bf16x8*)&sA[wr + f*16 + rl][koff];
        b[f] = *(const bf16x8*)&sB[wc + f*16 + rl][koff];
      }
      #pragma unroll
      for(int i=0;i<4;i++)
        #pragma unroll
        for(int j=0;j<4;j++)
          acc[i][j] = __builtin_amdgcn_mfma_f32_16x16x32_bf16(a[i], b[j], acc[i][j], 0, 0, 0);
    }
    __syncthreads();
  }

  #pragma unroll
  for(int i=0;i<4;i++){
    #pragma unroll
    for(int j=0;j<4;j++){
      #pragma unroll
      for(int g=0;g<4;g++){
        float v  = acc[i][j][g];
        float vp = __shfl_xor(v, 1);
        if(!(l & 1)){
          unsigned pv = pack_bf16(v, vp);
          int grow = row0 + wr + i*16 + (l>>4)*4 + g;
          int gcol = wc + j*16 + (l&15);
          if(grow < n) outb[(size_t)grow*64 + (gcol>>1)] = pv;
        }
      }
    }
  }
}

// ---------------- per-node attention terms el/er from bf16 feat (wave per node)
__global__ __launch_bounds__(256) void elr_kernel(const unsigned* __restrict__ featb,
    const float* __restrict__ al, const float* __restrict__ ar,
    float* __restrict__ el, float* __restrict__ er, int n){
  int wid = (blockIdx.x*blockDim.x + threadIdx.x) >> 6;
  int lane = threadIdx.x & 63;
  if(wid >= n) return;
  unsigned v = featb[(size_t)wid*64 + lane];
  float flo = bf_lo(v);
  float fhi = bf_hi(v);
  float a0 = al[2*lane], a1 = al[2*lane+1];
  float r0 = ar[2*lane], r1 = ar[2*lane+1];
  float pe = flo*a0 + fhi*a1;
  float qe = flo*r0 + fhi*r1;
  pe = half_sum(pe); qe = half_sum(qe);
  float el0 = __shfl(pe, 0),  el1 = __shfl(pe, 32);
  float er0 = __shfl(qe, 0),  er1 = __shfl(qe, 32);
  if(lane == 0){
    *(float2*)&el[(size_t)wid*2] = make_float2(el0, el1);
    *(float2*)&er[(size_t)wid*2] = make_float2(er0, er1);
  }
}

// ================= CSR build: two-level counting sort =================
__global__ __launch_bounds__(256) void csrA(const int* __restrict__ dst,
    int* __restrict__ thist, int E, int nbuck, int ntiles){
  __shared__ int h[512];
  int t = threadIdx.x;
  if(t < nbuck) h[t] = 0;
  __syncthreads();
  int base = blockIdx.x * CSR_TILE;
  for(int k = 0; k < CSR_TILE/256; ++k){
    int e = base + k*256 + t;
    if(e < E) atomicAdd(&h[dst[e] >> NBUCK_SH], 1);
  }
  __syncthreads();
  if(t < nbuck) thist[blockIdx.x*nbuck + t] = h[t];
}

__global__ __launch_bounds__(512) void csrB1(const int* __restrict__ thist,
    int* __restrict__ off, int* __restrict__ btotal, int nbuck, int ntiles){
  __shared__ int ls[512];
  int t = threadIdx.x;
  int b = blockIdx.x;
  int v = (t < ntiles) ? thist[(size_t)t*nbuck + b] : 0;
  ls[t] = v; __syncthreads();
  for(int o=1;o<512;o<<=1){
    int x = (t>=o) ? ls[t-o] : 0;
    __syncthreads();
    ls[t] += x;
    __syncthreads();
  }
  if(t < ntiles) off[(size_t)b*ntiles + t] = ls[t] - v;
  if(t == 511) btotal[b] = ls[511];
}

__global__ __launch_bounds__(256) void csrB2(const int* __restrict__ btotal,
    int* __restrict__ bbase, int nbuck, int E){
  __shared__ int ls[256];
  int t = threadIdx.x;
  int v = (t < nbuck) ? btotal[t] : 0;
  ls[t] = v; __syncthreads();
  for(int o=1;o<256;o<<=1){
    int x = (t>=o) ? ls[t-o] : 0;
    __syncthreads();
    ls[t] += x;
    __syncthreads();
  }
  if(t < nbuck) bbase[t] = ls[t] - v;
  if(t == 0) bbase[nbuck] = E;
}

__global__ __launch_bounds__(256) void csrC(const int* __restrict__ src,
    const int* __restrict__ dst, const int* __restrict__ off,
    const int* __restrict__ bbase, unsigned* __restrict__ tmp,
    int E, int nbuck, int ntiles){
  __shared__ int basel[512];
  __shared__ int cnt[512];
  int t = threadIdx.x;
  int tile = blockIdx.x;
  if(t < nbuck){
    basel[t] = bbase[t] + off[(size_t)t*ntiles + tile];
    cnt[t] = 0;
  }
  __syncthreads();
  int base = tile * CSR_TILE;
  for(int k = 0; k < CSR_TILE/256; ++k){
    int e = base + k*256 + t;
    if(e < E){
      int d = dst[e];
      int s = src[e];
      int b = d >> NBUCK_SH;
      int r = atomicAdd(&cnt[b], 1);
      tmp[basel[b] + r] = (unsigned)s | ((unsigned)(d & ((1<<NBUCK_SH)-1)) << 17);
    }
  }
}

__global__ __launch_bounds__(512) void csrD(const unsigned* __restrict__ tmp,
    const int* __restrict__ bbase, int* __restrict__ rowptr,
    int* __restrict__ esrc, int N, int E, int nbuck){
  __shared__ int hist[512];
  __shared__ int ls[512];
  int t = threadIdx.x;
  int b = blockIdx.x;
  int base = bbase[b];
  int cnt  = bbase[b+1] - base;
  int n0   = b << NBUCK_SH;
  int nn   = min(512, N - n0);
  hist[t] = 0;
  __syncthreads();
  for(int i = t; i < cnt; i += 512)
    atomicAdd(&hist[tmp[base+i] >> 17], 1);
  __syncthreads();
  int v = hist[t];
  ls[t] = v; __syncthreads();
  for(int o=1;o<512;o<<=1){
    int x = (t>=o) ? ls[t-o] : 0;
    __syncthreads();
    ls[t] += x;
    __syncthreads();
  }
  int rp = ls[t] - v;
  if(t < nn) rowptr[n0 + t] = base + rp;
  if(b == nbuck-1 && t == 0) rowptr[N] = E;
  __syncthreads();
  hist[t] = rp;
  __syncthreads();
  for(int i = t; i < cnt; i += 512){
    unsigned v2 = tmp[base+i];
    int dl = v2 >> 17;
    int s  = v2 & 0x1FFFF;
    int r  = atomicAdd(&hist[dl], 1);
    esrc[base + r] = s;
  }
}

// ---- chunk accumulator: broadcast (s, packed-weight) from lane e, 8 gathers in flight
__device__ __forceinline__ void agg_chunk(const unsigned* __restrict__ fb,
    int s, unsigned wp, int nval, int lane, float& acc0, float& acc1){
  for(int e = 0; e < nval; e += 8){
    unsigned v[8]; float w[8];
    #pragma unroll
    for(int u=0;u<8;u++){
      int ei = e + u;
      int sl = (ei < nval) ? ei : 0;
      int se = __shfl(s, sl);
      unsigned wpe = __shfl(wp, sl);
      float wu = (lane < 32) ? bf_lo(wpe) : bf_hi(wpe);
      if(ei >= nval) wu = 0.f;
      w[u] = wu;
      v[u] = fb[(size_t)se*64];
    }
    #pragma unroll
    for(int u=0;u<8;u++){
      acc0 += bf_lo(v[u]) * w[u];
      acc1 += bf_hi(v[u]) * w[u];
    }
  }
}

// ---------------- GAT aggregation: wave per dst node, bf16 gather -> bf16 out
__global__ __launch_bounds__(256) void agg_kernel(const unsigned* __restrict__ featb,
    const float* __restrict__ el, const float* __restrict__ er,
    const int* __restrict__ rowptr, const int* __restrict__ esrc,
    const float* __restrict__ bias, unsigned* __restrict__ outp, int n){
  int wid = (blockIdx.x*blockDim.x + threadIdx.x) >> 6;
  int lane = threadIdx.x & 63;
  if(wid >= n) return;
  int beg = rowptr[wid], end = rowptr[wid+1];
  int deg = end - beg;
  float2 erd = *(const float2*)&er[(size_t)wid*2];
  const unsigned* fb = featb + lane;
  float acc0 = 0.f, acc1 = 0.f;

  if(deg <= 64){
    // single chunk: weights stay in registers from the denominator pass
    int s = (lane < deg) ? esrc[beg + lane] : 0;
    float2 elv = *(const float2*)&el[(size_t)s*2];
    float e0 = elv.x + erd.x, e1 = elv.y + erd.y;
    e0 = (e0 >= 0.f) ? e0 : SLOPE*e0;
    e1 = (e1 >= 0.f) ? e1 : SLOPE*e1;
    float p0 = __expf(e0), p1 = __expf(e1);
    if(lane >= deg){ p0 = 0.f; p1 = 0.f; }
    float d0 = wave_sum(p0), d1 = wave_sum(p1);
    float w0 = p0 / fmaxf(d0, 1e-16f);
    float w1 = p1 / fmaxf(d1, 1e-16f);
    unsigned wp = pack_bf16(w0, w1);
    agg_chunk(fb, s, wp, deg, lane, acc0, acc1);
  } else {
    // pass 1: denominators
    float d0 = 0.f, d1 = 0.f;
    for(int base = beg; base < end; base += 64){
      int idx = base + lane;
      int s = (idx < end) ? esrc[idx] : 0;
      float2 elv = *(const float2*)&el[(size_t)s*2];
      float e0 = elv.x + erd.x, e1 = elv.y + erd.y;
      e0 = (e0 >= 0.f) ? e0 : SLOPE*e0;
      e1 = (e1 >= 0.f) ? e1 : SLOPE*e1;
      float p0 = __expf(e0), p1 = __expf(e1);
      if(idx >= end){ p0 = 0.f; p1 = 0.f; }
      d0 += p0; d1 += p1;
    }
    d0 = wave_sum(d0); d1 = wave_sum(d1);
    float inv0 = 1.0f / fmaxf(d0, 1e-16f);
    float inv1 = 1.0f / fmaxf(d1, 1e-16f);
    // pass 2: per-chunk weights + accumulation
    for(int base = beg; base < end; base += 64){
      int idx = base + lane;
      int s = (idx < end) ? esrc[idx] : 0;
      float2 elv = *(const float2*)&el[(size_t)s*2];
      float e0 = elv.x + erd.x, e1 = elv.y + erd.y;
      e0 = (e0 >= 0.f) ? e0 : SLOPE*e0;
      e1 = (e1 >= 0.f) ? e1 : SLOPE*e1;
      float w0 = __expf(e0) * inv0;
      float w1 = __expf(e1) * inv1;
      unsigned wp = pack_bf16(w0, w1);
      agg_chunk(fb, s, wp, min(64, end - base), lane, acc0, acc1);
    }
  }
  float2 bb = *(const float2*)&bias[2*lane];
  outp[(size_t)wid*64 + lane] =
      pack_bf16(fmaxf(acc0 + bb.x, 0.f), fmaxf(acc1 + bb.y, 0.f));
}

// ---------------- head: relu(h@Wout+bout) @ Wfc + bfc   (h is bf16-packed)
__global__ __launch_bounds__(256) void head_kernel(const unsigned* __restrict__ h,
    const float* __restrict__ Wout, const float* __restrict__ bout,
    const float* __restrict__ Wfc, const float* __restrict__ bfc,
    float* __restrict__ hfc, int n){
  __shared__ float sAT[32][68];
  __shared__ float sWo[32][68];
  __shared__ float sOT[64][68];
  __shared__ float sF [64][68];
  int t = threadIdx.x;
  int cx = t & 15;
  int ry = t >> 4;
  int row0 = blockIdx.x * 64;

  {
    int kr = t >> 4;
    int c0 = (t & 15) * 4;
    #pragma unroll
    for(int i=0;i<4;i++)
      *(float4*)&sF[kr+i*16][c0] = *(const float4*)&Wfc[(size_t)(kr+i*16)*64 + c0];
  }

  float acc[4][4] = {};
  for(int k0 = 0; k0 < 128; k0 += 32){
    #pragma unroll
    for(int u=0;u<2;u++){
      int f4 = t*2 + u;
      int r  = f4 >> 3;
      int kc = (f4 & 7) * 4;
      int gr = row0 + r;
      uint2 v = make_uint2(0,0);
      if(gr < n) v = *(const uint2*)&h[(size_t)gr*64 + ((k0+kc)>>1)];
      sAT[kc+0][r] = bf_lo(v.x);
      sAT[kc+1][r] = bf_hi(v.x);
      sAT[kc+2][r] = bf_lo(v.y);
      sAT[kc+3][r] = bf_hi(v.y);
    }
    #pragma unroll
    for(int u=0;u<2;u++){
      int f4 = t*2 + u;
      int kr = f4 >> 4;
      int c0 = (f4 & 15) * 4;
      *(float4*)&sWo[kr][c0] = *(const float4*)&Wout[(size_t)(k0+kr)*64 + c0];
    }
    __syncthreads();
    #pragma unroll 8
    for(int kk = 0; kk < 32; ++kk){
      float4 a4 = *(const float4*)&sAT[kk][ry*4];
      float4 b4 = *(const float4*)&sWo[kk][cx*4];
      float a[4] = {a4.x,a4.y,a4.z,a4.w};
      float b[4] = {b4.x,b4.y,b4.z,b4.w};
      #pragma unroll
      for(int i=0;i<4;i++)
        #pragma unroll
        for(int j=0;j<4;j++) acc[i][j] += a[i]*b[j];
    }
    __syncthreads();
  }
  {
    float4 bb = *(const float4*)&bout[cx*4];
    float bv[4] = {bb.x,bb.y,bb.z,bb.w};
    #pragma unroll
    for(int i=0;i<4;i++)
      #pragma unroll
      for(int j=0;j<4;j++)
        sOT[cx*4+j][ry*4+i] = fmaxf(acc[i][j] + bv[j], 0.f);
  }
  __syncthreads();
  float acc2[4][4] = {};
  #pragma unroll 8
  for(int kk = 0; kk < 64; ++kk){
    float4 a4 = *(const float4*)&sOT[kk][ry*4];
    float4 b4 = *(const float4*)&sF [kk][cx*4];
    float a[4] = {a4.x,a4.y,a4.z,a4.w};
    float b[4] = {b4.x,b4.y,b4.z,b4.w};
    #pragma unroll
    for(int i=0;i<4;i++)
      #pragma unroll
      for(int j=0;j<4;j++) acc2[i][j] += a[i]*b[j];
  }
  {
    float4 bb = *(const float4*)&bfc[cx*4];
    #pragma unroll
    for(int i=0;i<4;i++){
      int gr = row0 + ry*4 + i;
      if(gr < n){
        float4 o = make_float4(acc2[i][0]+bb.x, acc2[i][1]+bb.y,
                               acc2[i][2]+bb.z, acc2[i][3]+bb.w);
        *(float4*)&hfc[(size_t)gr*64 + cx*4] = o;
      }
    }
  }
}

// ---------------- BN stats (two-stage, deterministic)
__global__ __launch_bounds__(256) void bn_stats(const float* __restrict__ hfc,
    float* __restrict__ psum, float* __restrict__ psum2, int n){
  int t = threadIdx.x; int c = t & 63; int g = t >> 6;
  int rpb = (n + gridDim.x - 1) / gridDim.x;
  int r0 = blockIdx.x * rpb;
  int r1 = min(n, r0 + rpb);
  float s = 0.f, s2 = 0.f;
  for(int r = r0 + g; r < r1; r += 4){
    float v = hfc[(size_t)r*64 + c];
    s += v; s2 += v*v;
  }
  __shared__ float ls[256], ls2[256];
  ls[t]=s; ls2[t]=s2; __syncthreads();
  if(t < 64){
    s  = ls[t]+ls[t+64]+ls[t+128]+ls[t+192];
    s2 = ls2[t]+ls2[t+64]+ls2[t+128]+ls2[t+192];
    psum[blockIdx.x*64 + t]  = s;
    psum2[blockIdx.x*64 + t] = s2;
  }
}

__global__ __launch_bounds__(64) void bn_fin(const float* __restrict__ psum,
    const float* __restrict__ psum2, const float* __restrict__ gamma,
    const float* __restrict__ beta, float* __restrict__ scsh, int n, int nb){
  int c = threadIdx.x;
  float s=0.f, s2=0.f;
  for(int b=0;b<nb;b++){ s += psum[b*64+c]; s2 += psum2[b*64+c]; }
  float mu  = s / n;
  float var = s2 / n - mu*mu;
  float scale = rsqrtf(var + BN_EPS) * gamma[c];
  scsh[c]    = scale;
  scsh[64+c] = beta[c] - mu*scale;
}

// ---------------- BN apply + row softmax -> p
__global__ __launch_bounds__(256) void bn_softmax(const float* __restrict__ hfc,
    const float* __restrict__ scsh, float* __restrict__ p, int n){
  int wid = (blockIdx.x*blockDim.x + threadIdx.x) >> 6;
  int lane = threadIdx.x & 63;
  if(wid >= n) return;
  float y = hfc[(size_t)wid*64 + lane]*scsh[lane] + scsh[64+lane];
  float m = wave_max(y);
  float e = expf(y - m);
  float s = wave_sum(e);
  p[(size_t)wid*64 + lane] = e / s;
}

// ---------------- loss
__global__ __launch_bounds__(256) void loss1(const float* __restrict__ p,
    const int* __restrict__ train, const int* __restrict__ label,
    float* __restrict__ part, int ntrain){
  int lane = threadIdx.x & 63; int w = threadIdx.x >> 6;
  int gw = blockIdx.x*4 + w; int nw = gridDim.x*4;
  float acc = 0.f;
  for(int t = gw; t < ntrain; t += nw){
    int node = train[t];
    float v = p[(size_t)node*64 + lane];
    float m = wave_max(v);
    float e = expf(v - m);
    float s = wave_sum(e);
    float logp = (v - m) - logf(s);
    int lab = label[node];
    if(lane == lab) acc += logp;
  }
  acc = wave_sum(acc);
  __shared__ float ls[4];
  if(lane == 0) ls[w] = acc;
  __syncthreads();
  if(threadIdx.x == 0) part[blockIdx.x] = ls[0]+ls[1]+ls[2]+ls[3];
}

__global__ void loss2(const float* __restrict__ part, float* __restrict__ out,
                      int nb, int ntrain){
  if(threadIdx.x == 0){
    float s = 0.f;
    for(int i=0;i<nb;i++) s += part[i];
    out[0] = -s / (float)ntrain;
  }
}

extern "C" void kernel_launch(void* const* d_in, const int* in_sizes, int n_in,
                              void* d_out, int out_size, void* d_ws, size_t ws_size,
                              hipStream_t stream){
  const float* feature = (const float*)d_in[0];
  const int*   label   = (const int*)d_in[1];
  const int*   train   = (const int*)d_in[2];
  const int*   src     = (const int*)d_in[3];
  const int*   dst     = (const int*)d_in[4];
  const float* W0   = (const float*)d_in[5];
  const float* al0  = (const float*)d_in[6];
  const float* ar0  = (const float*)d_in[7];
  const float* b0   = (const float*)d_in[8];
  const float* W1   = (const float*)d_in[9];
  const float* al1  = (const float*)d_in[10];
  const float* ar1  = (const float*)d_in[11];
  const float* b1   = (const float*)d_in[12];
  const float* Wout = (const float*)d_in[13];
  const float* bout = (const float*)d_in[14];
  const float* Wfc  = (const float*)d_in[15];
  const float* bfc  = (const float*)d_in[16];
  const float* gamma= (const float*)d_in[17];
  const float* beta = (const float*)d_in[18];

  const int N  = in_sizes[1];
  const int NT = in_sizes[2];
  const int E  = in_sizes[3];

  const int nbuck  = (N + (1<<NBUCK_SH) - 1) >> NBUCK_SH;
  const int ntiles = (E + CSR_TILE - 1) / CSR_TILE;

  size_t off = 0;
  auto alloc = [&](size_t bytes)->void*{
    void* pp = (char*)d_ws + off;
    off += (bytes + 255) & ~(size_t)255;
    return pp;
  };
  unsigned* featb16 = (unsigned*)alloc((size_t)N*64*4);
  unsigned* hbuf2   = (unsigned*)alloc((size_t)N*64*4);
  float* el      = (float*)alloc((size_t)N*2*4);
  float* er      = (float*)alloc((size_t)N*2*4);
  int*   rowptr  = (int*)alloc((size_t)(N+1)*4);
  int*   esrc    = (int*)alloc((size_t)E*4);
  int*   thist   = (int*)alloc((size_t)ntiles*nbuck*4);
  int*   offarr  = (int*)alloc((size_t)nbuck*ntiles*4);
  int*   btotal  = (int*)alloc((size_t)nbuck*4);
  int*   bbase   = (int*)alloc((size_t)(nbuck+1)*4);
  unsigned* Wt0  = (unsigned*)alloc((size_t)128*128*4);
  unsigned* Wt1  = (unsigned*)alloc((size_t)128*64*4);
  float* psum    = (float*)alloc((size_t)256*64*4);
  float* psum2   = (float*)alloc((size_t)256*64*4);
  float* scsh    = (float*)alloc(128*4);
  float* lpart   = (float*)alloc(256*4);
  float* hfc     = (float*)featb16;
  unsigned* tmp  = hbuf2;

  float* p_out   = (float*)d_out;
  float* loss_out= (float*)d_out + (size_t)N*64;

  const int nwaveblk = (N + 3) / 4;

  // ---- weight prep (bf16, transposed)
  wtrans<<<64, 256, 0, stream>>>(W0, Wt0, 128, 7);
  wtrans<<<32, 256, 0, stream>>>(W1, Wt1, 64, 6);

  // ---- CSR build (two-level counting sort)
  csrA<<<ntiles, 256, 0, stream>>>(dst, thist, E, nbuck, ntiles);
  csrB1<<<nbuck, 512, 0, stream>>>(thist, offarr, btotal, nbuck, ntiles);
  csrB2<<<1, 256, 0, stream>>>(btotal, bbase, nbuck, E);
  csrC<<<ntiles, 256, 0, stream>>>(src, dst, offarr, bbase, tmp, E, nbuck, ntiles);
  csrD<<<nbuck, 512, 0, stream>>>(tmp, bbase, rowptr, esrc, N, E, nbuck);

  // ---- layer 0
  gemm_mfma<1><<<(N+127)/128, 256, 0, stream>>>(feature, Wt0, featb16, N, 256);
  elr_kernel<<<nwaveblk, 256, 0, stream>>>(featb16, al0, ar0, el, er, N);
  agg_kernel<<<nwaveblk, 256, 0, stream>>>(featb16, el, er, rowptr, esrc, b0, hbuf2, N);

  // ---- layer 1
  gemm_mfma<0><<<(N+127)/128, 256, 0, stream>>>(hbuf2, Wt1, featb16, N, 128);
  elr_kernel<<<nwaveblk, 256, 0, stream>>>(featb16, al1, ar1, el, er, N);
  agg_kernel<<<nwaveblk, 256, 0, stream>>>(featb16, el, er, rowptr, esrc, b1, hbuf2, N);

  // ---- dense head
  head_kernel<<<(N+63)/64, 256, 0, stream>>>(hbuf2, Wout, bout, Wfc, bfc, hfc, N);

  // ---- batchnorm
  bn_stats<<<256, 256, 0, stream>>>(hfc, psum, psum2, N);
  bn_fin<<<1, 64, 0, stream>>>(psum, psum2, gamma, beta, scsh, N, 256);
  bn_softmax<<<nwaveblk, 256, 0, stream>>>(hfc, scsh, p_out, N);

  // ---- loss
  loss1<<<40, 256, 0, stream>>>(p_out, train, label, lpart, NT);
  loss2<<<1, 64, 0, stream>>>(lpart, loss_out, 40, NT);
}

// Round 8
// 460.837 us; speedup vs baseline: 2.8217x; 1.0856x over previous
//
#include <hip/hip_runtime.h>

#define SLOPE 0.2f
#define BN_EPS 1e-5f

#define CSR_TILE 4096       // edges per tile (phase A/C)
#define NBUCK_SH 9          // bucket = dst >> 9  (512 nodes per bucket)

typedef __attribute__((ext_vector_type(8))) short bf16x8;
typedef __attribute__((ext_vector_type(4))) float f32x4;

__device__ __forceinline__ float wave_sum(float v){
  #pragma unroll
  for(int o=32;o;o>>=1) v += __shfl_xor(v,o);
  return v;
}
__device__ __forceinline__ float wave_max(float v){
  #pragma unroll
  for(int o=32;o;o>>=1) v = fmaxf(v,__shfl_xor(v,o));
  return v;
}
__device__ __forceinline__ unsigned pack_bf16(float a, float b){
  unsigned ua=__float_as_uint(a), ub=__float_as_uint(b);
  ua += 0x7fffu + ((ua>>16)&1u);
  ub += 0x7fffu + ((ub>>16)&1u);
  return (ua>>16) | (ub & 0xffff0000u);
}
__device__ __forceinline__ float bf_lo(unsigned u){ return __uint_as_float(u<<16); }
__device__ __forceinline__ float bf_hi(unsigned u){ return __uint_as_float(u & 0xffff0000u); }

// ---------------- both weight transposes in one launch
__global__ __launch_bounds__(256) void wtrans2(const float* __restrict__ W0,
    const float* __restrict__ W1, unsigned* __restrict__ Wt0, unsigned* __restrict__ Wt1){
  int idx = blockIdx.x*256 + threadIdx.x;
  if(blockIdx.x < 64){
    int c = idx >> 7, kp = idx & 127;          // W0: K=256 -> 128 kpairs
    Wt0[(size_t)c*128 + kp] = pack_bf16(W0[(size_t)(2*kp)*128 + c], W0[(size_t)(2*kp+1)*128 + c]);
  } else {
    int i2 = idx - 64*256;
    int c = i2 >> 6, kp = i2 & 63;             // W1: K=128 -> 64 kpairs
    Wt1[(size_t)c*64 + kp] = pack_bf16(W1[(size_t)(2*kp)*128 + c], W1[(size_t)(2*kp+1)*128 + c]);
  }
}

// ---------------- MFMA GEMM: A[n,K] @ W[K,128] -> bf16-packed out[n][64 uints]
// Fused epilogue: el[n][2], er[n][2] attention terms (from f32 accumulators).
template<int AF32>
__global__ __launch_bounds__(256) void gemm_mfma(const void* __restrict__ Aptr,
    const unsigned* __restrict__ Wt, unsigned* __restrict__ outb,
    const float* __restrict__ al, const float* __restrict__ ar,
    float* __restrict__ el, float* __restrict__ er, int n, int K){
  __shared__ unsigned sA[128][36];   // [row][kpair], 16B pad per row
  __shared__ unsigned sB[128][36];   // [col][kpair]
  int t = threadIdx.x;
  int w = t >> 6, l = t & 63;
  int wr = (w >> 1) * 64, wc = (w & 1) * 64;
  int row0 = blockIdx.x * 128;
  int K2 = K >> 1;

  f32x4 zero4 = {0.f,0.f,0.f,0.f};
  f32x4 acc[4][4];
  #pragma unroll
  for(int i=0;i<4;i++)
    #pragma unroll
    for(int j=0;j<4;j++) acc[i][j] = zero4;

  int sr = t >> 1;
  int uh = (t & 1) * 16;

  int ktiles = K >> 6;
  for(int kt = 0; kt < ktiles; ++kt){
    if(AF32){
      const float* A = (const float*)Aptr;
      int gr = row0 + sr;
      const float* ap = A + (size_t)gr*K + kt*64 + uh*2;
      #pragma unroll
      for(int i=0;i<8;i++){
        float4 v = make_float4(0.f,0.f,0.f,0.f);
        if(gr < n) v = *(const float4*)(ap + i*4);
        sA[sr][uh + i*2]   = pack_bf16(v.x, v.y);
        sA[sr][uh + i*2+1] = pack_bf16(v.z, v.w);
      }
    } else {
      const unsigned* A = (const unsigned*)Aptr;
      int gr = row0 + sr;
      const unsigned* ap = A + (size_t)gr*K2 + kt*32 + uh;
      #pragma unroll
      for(int i=0;i<4;i++){
        uint4 v = make_uint4(0,0,0,0);
        if(gr < n) v = *(const uint4*)(ap + i*4);
        *(uint4*)&sA[sr][uh + i*4] = v;
      }
    }
    {
      const unsigned* wp = Wt + (size_t)sr*K2 + kt*32 + uh;
      #pragma unroll
      for(int i=0;i<4;i++)
        *(uint4*)&sB[sr][uh + i*4] = *(const uint4*)(wp + i*4);
    }
    __syncthreads();
    #pragma unroll
    for(int ks=0; ks<2; ++ks){
      int koff = ks*16 + (l>>4)*4;
      int rl = l & 15;
      bf16x8 a[4], b[4];
      #pragma unroll
      for(int f=0; f<4; f++){
        a[f] = *(const bf16x8*)&sA[wr + f*16 + rl][koff];
        b[f] = *(const bf16x8*)&sB[wc + f*16 + rl][koff];
      }
      #pragma unroll
      for(int i=0;i<4;i++)
        #pragma unroll
        for(int j=0;j<4;j++)
          acc[i][j] = __builtin_amdgcn_mfma_f32_16x16x32_bf16(a[i], b[j], acc[i][j], 0, 0, 0);
    }
    __syncthreads();
  }

  // C-write: layout col=lane&15, row=(lane>>4)*4+reg; pack col pairs via shfl
  #pragma unroll
  for(int i=0;i<4;i++){
    #pragma unroll
    for(int j=0;j<4;j++){
      #pragma unroll
      for(int g=0;g<4;g++){
        float v  = acc[i][j][g];
        float vp = __shfl_xor(v, 1);
        if(!(l & 1)){
          unsigned pv = pack_bf16(v, vp);
          int grow = row0 + wr + i*16 + (l>>4)*4 + g;
          int gcol = wc + j*16 + (l&15);
          if(grow < n) outb[(size_t)grow*64 + (gcol>>1)] = pv;
        }
      }
    }
  }

  // fused el/er: this wave covers cols wc..wc+63 = head h entirely
  {
    int h = wc >> 6;
    float alv[4], arv[4];
    #pragma unroll
    for(int j=0;j<4;j++){
      int c = wc + j*16 + (l&15);
      alv[j] = al[c]; arv[j] = ar[c];
    }
    #pragma unroll
    for(int i=0;i<4;i++){
      #pragma unroll
      for(int g=0;g<4;g++){
        float pe = acc[i][0][g]*alv[0] + acc[i][1][g]*alv[1]
                 + acc[i][2][g]*alv[2] + acc[i][3][g]*alv[3];
        float qe = acc[i][0][g]*arv[0] + acc[i][1][g]*arv[1]
                 + acc[i][2][g]*arv[2] + acc[i][3][g]*arv[3];
        #pragma unroll
        for(int o=8;o;o>>=1){ pe += __shfl_xor(pe,o); qe += __shfl_xor(qe,o); }
        if((l & 15) == 0){
          int grow = row0 + wr + i*16 + (l>>4)*4 + g;
          if(grow < n){
            el[(size_t)grow*2 + h] = pe;
            er[(size_t)grow*2 + h] = qe;
          }
        }
      }
    }
  }
}

// ================= CSR build: two-level counting sort =================
__global__ __launch_bounds__(256) void csrA(const int* __restrict__ dst,
    int* __restrict__ thist, int E, int nbuck, int ntiles){
  __shared__ int h[512];
  int t = threadIdx.x;
  if(t < nbuck) h[t] = 0;
  __syncthreads();
  int base = blockIdx.x * CSR_TILE;
  for(int k = 0; k < CSR_TILE/256; ++k){
    int e = base + k*256 + t;
    if(e < E) atomicAdd(&h[dst[e] >> NBUCK_SH], 1);
  }
  __syncthreads();
  if(t < nbuck) thist[blockIdx.x*nbuck + t] = h[t];
}

__global__ __launch_bounds__(512) void csrB1(const int* __restrict__ thist,
    int* __restrict__ off, int* __restrict__ btotal, int nbuck, int ntiles){
  __shared__ int ls[512];
  int t = threadIdx.x;
  int b = blockIdx.x;
  int v = (t < ntiles) ? thist[(size_t)t*nbuck + b] : 0;
  ls[t] = v; __syncthreads();
  for(int o=1;o<512;o<<=1){
    int x = (t>=o) ? ls[t-o] : 0;
    __syncthreads();
    ls[t] += x;
    __syncthreads();
  }
  if(t < ntiles) off[(size_t)b*ntiles + t] = ls[t] - v;
  if(t == 511) btotal[b] = ls[511];
}

__global__ __launch_bounds__(256) void csrB2(const int* __restrict__ btotal,
    int* __restrict__ bbase, int nbuck, int E){
  __shared__ int ls[256];
  int t = threadIdx.x;
  int v = (t < nbuck) ? btotal[t] : 0;
  ls[t] = v; __syncthreads();
  for(int o=1;o<256;o<<=1){
    int x = (t>=o) ? ls[t-o] : 0;
    __syncthreads();
    ls[t] += x;
    __syncthreads();
  }
  if(t < nbuck) bbase[t] = ls[t] - v;
  if(t == 0) bbase[nbuck] = E;
}

__global__ __launch_bounds__(256) void csrC(const int* __restrict__ src,
    const int* __restrict__ dst, const int* __restrict__ off,
    const int* __restrict__ bbase, unsigned* __restrict__ tmp,
    int E, int nbuck, int ntiles){
  __shared__ int basel[512];
  __shared__ int cnt[512];
  int t = threadIdx.x;
  int tile = blockIdx.x;
  if(t < nbuck){
    basel[t] = bbase[t] + off[(size_t)t*ntiles + tile];
    cnt[t] = 0;
  }
  __syncthreads();
  int base = tile * CSR_TILE;
  for(int k = 0; k < CSR_TILE/256; ++k){
    int e = base + k*256 + t;
    if(e < E){
      int d = dst[e];
      int s = src[e];
      int b = d >> NBUCK_SH;
      int r = atomicAdd(&cnt[b], 1);
      tmp[basel[b] + r] = (unsigned)s | ((unsigned)(d & ((1<<NBUCK_SH)-1)) << 17);
    }
  }
}

__global__ __launch_bounds__(512) void csrD(const unsigned* __restrict__ tmp,
    const int* __restrict__ bbase, int* __restrict__ rowptr,
    int* __restrict__ esrc, int N, int E, int nbuck){
  __shared__ int hist[512];
  __shared__ int ls[512];
  int t = threadIdx.x;
  int b = blockIdx.x;
  int base = bbase[b];
  int cnt  = bbase[b+1] - base;
  int n0   = b << NBUCK_SH;
  int nn   = min(512, N - n0);
  hist[t] = 0;
  __syncthreads();
  for(int i = t; i < cnt; i += 512)
    atomicAdd(&hist[tmp[base+i] >> 17], 1);
  __syncthreads();
  int v = hist[t];
  ls[t] = v; __syncthreads();
  for(int o=1;o<512;o<<=1){
    int x = (t>=o) ? ls[t-o] : 0;
    __syncthreads();
    ls[t] += x;
    __syncthreads();
  }
  int rp = ls[t] - v;
  if(t < nn) rowptr[n0 + t] = base + rp;
  if(b == nbuck-1 && t == 0) rowptr[N] = E;
  __syncthreads();
  hist[t] = rp;
  __syncthreads();
  for(int i = t; i < cnt; i += 512){
    unsigned v2 = tmp[base+i];
    int dl = v2 >> 17;
    int s  = v2 & 0x1FFFF;
    int r  = atomicAdd(&hist[dl], 1);
    esrc[base + r] = s;
  }
}

// ---- 8-deep gather/accumulate over one ≤64-edge chunk; zero-weight lanes pad the tail
__device__ __forceinline__ void agg_chunk(const unsigned* __restrict__ featb,
    int s, unsigned wp, int nval, int lane, int shamt, float& acc0, float& acc1){
  for(int e = 0; e < nval; e += 8){
    unsigned v[8]; float w[8];
    #pragma unroll
    for(int u=0;u<8;u++){
      int se       = __shfl(s,  e+u);
      unsigned wpe = __shfl(wp, e+u);
      w[u] = __uint_as_float((wpe << shamt) & 0xffff0000u);
      v[u] = featb[((unsigned)se << 6) + (unsigned)lane];
    }
    #pragma unroll
    for(int u=0;u<8;u++){
      acc0 += bf_lo(v[u]) * w[u];
      acc1 += bf_hi(v[u]) * w[u];
    }
  }
}

// ---------------- GAT aggregation: wave per dst node, bf16 gather -> bf16 out
__global__ __launch_bounds__(256) void agg_kernel(const unsigned* __restrict__ featb,
    const float* __restrict__ el, const float* __restrict__ er,
    const int* __restrict__ rowptr, const int* __restrict__ esrc,
    const float* __restrict__ bias, unsigned* __restrict__ outp, int n){
  int wid = (blockIdx.x*blockDim.x + threadIdx.x) >> 6;
  int lane = threadIdx.x & 63;
  if(wid >= n) return;
  int beg = rowptr[wid], end = rowptr[wid+1];
  int deg = end - beg;
  float2 erd = *(const float2*)&er[(size_t)wid*2];
  int shamt = (lane < 32) ? 16 : 0;
  float acc0 = 0.f, acc1 = 0.f;

  if(deg <= 64){
    int s = (lane < deg) ? esrc[beg + lane] : 0;
    float2 elv = *(const float2*)&el[(size_t)s*2];
    float e0 = elv.x + erd.x, e1 = elv.y + erd.y;
    e0 = (e0 >= 0.f) ? e0 : SLOPE*e0;
    e1 = (e1 >= 0.f) ? e1 : SLOPE*e1;
    float p0 = __expf(e0), p1 = __expf(e1);
    if(lane >= deg){ p0 = 0.f; p1 = 0.f; }
    float d0 = wave_sum(p0), d1 = wave_sum(p1);
    unsigned wp = pack_bf16(p0 / fmaxf(d0, 1e-16f), p1 / fmaxf(d1, 1e-16f));
    agg_chunk(featb, s, wp, deg, lane, shamt, acc0, acc1);
  } else {
    float d0 = 0.f, d1 = 0.f;
    for(int base = beg; base < end; base += 64){
      int idx = base + lane;
      int s = (idx < end) ? esrc[idx] : 0;
      float2 elv = *(const float2*)&el[(size_t)s*2];
      float e0 = elv.x + erd.x, e1 = elv.y + erd.y;
      e0 = (e0 >= 0.f) ? e0 : SLOPE*e0;
      e1 = (e1 >= 0.f) ? e1 : SLOPE*e1;
      float p0 = __expf(e0), p1 = __expf(e1);
      if(idx >= end){ p0 = 0.f; p1 = 0.f; }
      d0 += p0; d1 += p1;
    }
    d0 = wave_sum(d0); d1 = wave_sum(d1);
    float inv0 = 1.0f / fmaxf(d0, 1e-16f);
    float inv1 = 1.0f / fmaxf(d1, 1e-16f);
    for(int base = beg; base < end; base += 64){
      int idx = base + lane;
      int s = (idx < end) ? esrc[idx] : 0;
      float2 elv = *(const float2*)&el[(size_t)s*2];
      float e0 = elv.x + erd.x, e1 = elv.y + erd.y;
      e0 = (e0 >= 0.f) ? e0 : SLOPE*e0;
      e1 = (e1 >= 0.f) ? e1 : SLOPE*e1;
      unsigned wp = pack_bf16(__expf(e0) * inv0, __expf(e1) * inv1);
      if(idx >= end) wp = 0;
      agg_chunk(featb, s, wp, min(64, end - base), lane, shamt, acc0, acc1);
    }
  }
  float2 bb = *(const float2*)&bias[2*lane];
  outp[(size_t)wid*64 + lane] =
      pack_bf16(fmaxf(acc0 + bb.x, 0.f), fmaxf(acc1 + bb.y, 0.f));
}

// ---------------- head: relu(h@Wout+bout) @ Wfc + bfc   (h is bf16-packed)
__global__ __launch_bounds__(256) void head_kernel(const unsigned* __restrict__ h,
    const float* __restrict__ Wout, const float* __restrict__ bout,
    const float* __restrict__ Wfc, const float* __restrict__ bfc,
    float* __restrict__ hfc, int n){
  __shared__ float sAT[32][68];
  __shared__ float sWo[32][68];
  __shared__ float sOT[64][68];
  __shared__ float sF [64][68];
  int t = threadIdx.x;
  int cx = t & 15;
  int ry = t >> 4;
  int row0 = blockIdx.x * 64;

  {
    int kr = t >> 4;
    int c0 = (t & 15) * 4;
    #pragma unroll
    for(int i=0;i<4;i++)
      *(float4*)&sF[kr+i*16][c0] = *(const float4*)&Wfc[(size_t)(kr+i*16)*64 + c0];
  }

  float acc[4][4] = {};
  for(int k0 = 0; k0 < 128; k0 += 32){
    #pragma unroll
    for(int u=0;u<2;u++){
      int f4 = t*2 + u;
      int r  = f4 >> 3;
      int kc = (f4 & 7) * 4;
      int gr = row0 + r;
      uint2 v = make_uint2(0,0);
      if(gr < n) v = *(const uint2*)&h[(size_t)gr*64 + ((k0+kc)>>1)];
      sAT[kc+0][r] = bf_lo(v.x);
      sAT[kc+1][r] = bf_hi(v.x);
      sAT[kc+2][r] = bf_lo(v.y);
      sAT[kc+3][r] = bf_hi(v.y);
    }
    #pragma unroll
    for(int u=0;u<2;u++){
      int f4 = t*2 + u;
      int kr = f4 >> 4;
      int c0 = (f4 & 15) * 4;
      *(float4*)&sWo[kr][c0] = *(const float4*)&Wout[(size_t)(k0+kr)*64 + c0];
    }
    __syncthreads();
    #pragma unroll 8
    for(int kk = 0; kk < 32; ++kk){
      float4 a4 = *(const float4*)&sAT[kk][ry*4];
      float4 b4 = *(const float4*)&sWo[kk][cx*4];
      float a[4] = {a4.x,a4.y,a4.z,a4.w};
      float b[4] = {b4.x,b4.y,b4.z,b4.w};
      #pragma unroll
      for(int i=0;i<4;i++)
        #pragma unroll
        for(int j=0;j<4;j++) acc[i][j] += a[i]*b[j];
    }
    __syncthreads();
  }
  {
    float4 bb = *(const float4*)&bout[cx*4];
    float bv[4] = {bb.x,bb.y,bb.z,bb.w};
    #pragma unroll
    for(int i=0;i<4;i++)
      #pragma unroll
      for(int j=0;j<4;j++)
        sOT[cx*4+j][ry*4+i] = fmaxf(acc[i][j] + bv[j], 0.f);
  }
  __syncthreads();
  float acc2[4][4] = {};
  #pragma unroll 8
  for(int kk = 0; kk < 64; ++kk){
    float4 a4 = *(const float4*)&sOT[kk][ry*4];
    float4 b4 = *(const float4*)&sF [kk][cx*4];
    float a[4] = {a4.x,a4.y,a4.z,a4.w};
    float b[4] = {b4.x,b4.y,b4.z,b4.w};
    #pragma unroll
    for(int i=0;i<4;i++)
      #pragma unroll
      for(int j=0;j<4;j++) acc2[i][j] += a[i]*b[j];
  }
  {
    float4 bb = *(const float4*)&bfc[cx*4];
    #pragma unroll
    for(int i=0;i<4;i++){
      int gr = row0 + ry*4 + i;
      if(gr < n){
        float4 o = make_float4(acc2[i][0]+bb.x, acc2[i][1]+bb.y,
                               acc2[i][2]+bb.z, acc2[i][3]+bb.w);
        *(float4*)&hfc[(size_t)gr*64 + cx*4] = o;
      }
    }
  }
}

// ---------------- BN stats (two-stage, deterministic)
__global__ __launch_bounds__(256) void bn_stats(const float* __restrict__ hfc,
    float* __restrict__ psum, float* __restrict__ psum2, int n){
  int t = threadIdx.x; int c = t & 63; int g = t >> 6;
  int rpb = (n + gridDim.x - 1) / gridDim.x;
  int r0 = blockIdx.x * rpb;
  int r1 = min(n, r0 + rpb);
  float s = 0.f, s2 = 0.f;
  for(int r = r0 + g; r < r1; r += 4){
    float v = hfc[(size_t)r*64 + c];
    s += v; s2 += v*v;
  }
  __shared__ float ls[256], ls2[256];
  ls[t]=s; ls2[t]=s2; __syncthreads();
  if(t < 64){
    s  = ls[t]+ls[t+64]+ls[t+128]+ls[t+192];
    s2 = ls2[t]+ls2[t+64]+ls2[t+128]+ls2[t+192];
    psum[blockIdx.x*64 + t]  = s;
    psum2[blockIdx.x*64 + t] = s2;
  }
}

__global__ __launch_bounds__(64) void bn_fin(const float* __restrict__ psum,
    const float* __restrict__ psum2, const float* __restrict__ gamma,
    const float* __restrict__ beta, float* __restrict__ scsh, int n, int nb){
  int c = threadIdx.x;
  float s=0.f, s2=0.f;
  for(int b=0;b<nb;b++){ s += psum[b*64+c]; s2 += psum2[b*64+c]; }
  float mu  = s / n;
  float var = s2 / n - mu*mu;
  float scale = rsqrtf(var + BN_EPS) * gamma[c];
  scsh[c]    = scale;
  scsh[64+c] = beta[c] - mu*scale;
}

// ---------------- BN apply + row softmax -> p
__global__ __launch_bounds__(256) void bn_softmax(const float* __restrict__ hfc,
    const float* __restrict__ scsh, float* __restrict__ p, int n){
  int wid = (blockIdx.x*blockDim.x + threadIdx.x) >> 6;
  int lane = threadIdx.x & 63;
  if(wid >= n) return;
  float y = hfc[(size_t)wid*64 + lane]*scsh[lane] + scsh[64+lane];
  float m = wave_max(y);
  float e = expf(y - m);
  float s = wave_sum(e);
  p[(size_t)wid*64 + lane] = e / s;
}

// ---------------- loss
__global__ __launch_bounds__(256) void loss1(const float* __restrict__ p,
    const int* __restrict__ train, const int* __restrict__ label,
    float* __restrict__ part, int ntrain){
  int lane = threadIdx.x & 63; int w = threadIdx.x >> 6;
  int gw = blockIdx.x*4 + w; int nw = gridDim.x*4;
  float acc = 0.f;
  for(int t = gw; t < ntrain; t += nw){
    int node = train[t];
    float v = p[(size_t)node*64 + lane];
    float m = wave_max(v);
    float e = expf(v - m);
    float s = wave_sum(e);
    float logp = (v - m) - logf(s);
    int lab = label[node];
    if(lane == lab) acc += logp;
  }
  acc = wave_sum(acc);
  __shared__ float ls[4];
  if(lane == 0) ls[w] = acc;
  __syncthreads();
  if(threadIdx.x == 0) part[blockIdx.x] = ls[0]+ls[1]+ls[2]+ls[3];
}

__global__ void loss2(const float* __restrict__ part, float* __restrict__ out,
                      int nb, int ntrain){
  if(threadIdx.x == 0){
    float s = 0.f;
    for(int i=0;i<nb;i++) s += part[i];
    out[0] = -s / (float)ntrain;
  }
}

extern "C" void kernel_launch(void* const* d_in, const int* in_sizes, int n_in,
                              void* d_out, int out_size, void* d_ws, size_t ws_size,
                              hipStream_t stream){
  const float* feature = (const float*)d_in[0];
  const int*   label   = (const int*)d_in[1];
  const int*   train   = (const int*)d_in[2];
  const int*   src     = (const int*)d_in[3];
  const int*   dst     = (const int*)d_in[4];
  const float* W0   = (const float*)d_in[5];
  const float* al0  = (const float*)d_in[6];
  const float* ar0  = (const float*)d_in[7];
  const float* b0   = (const float*)d_in[8];
  const float* W1   = (const float*)d_in[9];
  const float* al1  = (const float*)d_in[10];
  const float* ar1  = (const float*)d_in[11];
  const float* b1   = (const float*)d_in[12];
  const float* Wout = (const float*)d_in[13];
  const float* bout = (const float*)d_in[14];
  const float* Wfc  = (const float*)d_in[15];
  const float* bfc  = (const float*)d_in[16];
  const float* gamma= (const float*)d_in[17];
  const float* beta = (const float*)d_in[18];

  const int N  = in_sizes[1];
  const int NT = in_sizes[2];
  const int E  = in_sizes[3];

  const int nbuck  = (N + (1<<NBUCK_SH) - 1) >> NBUCK_SH;
  const int ntiles = (E + CSR_TILE - 1) / CSR_TILE;

  size_t off = 0;
  auto alloc = [&](size_t bytes)->void*{
    void* pp = (char*)d_ws + off;
    off += (bytes + 255) & ~(size_t)255;
    return pp;
  };
  unsigned* featb16 = (unsigned*)alloc((size_t)N*64*4);
  unsigned* hbuf2   = (unsigned*)alloc((size_t)N*64*4);
  float* el      = (float*)alloc((size_t)N*2*4);
  float* er      = (float*)alloc((size_t)N*2*4);
  int*   rowptr  = (int*)alloc((size_t)(N+1)*4);
  int*   esrc    = (int*)alloc((size_t)E*4);
  int*   thist   = (int*)alloc((size_t)ntiles*nbuck*4);
  int*   offarr  = (int*)alloc((size_t)nbuck*ntiles*4);
  int*   btotal  = (int*)alloc((size_t)nbuck*4);
  int*   bbase   = (int*)alloc((size_t)(nbuck+1)*4);
  unsigned* Wt0  = (unsigned*)alloc((size_t)128*128*4);
  unsigned* Wt1  = (unsigned*)alloc((size_t)128*64*4);
  float* psum    = (float*)alloc((size_t)256*64*4);
  float* psum2   = (float*)alloc((size_t)256*64*4);
  float* scsh    = (float*)alloc(128*4);
  float* lpart   = (float*)alloc(256*4);
  float* hfc     = (float*)featb16;
  unsigned* tmp  = hbuf2;

  float* p_out   = (float*)d_out;
  float* loss_out= (float*)d_out + (size_t)N*64;

  const int nwaveblk = (N + 3) / 4;

  // ---- weight prep (bf16, transposed) — single launch
  wtrans2<<<96, 256, 0, stream>>>(W0, W1, Wt0, Wt1);

  // ---- CSR build (two-level counting sort)
  csrA<<<ntiles, 256, 0, stream>>>(dst, thist, E, nbuck, ntiles);
  csrB1<<<nbuck, 512, 0, stream>>>(thist, offarr, btotal, nbuck, ntiles);
  csrB2<<<1, 256, 0, stream>>>(btotal, bbase, nbuck, E);
  csrC<<<ntiles, 256, 0, stream>>>(src, dst, offarr, bbase, tmp, E, nbuck, ntiles);
  csrD<<<nbuck, 512, 0, stream>>>(tmp, bbase, rowptr, esrc, N, E, nbuck);

  // ---- layer 0 (gemm fuses el/er epilogue)
  gemm_mfma<1><<<(N+127)/128, 256, 0, stream>>>(feature, Wt0, featb16, al0, ar0, el, er, N, 256);
  agg_kernel<<<nwaveblk, 256, 0, stream>>>(featb16, el, er, rowptr, esrc, b0, hbuf2, N);

  // ---- layer 1
  gemm_mfma<0><<<(N+127)/128, 256, 0, stream>>>(hbuf2, Wt1, featb16, al1, ar1, el, er, N, 128);
  agg_kernel<<<nwaveblk, 256, 0, stream>>>(featb16, el, er, rowptr, esrc, b1, hbuf2, N);

  // ---- dense head
  head_kernel<<<(N+63)/64, 256, 0, stream>>>(hbuf2, Wout, bout, Wfc, bfc, hfc, N);

  // ---- batchnorm
  bn_stats<<<256, 256, 0, stream>>>(hfc, psum, psum2, N);
  bn_fin<<<1, 64, 0, stream>>>(psum, psum2, gamma, beta, scsh, N, 256);
  bn_softmax<<<nwaveblk, 256, 0, stream>>>(hfc, scsh, p_out, N);

  // ---- loss
  loss1<<<40, 256, 0, stream>>>(p_out, train, label, lpart, NT);
  loss2<<<1, 64, 0, stream>>>(lpart, loss_out, 40, NT);
}

// Round 9
// 458.639 us; speedup vs baseline: 2.8352x; 1.0048x over previous
//
#include <hip/hip_runtime.h>

#define SLOPE 0.2f
#define BN_EPS 1e-5f

#define CSR_TILE 4096       // edges per tile (phase A/C)
#define NBUCK_SH 9          // bucket = dst >> 9  (512 nodes per bucket)

typedef __attribute__((ext_vector_type(8))) short bf16x8;
typedef __attribute__((ext_vector_type(4))) float f32x4;

__device__ __forceinline__ float wave_sum(float v){
  #pragma unroll
  for(int o=32;o;o>>=1) v += __shfl_xor(v,o);
  return v;
}
__device__ __forceinline__ float wave_max(float v){
  #pragma unroll
  for(int o=32;o;o>>=1) v = fmaxf(v,__shfl_xor(v,o));
  return v;
}
__device__ __forceinline__ unsigned pack_bf16(float a, float b){
  unsigned ua=__float_as_uint(a), ub=__float_as_uint(b);
  ua += 0x7fffu + ((ua>>16)&1u);
  ub += 0x7fffu + ((ub>>16)&1u);
  return (ua>>16) | (ub & 0xffff0000u);
}
__device__ __forceinline__ float bf_lo(unsigned u){ return __uint_as_float(u<<16); }
__device__ __forceinline__ float bf_hi(unsigned u){ return __uint_as_float(u & 0xffff0000u); }

// ---------------- both weight transposes in one launch
__global__ __launch_bounds__(256) void wtrans2(const float* __restrict__ W0,
    const float* __restrict__ W1, unsigned* __restrict__ Wt0, unsigned* __restrict__ Wt1){
  int idx = blockIdx.x*256 + threadIdx.x;
  if(blockIdx.x < 64){
    int c = idx >> 7, kp = idx & 127;          // W0: K=256 -> 128 kpairs
    Wt0[(size_t)c*128 + kp] = pack_bf16(W0[(size_t)(2*kp)*128 + c], W0[(size_t)(2*kp+1)*128 + c]);
  } else {
    int i2 = idx - 64*256;
    int c = i2 >> 6, kp = i2 & 63;             // W1: K=128 -> 64 kpairs
    Wt1[(size_t)c*64 + kp] = pack_bf16(W1[(size_t)(2*kp)*128 + c], W1[(size_t)(2*kp+1)*128 + c]);
  }
}

// ---------------- MFMA GEMM: A[n,K] @ W[K,128] -> bf16-packed out[n][64 uints]
// 64-row x 128-col tile, 4 waves (16 rows x 128 cols each), register prefetch.
// Fused epilogue: el[n][2], er[n][2].
template<int AF32>
__global__ __launch_bounds__(256) void gemm_mfma(const void* __restrict__ Aptr,
    const unsigned* __restrict__ Wt, unsigned* __restrict__ outb,
    const float* __restrict__ al, const float* __restrict__ ar,
    float* __restrict__ el, float* __restrict__ er, int n, int K){
  __shared__ unsigned sA[64][36];    // [row][kpair]
  __shared__ unsigned sB[128][36];   // [col][kpair]
  int t = threadIdx.x;
  int w = t >> 6, l = t & 63;
  int row0 = blockIdx.x * 64;
  int K2 = K >> 1;
  int ktiles = K >> 6;

  // staging coords: A = 512 uint4 (2/thread), B = 1024 uint4 (4/thread)
  int arow[2], aslot[2];
  #pragma unroll
  for(int i=0;i<2;i++){ int u4 = t*2+i; arow[i] = u4>>3; aslot[i] = u4&7; }
  int bcol[4], bslot[4];
  #pragma unroll
  for(int i=0;i<4;i++){ int u4 = t + i*256; bcol[i] = u4>>3; bslot[i] = u4&7; }

  uint4 pa[2];
  float4 paf[2][2];
  uint4 pb[4];

  auto load_tile = [&](int kt){
    if(AF32){
      const float* A = (const float*)Aptr;
      #pragma unroll
      for(int i=0;i<2;i++){
        int gr = row0 + arow[i];
        paf[i][0] = make_float4(0.f,0.f,0.f,0.f);
        paf[i][1] = make_float4(0.f,0.f,0.f,0.f);
        if(gr < n){
          const float* ap = A + (size_t)gr*K + kt*64 + aslot[i]*8;
          paf[i][0] = *(const float4*)ap;
          paf[i][1] = *(const float4*)(ap+4);
        }
      }
    } else {
      const unsigned* A = (const unsigned*)Aptr;
      #pragma unroll
      for(int i=0;i<2;i++){
        int gr = row0 + arow[i];
        pa[i] = make_uint4(0,0,0,0);
        if(gr < n) pa[i] = *(const uint4*)(A + (size_t)gr*K2 + kt*32 + aslot[i]*4);
      }
    }
    #pragma unroll
    for(int i=0;i<4;i++)
      pb[i] = *(const uint4*)(Wt + (size_t)bcol[i]*K2 + kt*32 + bslot[i]*4);
  };

  auto store_tile = [&](){
    if(AF32){
      #pragma unroll
      for(int i=0;i<2;i++){
        uint4 v;
        v.x = pack_bf16(paf[i][0].x, paf[i][0].y);
        v.y = pack_bf16(paf[i][0].z, paf[i][0].w);
        v.z = pack_bf16(paf[i][1].x, paf[i][1].y);
        v.w = pack_bf16(paf[i][1].z, paf[i][1].w);
        *(uint4*)&sA[arow[i]][aslot[i]*4] = v;
      }
    } else {
      #pragma unroll
      for(int i=0;i<2;i++)
        *(uint4*)&sA[arow[i]][aslot[i]*4] = pa[i];
    }
    #pragma unroll
    for(int i=0;i<4;i++)
      *(uint4*)&sB[bcol[i]][bslot[i]*4] = pb[i];
  };

  f32x4 zero4 = {0.f,0.f,0.f,0.f};
  f32x4 acc[8];
  #pragma unroll
  for(int j=0;j<8;j++) acc[j] = zero4;

  int rl = l & 15;
  load_tile(0);
  for(int kt = 0; kt < ktiles; ++kt){
    store_tile();
    __syncthreads();
    if(kt+1 < ktiles) load_tile(kt+1);   // in flight during MFMA below
    #pragma unroll
    for(int ks=0; ks<2; ++ks){
      int koff = ks*16 + (l>>4)*4;
      bf16x8 a = *(const bf16x8*)&sA[w*16 + rl][koff];
      #pragma unroll
      for(int j=0;j<8;j++){
        bf16x8 b = *(const bf16x8*)&sB[j*16 + rl][koff];
        acc[j] = __builtin_amdgcn_mfma_f32_16x16x32_bf16(a, b, acc[j], 0, 0, 0);
      }
    }
    __syncthreads();
  }

  // C-write: layout col=lane&15, row=(lane>>4)*4+reg; pack col pairs via shfl
  #pragma unroll
  for(int j=0;j<8;j++){
    #pragma unroll
    for(int g=0;g<4;g++){
      float v  = acc[j][g];
      float vp = __shfl_xor(v, 1);
      if(!(l & 1)){
        unsigned pv = pack_bf16(v, vp);
        int grow = row0 + w*16 + (l>>4)*4 + g;
        int gcol = j*16 + (l&15);
        if(grow < n) outb[(size_t)grow*64 + (gcol>>1)] = pv;
      }
    }
  }

  // fused el/er: wave covers all 128 cols (both heads); 16-lane-group reduce
  {
    float alv[8], arv[8];
    #pragma unroll
    for(int j=0;j<8;j++){
      int c = j*16 + (l&15);
      alv[j] = al[c]; arv[j] = ar[c];
    }
    #pragma unroll
    for(int h=0;h<2;h++){
      #pragma unroll
      for(int g=0;g<4;g++){
        float pe = acc[h*4+0][g]*alv[h*4+0] + acc[h*4+1][g]*alv[h*4+1]
                 + acc[h*4+2][g]*alv[h*4+2] + acc[h*4+3][g]*alv[h*4+3];
        float qe = acc[h*4+0][g]*arv[h*4+0] + acc[h*4+1][g]*arv[h*4+1]
                 + acc[h*4+2][g]*arv[h*4+2] + acc[h*4+3][g]*arv[h*4+3];
        #pragma unroll
        for(int o=8;o;o>>=1){ pe += __shfl_xor(pe,o); qe += __shfl_xor(qe,o); }
        if((l & 15) == 0){
          int grow = row0 + w*16 + (l>>4)*4 + g;
          if(grow < n){
            el[(size_t)grow*2 + h] = pe;
            er[(size_t)grow*2 + h] = qe;
          }
        }
      }
    }
  }
}

// ================= CSR build: two-level counting sort =================
__global__ __launch_bounds__(256) void csrA(const int* __restrict__ dst,
    int* __restrict__ thist, int E, int nbuck, int ntiles){
  __shared__ int h[512];
  int t = threadIdx.x;
  if(t < nbuck) h[t] = 0;
  __syncthreads();
  int base = blockIdx.x * CSR_TILE;
  for(int k = 0; k < CSR_TILE/256; ++k){
    int e = base + k*256 + t;
    if(e < E) atomicAdd(&h[dst[e] >> NBUCK_SH], 1);
  }
  __syncthreads();
  if(t < nbuck) thist[blockIdx.x*nbuck + t] = h[t];
}

__global__ __launch_bounds__(512) void csrB1(const int* __restrict__ thist,
    int* __restrict__ off, int* __restrict__ btotal, int nbuck, int ntiles){
  __shared__ int ls[512];
  int t = threadIdx.x;
  int b = blockIdx.x;
  int v = (t < ntiles) ? thist[(size_t)t*nbuck + b] : 0;
  ls[t] = v; __syncthreads();
  for(int o=1;o<512;o<<=1){
    int x = (t>=o) ? ls[t-o] : 0;
    __syncthreads();
    ls[t] += x;
    __syncthreads();
  }
  if(t < ntiles) off[(size_t)b*ntiles + t] = ls[t] - v;
  if(t == 511) btotal[b] = ls[511];
}

__global__ __launch_bounds__(256) void csrB2(const int* __restrict__ btotal,
    int* __restrict__ bbase, int nbuck, int E){
  __shared__ int ls[256];
  int t = threadIdx.x;
  int v = (t < nbuck) ? btotal[t] : 0;
  ls[t] = v; __syncthreads();
  for(int o=1;o<256;o<<=1){
    int x = (t>=o) ? ls[t-o] : 0;
    __syncthreads();
    ls[t] += x;
    __syncthreads();
  }
  if(t < nbuck) bbase[t] = ls[t] - v;
  if(t == 0) bbase[nbuck] = E;
}

__global__ __launch_bounds__(256) void csrC(const int* __restrict__ src,
    const int* __restrict__ dst, const int* __restrict__ off,
    const int* __restrict__ bbase, unsigned* __restrict__ tmp,
    int E, int nbuck, int ntiles){
  __shared__ int basel[512];
  __shared__ int cnt[512];
  int t = threadIdx.x;
  int tile = blockIdx.x;
  if(t < nbuck){
    basel[t] = bbase[t] + off[(size_t)t*ntiles + tile];
    cnt[t] = 0;
  }
  __syncthreads();
  int base = tile * CSR_TILE;
  for(int k = 0; k < CSR_TILE/256; ++k){
    int e = base + k*256 + t;
    if(e < E){
      int d = dst[e];
      int s = src[e];
      int b = d >> NBUCK_SH;
      int r = atomicAdd(&cnt[b], 1);
      tmp[basel[b] + r] = (unsigned)s | ((unsigned)(d & ((1<<NBUCK_SH)-1)) << 17);
    }
  }
}

__global__ __launch_bounds__(512) void csrD(const unsigned* __restrict__ tmp,
    const int* __restrict__ bbase, int* __restrict__ rowptr,
    int* __restrict__ esrc, int N, int E, int nbuck){
  __shared__ int hist[512];
  __shared__ int ls[512];
  int t = threadIdx.x;
  int b = blockIdx.x;
  int base = bbase[b];
  int cnt  = bbase[b+1] - base;
  int n0   = b << NBUCK_SH;
  int nn   = min(512, N - n0);
  hist[t] = 0;
  __syncthreads();
  for(int i = t; i < cnt; i += 512)
    atomicAdd(&hist[tmp[base+i] >> 17], 1);
  __syncthreads();
  int v = hist[t];
  ls[t] = v; __syncthreads();
  for(int o=1;o<512;o<<=1){
    int x = (t>=o) ? ls[t-o] : 0;
    __syncthreads();
    ls[t] += x;
    __syncthreads();
  }
  int rp = ls[t] - v;
  if(t < nn) rowptr[n0 + t] = base + rp;
  if(b == nbuck-1 && t == 0) rowptr[N] = E;
  __syncthreads();
  hist[t] = rp;
  __syncthreads();
  for(int i = t; i < cnt; i += 512){
    unsigned v2 = tmp[base+i];
    int dl = v2 >> 17;
    int s  = v2 & 0x1FFFF;
    int r  = atomicAdd(&hist[dl], 1);
    esrc[base + r] = s;
  }
}

// ---- 8-deep gather/accumulate over one ≤64-edge chunk; zero-weight lanes pad the tail
__device__ __forceinline__ void agg_chunk(const unsigned* __restrict__ featb,
    int s, unsigned wp, int nval, int lane, int shamt, float& acc0, float& acc1){
  for(int e = 0; e < nval; e += 8){
    unsigned v[8]; float w[8];
    #pragma unroll
    for(int u=0;u<8;u++){
      int se       = __shfl(s,  e+u);
      unsigned wpe = __shfl(wp, e+u);
      w[u] = __uint_as_float((wpe << shamt) & 0xffff0000u);
      v[u] = featb[((unsigned)se << 6) + (unsigned)lane];
    }
    #pragma unroll
    for(int u=0;u<8;u++){
      acc0 += bf_lo(v[u]) * w[u];
      acc1 += bf_hi(v[u]) * w[u];
    }
  }
}

// ---------------- GAT aggregation: wave per dst node, bf16 gather -> bf16 out
__global__ __launch_bounds__(256) void agg_kernel(const unsigned* __restrict__ featb,
    const float* __restrict__ el, const float* __restrict__ er,
    const int* __restrict__ rowptr, const int* __restrict__ esrc,
    const float* __restrict__ bias, unsigned* __restrict__ outp, int n){
  int wid = (blockIdx.x*blockDim.x + threadIdx.x) >> 6;
  int lane = threadIdx.x & 63;
  if(wid >= n) return;
  int beg = rowptr[wid], end = rowptr[wid+1];
  int deg = end - beg;
  float2 erd = *(const float2*)&er[(size_t)wid*2];
  int shamt = (lane < 32) ? 16 : 0;
  float acc0 = 0.f, acc1 = 0.f;

  if(deg <= 64){
    int s = (lane < deg) ? esrc[beg + lane] : 0;
    float2 elv = *(const float2*)&el[(size_t)s*2];
    float e0 = elv.x + erd.x, e1 = elv.y + erd.y;
    e0 = (e0 >= 0.f) ? e0 : SLOPE*e0;
    e1 = (e1 >= 0.f) ? e1 : SLOPE*e1;
    float p0 = __expf(e0), p1 = __expf(e1);
    if(lane >= deg){ p0 = 0.f; p1 = 0.f; }
    float d0 = wave_sum(p0), d1 = wave_sum(p1);
    unsigned wp = pack_bf16(p0 / fmaxf(d0, 1e-16f), p1 / fmaxf(d1, 1e-16f));
    agg_chunk(featb, s, wp, deg, lane, shamt, acc0, acc1);
  } else {
    float d0 = 0.f, d1 = 0.f;
    for(int base = beg; base < end; base += 64){
      int idx = base + lane;
      int s = (idx < end) ? esrc[idx] : 0;
      float2 elv = *(const float2*)&el[(size_t)s*2];
      float e0 = elv.x + erd.x, e1 = elv.y + erd.y;
      e0 = (e0 >= 0.f) ? e0 : SLOPE*e0;
      e1 = (e1 >= 0.f) ? e1 : SLOPE*e1;
      float p0 = __expf(e0), p1 = __expf(e1);
      if(idx >= end){ p0 = 0.f; p1 = 0.f; }
      d0 += p0; d1 += p1;
    }
    d0 = wave_sum(d0); d1 = wave_sum(d1);
    float inv0 = 1.0f / fmaxf(d0, 1e-16f);
    float inv1 = 1.0f / fmaxf(d1, 1e-16f);
    for(int base = beg; base < end; base += 64){
      int idx = base + lane;
      int s = (idx < end) ? esrc[idx] : 0;
      float2 elv = *(const float2*)&el[(size_t)s*2];
      float e0 = elv.x + erd.x, e1 = elv.y + erd.y;
      e0 = (e0 >= 0.f) ? e0 : SLOPE*e0;
      e1 = (e1 >= 0.f) ? e1 : SLOPE*e1;
      unsigned wp = pack_bf16(__expf(e0) * inv0, __expf(e1) * inv1);
      if(idx >= end) wp = 0;
      agg_chunk(featb, s, wp, min(64, end - base), lane, shamt, acc0, acc1);
    }
  }
  float2 bb = *(const float2*)&bias[2*lane];
  outp[(size_t)wid*64 + lane] =
      pack_bf16(fmaxf(acc0 + bb.x, 0.f), fmaxf(acc1 + bb.y, 0.f));
}

// ---------------- head: relu(h@Wout+bout) @ Wfc + bfc   (h is bf16-packed)
__global__ __launch_bounds__(256) void head_kernel(const unsigned* __restrict__ h,
    const float* __restrict__ Wout, const float* __restrict__ bout,
    const float* __restrict__ Wfc, const float* __restrict__ bfc,
    float* __restrict__ hfc, int n){
  __shared__ float sAT[32][68];
  __shared__ float sWo[32][68];
  __shared__ float sOT[64][68];
  __shared__ float sF [64][68];
  int t = threadIdx.x;
  int cx = t & 15;
  int ry = t >> 4;
  int row0 = blockIdx.x * 64;

  {
    int kr = t >> 4;
    int c0 = (t & 15) * 4;
    #pragma unroll
    for(int i=0;i<4;i++)
      *(float4*)&sF[kr+i*16][c0] = *(const float4*)&Wfc[(size_t)(kr+i*16)*64 + c0];
  }

  float acc[4][4] = {};
  for(int k0 = 0; k0 < 128; k0 += 32){
    #pragma unroll
    for(int u=0;u<2;u++){
      int f4 = t*2 + u;
      int r  = f4 >> 3;
      int kc = (f4 & 7) * 4;
      int gr = row0 + r;
      uint2 v = make_uint2(0,0);
      if(gr < n) v = *(const uint2*)&h[(size_t)gr*64 + ((k0+kc)>>1)];
      sAT[kc+0][r] = bf_lo(v.x);
      sAT[kc+1][r] = bf_hi(v.x);
      sAT[kc+2][r] = bf_lo(v.y);
      sAT[kc+3][r] = bf_hi(v.y);
    }
    #pragma unroll
    for(int u=0;u<2;u++){
      int f4 = t*2 + u;
      int kr = f4 >> 4;
      int c0 = (f4 & 15) * 4;
      *(float4*)&sWo[kr][c0] = *(const float4*)&Wout[(size_t)(k0+kr)*64 + c0];
    }
    __syncthreads();
    #pragma unroll 8
    for(int kk = 0; kk < 32; ++kk){
      float4 a4 = *(const float4*)&sAT[kk][ry*4];
      float4 b4 = *(const float4*)&sWo[kk][cx*4];
      float a[4] = {a4.x,a4.y,a4.z,a4.w};
      float b[4] = {b4.x,b4.y,b4.z,b4.w};
      #pragma unroll
      for(int i=0;i<4;i++)
        #pragma unroll
        for(int j=0;j<4;j++) acc[i][j] += a[i]*b[j];
    }
    __syncthreads();
  }
  {
    float4 bb = *(const float4*)&bout[cx*4];
    float bv[4] = {bb.x,bb.y,bb.z,bb.w};
    #pragma unroll
    for(int i=0;i<4;i++)
      #pragma unroll
      for(int j=0;j<4;j++)
        sOT[cx*4+j][ry*4+i] = fmaxf(acc[i][j] + bv[j], 0.f);
  }
  __syncthreads();
  float acc2[4][4] = {};
  #pragma unroll 8
  for(int kk = 0; kk < 64; ++kk){
    float4 a4 = *(const float4*)&sOT[kk][ry*4];
    float4 b4 = *(const float4*)&sF [kk][cx*4];
    float a[4] = {a4.x,a4.y,a4.z,a4.w};
    float b[4] = {b4.x,b4.y,b4.z,b4.w};
    #pragma unroll
    for(int i=0;i<4;i++)
      #pragma unroll
      for(int j=0;j<4;j++) acc2[i][j] += a[i]*b[j];
  }
  {
    float4 bb = *(const float4*)&bfc[cx*4];
    #pragma unroll
    for(int i=0;i<4;i++){
      int gr = row0 + ry*4 + i;
      if(gr < n){
        float4 o = make_float4(acc2[i][0]+bb.x, acc2[i][1]+bb.y,
                               acc2[i][2]+bb.z, acc2[i][3]+bb.w);
        *(float4*)&hfc[(size_t)gr*64 + cx*4] = o;
      }
    }
  }
}

// ---------------- BN stats (two-stage, deterministic)
__global__ __launch_bounds__(256) void bn_stats(const float* __restrict__ hfc,
    float* __restrict__ psum, float* __restrict__ psum2, int n){
  int t = threadIdx.x; int c = t & 63; int g = t >> 6;
  int rpb = (n + gridDim.x - 1) / gridDim.x;
  int r0 = blockIdx.x * rpb;
  int r1 = min(n, r0 + rpb);
  float s = 0.f, s2 = 0.f;
  for(int r = r0 + g; r < r1; r += 4){
    float v = hfc[(size_t)r*64 + c];
    s += v; s2 += v*v;
  }
  __shared__ float ls[256], ls2[256];
  ls[t]=s; ls2[t]=s2; __syncthreads();
  if(t < 64){
    s  = ls[t]+ls[t+64]+ls[t+128]+ls[t+192];
    s2 = ls2[t]+ls2[t+64]+ls2[t+128]+ls2[t+192];
    psum[blockIdx.x*64 + t]  = s;
    psum2[blockIdx.x*64 + t] = s2;
  }
}

__global__ __launch_bounds__(64) void bn_fin(const float* __restrict__ psum,
    const float* __restrict__ psum2, const float* __restrict__ gamma,
    const float* __restrict__ beta, float* __restrict__ scsh, int n, int nb){
  int c = threadIdx.x;
  float s=0.f, s2=0.f;
  for(int b=0;b<nb;b++){ s += psum[b*64+c]; s2 += psum2[b*64+c]; }
  float mu  = s / n;
  float var = s2 / n - mu*mu;
  float scale = rsqrtf(var + BN_EPS) * gamma[c];
  scsh[c]    = scale;
  scsh[64+c] = beta[c] - mu*scale;
}

// ---------------- BN apply + row softmax -> p
__global__ __launch_bounds__(256) void bn_softmax(const float* __restrict__ hfc,
    const float* __restrict__ scsh, float* __restrict__ p, int n){
  int wid = (blockIdx.x*blockDim.x + threadIdx.x) >> 6;
  int lane = threadIdx.x & 63;
  if(wid >= n) return;
  float y = hfc[(size_t)wid*64 + lane]*scsh[lane] + scsh[64+lane];
  float m = wave_max(y);
  float e = expf(y - m);
  float s = wave_sum(e);
  p[(size_t)wid*64 + lane] = e / s;
}

// ---------------- loss
__global__ __launch_bounds__(256) void loss1(const float* __restrict__ p,
    const int* __restrict__ train, const int* __restrict__ label,
    float* __restrict__ part, int ntrain){
  int lane = threadIdx.x & 63; int w = threadIdx.x >> 6;
  int gw = blockIdx.x*4 + w; int nw = gridDim.x*4;
  float acc = 0.f;
  for(int t = gw; t < ntrain; t += nw){
    int node = train[t];
    float v = p[(size_t)node*64 + lane];
    float m = wave_max(v);
    float e = expf(v - m);
    float s = wave_sum(e);
    float logp = (v - m) - logf(s);
    int lab = label[node];
    if(lane == lab) acc += logp;
  }
  acc = wave_sum(acc);
  __shared__ float ls[4];
  if(lane == 0) ls[w] = acc;
  __syncthreads();
  if(threadIdx.x == 0) part[blockIdx.x] = ls[0]+ls[1]+ls[2]+ls[3];
}

__global__ void loss2(const float* __restrict__ part, float* __restrict__ out,
                      int nb, int ntrain){
  if(threadIdx.x == 0){
    float s = 0.f;
    for(int i=0;i<nb;i++) s += part[i];
    out[0] = -s / (float)ntrain;
  }
}

extern "C" void kernel_launch(void* const* d_in, const int* in_sizes, int n_in,
                              void* d_out, int out_size, void* d_ws, size_t ws_size,
                              hipStream_t stream){
  const float* feature = (const float*)d_in[0];
  const int*   label   = (const int*)d_in[1];
  const int*   train   = (const int*)d_in[2];
  const int*   src     = (const int*)d_in[3];
  const int*   dst     = (const int*)d_in[4];
  const float* W0   = (const float*)d_in[5];
  const float* al0  = (const float*)d_in[6];
  const float* ar0  = (const float*)d_in[7];
  const float* b0   = (const float*)d_in[8];
  const float* W1   = (const float*)d_in[9];
  const float* al1  = (const float*)d_in[10];
  const float* ar1  = (const float*)d_in[11];
  const float* b1   = (const float*)d_in[12];
  const float* Wout = (const float*)d_in[13];
  const float* bout = (const float*)d_in[14];
  const float* Wfc  = (const float*)d_in[15];
  const float* bfc  = (const float*)d_in[16];
  const float* gamma= (const float*)d_in[17];
  const float* beta = (const float*)d_in[18];

  const int N  = in_sizes[1];
  const int NT = in_sizes[2];
  const int E  = in_sizes[3];

  const int nbuck  = (N + (1<<NBUCK_SH) - 1) >> NBUCK_SH;
  const int ntiles = (E + CSR_TILE - 1) / CSR_TILE;

  size_t off = 0;
  auto alloc = [&](size_t bytes)->void*{
    void* pp = (char*)d_ws + off;
    off += (bytes + 255) & ~(size_t)255;
    return pp;
  };
  unsigned* featb16 = (unsigned*)alloc((size_t)N*64*4);
  unsigned* hbuf2   = (unsigned*)alloc((size_t)N*64*4);
  float* el      = (float*)alloc((size_t)N*2*4);
  float* er      = (float*)alloc((size_t)N*2*4);
  int*   rowptr  = (int*)alloc((size_t)(N+1)*4);
  int*   esrc    = (int*)alloc((size_t)E*4);
  int*   thist   = (int*)alloc((size_t)ntiles*nbuck*4);
  int*   offarr  = (int*)alloc((size_t)nbuck*ntiles*4);
  int*   btotal  = (int*)alloc((size_t)nbuck*4);
  int*   bbase   = (int*)alloc((size_t)(nbuck+1)*4);
  unsigned* Wt0  = (unsigned*)alloc((size_t)128*128*4);
  unsigned* Wt1  = (unsigned*)alloc((size_t)128*64*4);
  float* psum    = (float*)alloc((size_t)256*64*4);
  float* psum2   = (float*)alloc((size_t)256*64*4);
  float* scsh    = (float*)alloc(128*4);
  float* lpart   = (float*)alloc(256*4);
  float* hfc     = (float*)featb16;
  unsigned* tmp  = hbuf2;

  float* p_out   = (float*)d_out;
  float* loss_out= (float*)d_out + (size_t)N*64;

  const int nwaveblk = (N + 3) / 4;

  // ---- weight prep (bf16, transposed) — single launch
  wtrans2<<<96, 256, 0, stream>>>(W0, W1, Wt0, Wt1);

  // ---- CSR build (two-level counting sort)
  csrA<<<ntiles, 256, 0, stream>>>(dst, thist, E, nbuck, ntiles);
  csrB1<<<nbuck, 512, 0, stream>>>(thist, offarr, btotal, nbuck, ntiles);
  csrB2<<<1, 256, 0, stream>>>(btotal, bbase, nbuck, E);
  csrC<<<ntiles, 256, 0, stream>>>(src, dst, offarr, bbase, tmp, E, nbuck, ntiles);
  csrD<<<nbuck, 512, 0, stream>>>(tmp, bbase, rowptr, esrc, N, E, nbuck);

  // ---- layer 0 (gemm fuses el/er epilogue)
  gemm_mfma<1><<<(N+63)/64, 256, 0, stream>>>(feature, Wt0, featb16, al0, ar0, el, er, N, 256);
  agg_kernel<<<nwaveblk, 256, 0, stream>>>(featb16, el, er, rowptr, esrc, b0, hbuf2, N);

  // ---- layer 1
  gemm_mfma<0><<<(N+63)/64, 256, 0, stream>>>(hbuf2, Wt1, featb16, al1, ar1, el, er, N, 128);
  agg_kernel<<<nwaveblk, 256, 0, stream>>>(featb16, el, er, rowptr, esrc, b1, hbuf2, N);

  // ---- dense head
  head_kernel<<<(N+63)/64, 256, 0, stream>>>(hbuf2, Wout, bout, Wfc, bfc, hfc, N);

  // ---- batchnorm
  bn_stats<<<256, 256, 0, stream>>>(hfc, psum, psum2, N);
  bn_fin<<<1, 64, 0, stream>>>(psum, psum2, gamma, beta, scsh, N, 256);
  bn_softmax<<<nwaveblk, 256, 0, stream>>>(hfc, scsh, p_out, N);

  // ---- loss
  loss1<<<40, 256, 0, stream>>>(p_out, train, label, lpart, NT);
  loss2<<<1, 64, 0, stream>>>(lpart, loss_out, 40, NT);
}

// Round 10
// 458.318 us; speedup vs baseline: 2.8372x; 1.0007x over previous
//
#include <hip/hip_runtime.h>

#define SLOPE 0.2f
#define BN_EPS 1e-5f

#define CSR_TILE 4096       // edges per tile (phase A/C)
#define NBUCK_SH 9          // bucket = dst >> 9  (512 nodes per bucket)

typedef __attribute__((ext_vector_type(8))) short bf16x8;
typedef __attribute__((ext_vector_type(4))) float f32x4;

__device__ __forceinline__ float wave_sum(float v){
  #pragma unroll
  for(int o=32;o;o>>=1) v += __shfl_xor(v,o);
  return v;
}
__device__ __forceinline__ float wave_max(float v){
  #pragma unroll
  for(int o=32;o;o>>=1) v = fmaxf(v,__shfl_xor(v,o));
  return v;
}
__device__ __forceinline__ unsigned pack_bf16(float a, float b){
  unsigned ua=__float_as_uint(a), ub=__float_as_uint(b);
  ua += 0x7fffu + ((ua>>16)&1u);
  ub += 0x7fffu + ((ub>>16)&1u);
  return (ua>>16) | (ub & 0xffff0000u);
}
__device__ __forceinline__ float bf_lo(unsigned u){ return __uint_as_float(u<<16); }
__device__ __forceinline__ float bf_hi(unsigned u){ return __uint_as_float(u & 0xffff0000u); }

// ---------------- both weight transposes in one launch
__global__ __launch_bounds__(256) void wtrans2(const float* __restrict__ W0,
    const float* __restrict__ W1, unsigned* __restrict__ Wt0, unsigned* __restrict__ Wt1){
  int idx = blockIdx.x*256 + threadIdx.x;
  if(blockIdx.x < 64){
    int c = idx >> 7, kp = idx & 127;          // W0: K=256 -> 128 kpairs
    Wt0[(size_t)c*128 + kp] = pack_bf16(W0[(size_t)(2*kp)*128 + c], W0[(size_t)(2*kp+1)*128 + c]);
  } else {
    int i2 = idx - 64*256;
    int c = i2 >> 6, kp = i2 & 63;             // W1: K=128 -> 64 kpairs
    Wt1[(size_t)c*64 + kp] = pack_bf16(W1[(size_t)(2*kp)*128 + c], W1[(size_t)(2*kp+1)*128 + c]);
  }
}

// ---------------- MFMA GEMM: A[n,K] @ W[K,128] -> bf16-packed out[n][64 uints]
// 64-row x 128-col tile, 4 waves (16 rows x 128 cols each), register prefetch.
// Epilogue stages C + el/er through LDS -> full-line coalesced HBM writes.
template<int AF32>
__global__ __launch_bounds__(256) void gemm_mfma(const void* __restrict__ Aptr,
    const unsigned* __restrict__ Wt, unsigned* __restrict__ outb,
    const float* __restrict__ al, const float* __restrict__ ar,
    float* __restrict__ el, float* __restrict__ er, int n, int K){
  __shared__ unsigned sA[64][36];    // [row][kpair]
  __shared__ unsigned sB[128][36];   // [col][kpair]
  int t = threadIdx.x;
  int w = t >> 6, l = t & 63;
  int row0 = blockIdx.x * 64;
  int K2 = K >> 1;
  int ktiles = K >> 6;

  // staging coords: A = 512 uint4 (2/thread), B = 1024 uint4 (4/thread)
  int arow[2], aslot[2];
  #pragma unroll
  for(int i=0;i<2;i++){ int u4 = t*2+i; arow[i] = u4>>3; aslot[i] = u4&7; }
  int bcol[4], bslot[4];
  #pragma unroll
  for(int i=0;i<4;i++){ int u4 = t + i*256; bcol[i] = u4>>3; bslot[i] = u4&7; }

  uint4 pa[2];
  float4 paf[2][2];
  uint4 pb[4];

  auto load_tile = [&](int kt){
    if(AF32){
      const float* A = (const float*)Aptr;
      #pragma unroll
      for(int i=0;i<2;i++){
        int gr = row0 + arow[i];
        paf[i][0] = make_float4(0.f,0.f,0.f,0.f);
        paf[i][1] = make_float4(0.f,0.f,0.f,0.f);
        if(gr < n){
          const float* ap = A + (size_t)gr*K + kt*64 + aslot[i]*8;
          paf[i][0] = *(const float4*)ap;
          paf[i][1] = *(const float4*)(ap+4);
        }
      }
    } else {
      const unsigned* A = (const unsigned*)Aptr;
      #pragma unroll
      for(int i=0;i<2;i++){
        int gr = row0 + arow[i];
        pa[i] = make_uint4(0,0,0,0);
        if(gr < n) pa[i] = *(const uint4*)(A + (size_t)gr*K2 + kt*32 + aslot[i]*4);
      }
    }
    #pragma unroll
    for(int i=0;i<4;i++)
      pb[i] = *(const uint4*)(Wt + (size_t)bcol[i]*K2 + kt*32 + bslot[i]*4);
  };

  auto store_tile = [&](){
    if(AF32){
      #pragma unroll
      for(int i=0;i<2;i++){
        uint4 v;
        v.x = pack_bf16(paf[i][0].x, paf[i][0].y);
        v.y = pack_bf16(paf[i][0].z, paf[i][0].w);
        v.z = pack_bf16(paf[i][1].x, paf[i][1].y);
        v.w = pack_bf16(paf[i][1].z, paf[i][1].w);
        *(uint4*)&sA[arow[i]][aslot[i]*4] = v;
      }
    } else {
      #pragma unroll
      for(int i=0;i<2;i++)
        *(uint4*)&sA[arow[i]][aslot[i]*4] = pa[i];
    }
    #pragma unroll
    for(int i=0;i<4;i++)
      *(uint4*)&sB[bcol[i]][bslot[i]*4] = pb[i];
  };

  f32x4 zero4 = {0.f,0.f,0.f,0.f};
  f32x4 acc[8];
  #pragma unroll
  for(int j=0;j<8;j++) acc[j] = zero4;

  int rl = l & 15;
  load_tile(0);
  for(int kt = 0; kt < ktiles; ++kt){
    store_tile();
    __syncthreads();
    if(kt+1 < ktiles) load_tile(kt+1);   // in flight during MFMA below
    #pragma unroll
    for(int ks=0; ks<2; ++ks){
      int koff = ks*16 + (l>>4)*4;
      bf16x8 a = *(const bf16x8*)&sA[w*16 + rl][koff];
      #pragma unroll
      for(int j=0;j<8;j++){
        bf16x8 b = *(const bf16x8*)&sB[j*16 + rl][koff];
        acc[j] = __builtin_amdgcn_mfma_f32_16x16x32_bf16(a, b, acc[j], 0, 0, 0);
      }
    }
    __syncthreads();
  }

  // ---- epilogue: stage through LDS, then full-line writes ----
  unsigned (*sC)[68] = (unsigned(*)[68])&sB[0][0];   // 64x68 uints <= sB (4608)
  float* sel = (float*)&sA[0][0];                    // [64][2]
  float* ser = sel + 128;                            // [64][2]

  // el/er partials (wave covers all 128 cols = both heads), 16-lane-group reduce
  {
    float alv[8], arv[8];
    #pragma unroll
    for(int j=0;j<8;j++){
      int c = j*16 + (l&15);
      alv[j] = al[c]; arv[j] = ar[c];
    }
    #pragma unroll
    for(int h=0;h<2;h++){
      #pragma unroll
      for(int g=0;g<4;g++){
        float pe = acc[h*4+0][g]*alv[h*4+0] + acc[h*4+1][g]*alv[h*4+1]
                 + acc[h*4+2][g]*alv[h*4+2] + acc[h*4+3][g]*alv[h*4+3];
        float qe = acc[h*4+0][g]*arv[h*4+0] + acc[h*4+1][g]*arv[h*4+1]
                 + acc[h*4+2][g]*arv[h*4+2] + acc[h*4+3][g]*arv[h*4+3];
        #pragma unroll
        for(int o=8;o;o>>=1){ pe += __shfl_xor(pe,o); qe += __shfl_xor(qe,o); }
        if((l & 15) == 0){
          int r = w*16 + (l>>4)*4 + g;
          sel[r*2+h] = pe;
          ser[r*2+h] = qe;
        }
      }
    }
  }
  // pack C col-pairs via shfl, stage into sC
  #pragma unroll
  for(int j=0;j<8;j++){
    #pragma unroll
    for(int g=0;g<4;g++){
      float v  = acc[j][g];
      float vp = __shfl_xor(v, 1);
      if(!(l & 1)){
        int r = w*16 + (l>>4)*4 + g;
        sC[r][j*8 + ((l&15)>>1)] = pack_bf16(v, vp);
      }
    }
  }
  __syncthreads();
  // linear coalesced writes: C (uint4 x4/thread), el/er (float2/row)
  #pragma unroll
  for(int i=0;i<4;i++){
    int r = (t>>4) + i*16;
    int q = (t&15)*4;
    int gr = row0 + r;
    if(gr < n) *(uint4*)&outb[(size_t)gr*64 + q] = *(const uint4*)&sC[r][q];
  }
  if(t < 64){
    int gr = row0 + t;
    if(gr < n) *(float2*)&el[(size_t)gr*2] = *(const float2*)&sel[t*2];
  } else if(t < 128){
    int r = t - 64;
    int gr = row0 + r;
    if(gr < n) *(float2*)&er[(size_t)gr*2] = *(const float2*)&ser[r*2];
  }
}

// ================= CSR build: two-level counting sort =================
__global__ __launch_bounds__(256) void csrA(const int* __restrict__ dst,
    int* __restrict__ thist, int E, int nbuck, int ntiles){
  __shared__ int h[512];
  int t = threadIdx.x;
  if(t < nbuck) h[t] = 0;
  __syncthreads();
  int base = blockIdx.x * CSR_TILE;
  for(int k = 0; k < CSR_TILE/256; ++k){
    int e = base + k*256 + t;
    if(e < E) atomicAdd(&h[dst[e] >> NBUCK_SH], 1);
  }
  __syncthreads();
  if(t < nbuck) thist[blockIdx.x*nbuck + t] = h[t];
}

__global__ __launch_bounds__(512) void csrB1(const int* __restrict__ thist,
    int* __restrict__ off, int* __restrict__ btotal, int nbuck, int ntiles){
  __shared__ int ls[512];
  int t = threadIdx.x;
  int b = blockIdx.x;
  int v = (t < ntiles) ? thist[(size_t)t*nbuck + b] : 0;
  ls[t] = v; __syncthreads();
  for(int o=1;o<512;o<<=1){
    int x = (t>=o) ? ls[t-o] : 0;
    __syncthreads();
    ls[t] += x;
    __syncthreads();
  }
  if(t < ntiles) off[(size_t)b*ntiles + t] = ls[t] - v;
  if(t == 511) btotal[b] = ls[511];
}

__global__ __launch_bounds__(256) void csrB2(const int* __restrict__ btotal,
    int* __restrict__ bbase, int nbuck, int E){
  __shared__ int ls[256];
  int t = threadIdx.x;
  int v = (t < nbuck) ? btotal[t] : 0;
  ls[t] = v; __syncthreads();
  for(int o=1;o<256;o<<=1){
    int x = (t>=o) ? ls[t-o] : 0;
    __syncthreads();
    ls[t] += x;
    __syncthreads();
  }
  if(t < nbuck) bbase[t] = ls[t] - v;
  if(t == 0) bbase[nbuck] = E;
}

__global__ __launch_bounds__(256) void csrC(const int* __restrict__ src,
    const int* __restrict__ dst, const int* __restrict__ off,
    const int* __restrict__ bbase, unsigned* __restrict__ tmp,
    int E, int nbuck, int ntiles){
  __shared__ int basel[512];
  __shared__ int cnt[512];
  int t = threadIdx.x;
  int tile = blockIdx.x;
  if(t < nbuck){
    basel[t] = bbase[t] + off[(size_t)t*ntiles + tile];
    cnt[t] = 0;
  }
  __syncthreads();
  int base = tile * CSR_TILE;
  for(int k = 0; k < CSR_TILE/256; ++k){
    int e = base + k*256 + t;
    if(e < E){
      int d = dst[e];
      int s = src[e];
      int b = d >> NBUCK_SH;
      int r = atomicAdd(&cnt[b], 1);
      tmp[basel[b] + r] = (unsigned)s | ((unsigned)(d & ((1<<NBUCK_SH)-1)) << 17);
    }
  }
}

__global__ __launch_bounds__(512) void csrD(const unsigned* __restrict__ tmp,
    const int* __restrict__ bbase, int* __restrict__ rowptr,
    int* __restrict__ esrc, int N, int E, int nbuck){
  __shared__ int hist[512];
  __shared__ int ls[512];
  int t = threadIdx.x;
  int b = blockIdx.x;
  int base = bbase[b];
  int cnt  = bbase[b+1] - base;
  int n0   = b << NBUCK_SH;
  int nn   = min(512, N - n0);
  hist[t] = 0;
  __syncthreads();
  for(int i = t; i < cnt; i += 512)
    atomicAdd(&hist[tmp[base+i] >> 17], 1);
  __syncthreads();
  int v = hist[t];
  ls[t] = v; __syncthreads();
  for(int o=1;o<512;o<<=1){
    int x = (t>=o) ? ls[t-o] : 0;
    __syncthreads();
    ls[t] += x;
    __syncthreads();
  }
  int rp = ls[t] - v;
  if(t < nn) rowptr[n0 + t] = base + rp;
  if(b == nbuck-1 && t == 0) rowptr[N] = E;
  __syncthreads();
  hist[t] = rp;
  __syncthreads();
  for(int i = t; i < cnt; i += 512){
    unsigned v2 = tmp[base+i];
    int dl = v2 >> 17;
    int s  = v2 & 0x1FFFF;
    int r  = atomicAdd(&hist[dl], 1);
    esrc[base + r] = s;
  }
}

// ---- 8-deep gather/accumulate over one ≤64-edge chunk; zero-weight lanes pad the tail
__device__ __forceinline__ void agg_chunk(const unsigned* __restrict__ featb,
    int s, unsigned wp, int nval, int lane, int shamt, float& acc0, float& acc1){
  for(int e = 0; e < nval; e += 8){
    unsigned v[8]; float w[8];
    #pragma unroll
    for(int u=0;u<8;u++){
      int se       = __shfl(s,  e+u);
      unsigned wpe = __shfl(wp, e+u);
      w[u] = __uint_as_float((wpe << shamt) & 0xffff0000u);
      v[u] = featb[((unsigned)se << 6) + (unsigned)lane];
    }
    #pragma unroll
    for(int u=0;u<8;u++){
      acc0 += bf_lo(v[u]) * w[u];
      acc1 += bf_hi(v[u]) * w[u];
    }
  }
}

// ---------------- GAT aggregation: wave per dst node, bf16 gather -> bf16 out
__global__ __launch_bounds__(256) void agg_kernel(const unsigned* __restrict__ featb,
    const float* __restrict__ el, const float* __restrict__ er,
    const int* __restrict__ rowptr, const int* __restrict__ esrc,
    const float* __restrict__ bias, unsigned* __restrict__ outp, int n){
  int wid = (blockIdx.x*blockDim.x + threadIdx.x) >> 6;
  int lane = threadIdx.x & 63;
  if(wid >= n) return;
  int beg = rowptr[wid], end = rowptr[wid+1];
  int deg = end - beg;
  float2 erd = *(const float2*)&er[(size_t)wid*2];
  int shamt = (lane < 32) ? 16 : 0;
  float acc0 = 0.f, acc1 = 0.f;

  if(deg <= 64){
    int s = (lane < deg) ? esrc[beg + lane] : 0;
    float2 elv = *(const float2*)&el[(size_t)s*2];
    float e0 = elv.x + erd.x, e1 = elv.y + erd.y;
    e0 = (e0 >= 0.f) ? e0 : SLOPE*e0;
    e1 = (e1 >= 0.f) ? e1 : SLOPE*e1;
    float p0 = __expf(e0), p1 = __expf(e1);
    if(lane >= deg){ p0 = 0.f; p1 = 0.f; }
    float d0 = wave_sum(p0), d1 = wave_sum(p1);
    unsigned wp = pack_bf16(p0 / fmaxf(d0, 1e-16f), p1 / fmaxf(d1, 1e-16f));
    agg_chunk(featb, s, wp, deg, lane, shamt, acc0, acc1);
  } else {
    float d0 = 0.f, d1 = 0.f;
    for(int base = beg; base < end; base += 64){
      int idx = base + lane;
      int s = (idx < end) ? esrc[idx] : 0;
      float2 elv = *(const float2*)&el[(size_t)s*2];
      float e0 = elv.x + erd.x, e1 = elv.y + erd.y;
      e0 = (e0 >= 0.f) ? e0 : SLOPE*e0;
      e1 = (e1 >= 0.f) ? e1 : SLOPE*e1;
      float p0 = __expf(e0), p1 = __expf(e1);
      if(idx >= end){ p0 = 0.f; p1 = 0.f; }
      d0 += p0; d1 += p1;
    }
    d0 = wave_sum(d0); d1 = wave_sum(d1);
    float inv0 = 1.0f / fmaxf(d0, 1e-16f);
    float inv1 = 1.0f / fmaxf(d1, 1e-16f);
    for(int base = beg; base < end; base += 64){
      int idx = base + lane;
      int s = (idx < end) ? esrc[idx] : 0;
      float2 elv = *(const float2*)&el[(size_t)s*2];
      float e0 = elv.x + erd.x, e1 = elv.y + erd.y;
      e0 = (e0 >= 0.f) ? e0 : SLOPE*e0;
      e1 = (e1 >= 0.f) ? e1 : SLOPE*e1;
      unsigned wp = pack_bf16(__expf(e0) * inv0, __expf(e1) * inv1);
      if(idx >= end) wp = 0;
      agg_chunk(featb, s, wp, min(64, end - base), lane, shamt, acc0, acc1);
    }
  }
  float2 bb = *(const float2*)&bias[2*lane];
  outp[(size_t)wid*64 + lane] =
      pack_bf16(fmaxf(acc0 + bb.x, 0.f), fmaxf(acc1 + bb.y, 0.f));
}

// ---------------- head: relu(h@Wout+bout) @ Wfc + bfc   (h is bf16-packed)
__global__ __launch_bounds__(256) void head_kernel(const unsigned* __restrict__ h,
    const float* __restrict__ Wout, const float* __restrict__ bout,
    const float* __restrict__ Wfc, const float* __restrict__ bfc,
    float* __restrict__ hfc, int n){
  __shared__ float sAT[32][68];
  __shared__ float sWo[32][68];
  __shared__ float sOT[64][68];
  __shared__ float sF [64][68];
  int t = threadIdx.x;
  int cx = t & 15;
  int ry = t >> 4;
  int row0 = blockIdx.x * 64;

  {
    int kr = t >> 4;
    int c0 = (t & 15) * 4;
    #pragma unroll
    for(int i=0;i<4;i++)
      *(float4*)&sF[kr+i*16][c0] = *(const float4*)&Wfc[(size_t)(kr+i*16)*64 + c0];
  }

  float acc[4][4] = {};
  for(int k0 = 0; k0 < 128; k0 += 32){
    #pragma unroll
    for(int u=0;u<2;u++){
      int f4 = t*2 + u;
      int r  = f4 >> 3;
      int kc = (f4 & 7) * 4;
      int gr = row0 + r;
      uint2 v = make_uint2(0,0);
      if(gr < n) v = *(const uint2*)&h[(size_t)gr*64 + ((k0+kc)>>1)];
      sAT[kc+0][r] = bf_lo(v.x);
      sAT[kc+1][r] = bf_hi(v.x);
      sAT[kc+2][r] = bf_lo(v.y);
      sAT[kc+3][r] = bf_hi(v.y);
    }
    #pragma unroll
    for(int u=0;u<2;u++){
      int f4 = t*2 + u;
      int kr = f4 >> 4;
      int c0 = (f4 & 15) * 4;
      *(float4*)&sWo[kr][c0] = *(const float4*)&Wout[(size_t)(k0+kr)*64 + c0];
    }
    __syncthreads();
    #pragma unroll 8
    for(int kk = 0; kk < 32; ++kk){
      float4 a4 = *(const float4*)&sAT[kk][ry*4];
      float4 b4 = *(const float4*)&sWo[kk][cx*4];
      float a[4] = {a4.x,a4.y,a4.z,a4.w};
      float b[4] = {b4.x,b4.y,b4.z,b4.w};
      #pragma unroll
      for(int i=0;i<4;i++)
        #pragma unroll
        for(int j=0;j<4;j++) acc[i][j] += a[i]*b[j];
    }
    __syncthreads();
  }
  {
    float4 bb = *(const float4*)&bout[cx*4];
    float bv[4] = {bb.x,bb.y,bb.z,bb.w};
    #pragma unroll
    for(int i=0;i<4;i++)
      #pragma unroll
      for(int j=0;j<4;j++)
        sOT[cx*4+j][ry*4+i] = fmaxf(acc[i][j] + bv[j], 0.f);
  }
  __syncthreads();
  float acc2[4][4] = {};
  #pragma unroll 8
  for(int kk = 0; kk < 64; ++kk){
    float4 a4 = *(const float4*)&sOT[kk][ry*4];
    float4 b4 = *(const float4*)&sF [kk][cx*4];
    float a[4] = {a4.x,a4.y,a4.z,a4.w};
    float b[4] = {b4.x,b4.y,b4.z,b4.w};
    #pragma unroll
    for(int i=0;i<4;i++)
      #pragma unroll
      for(int j=0;j<4;j++) acc2[i][j] += a[i]*b[j];
  }
  {
    float4 bb = *(const float4*)&bfc[cx*4];
    #pragma unroll
    for(int i=0;i<4;i++){
      int gr = row0 + ry*4 + i;
      if(gr < n){
        float4 o = make_float4(acc2[i][0]+bb.x, acc2[i][1]+bb.y,
                               acc2[i][2]+bb.z, acc2[i][3]+bb.w);
        *(float4*)&hfc[(size_t)gr*64 + cx*4] = o;
      }
    }
  }
}

// ---------------- BN stats (two-stage, deterministic)
__global__ __launch_bounds__(256) void bn_stats(const float* __restrict__ hfc,
    float* __restrict__ psum, float* __restrict__ psum2, int n){
  int t = threadIdx.x; int c = t & 63; int g = t >> 6;
  int rpb = (n + gridDim.x - 1) / gridDim.x;
  int r0 = blockIdx.x * rpb;
  int r1 = min(n, r0 + rpb);
  float s = 0.f, s2 = 0.f;
  for(int r = r0 + g; r < r1; r += 4){
    float v = hfc[(size_t)r*64 + c];
    s += v; s2 += v*v;
  }
  __shared__ float ls[256], ls2[256];
  ls[t]=s; ls2[t]=s2; __syncthreads();
  if(t < 64){
    s  = ls[t]+ls[t+64]+ls[t+128]+ls[t+192];
    s2 = ls2[t]+ls2[t+64]+ls2[t+128]+ls2[t+192];
    psum[blockIdx.x*64 + t]  = s;
    psum2[blockIdx.x*64 + t] = s2;
  }
}

__global__ __launch_bounds__(64) void bn_fin(const float* __restrict__ psum,
    const float* __restrict__ psum2, const float* __restrict__ gamma,
    const float* __restrict__ beta, float* __restrict__ scsh, int n, int nb){
  int c = threadIdx.x;
  float s=0.f, s2=0.f;
  for(int b=0;b<nb;b++){ s += psum[b*64+c]; s2 += psum2[b*64+c]; }
  float mu  = s / n;
  float var = s2 / n - mu*mu;
  float scale = rsqrtf(var + BN_EPS) * gamma[c];
  scsh[c]    = scale;
  scsh[64+c] = beta[c] - mu*scale;
}

// ---------------- BN apply + row softmax -> p
__global__ __launch_bounds__(256) void bn_softmax(const float* __restrict__ hfc,
    const float* __restrict__ scsh, float* __restrict__ p, int n){
  int wid = (blockIdx.x*blockDim.x + threadIdx.x) >> 6;
  int lane = threadIdx.x & 63;
  if(wid >= n) return;
  float y = hfc[(size_t)wid*64 + lane]*scsh[lane] + scsh[64+lane];
  float m = wave_max(y);
  float e = expf(y - m);
  float s = wave_sum(e);
  p[(size_t)wid*64 + lane] = e / s;
}

// ---------------- loss
__global__ __launch_bounds__(256) void loss1(const float* __restrict__ p,
    const int* __restrict__ train, const int* __restrict__ label,
    float* __restrict__ part, int ntrain){
  int lane = threadIdx.x & 63; int w = threadIdx.x >> 6;
  int gw = blockIdx.x*4 + w; int nw = gridDim.x*4;
  float acc = 0.f;
  for(int t = gw; t < ntrain; t += nw){
    int node = train[t];
    float v = p[(size_t)node*64 + lane];
    float m = wave_max(v);
    float e = expf(v - m);
    float s = wave_sum(e);
    float logp = (v - m) - logf(s);
    int lab = label[node];
    if(lane == lab) acc += logp;
  }
  acc = wave_sum(acc);
  __shared__ float ls[4];
  if(lane == 0) ls[w] = acc;
  __syncthreads();
  if(threadIdx.x == 0) part[blockIdx.x] = ls[0]+ls[1]+ls[2]+ls[3];
}

__global__ void loss2(const float* __restrict__ part, float* __restrict__ out,
                      int nb, int ntrain){
  if(threadIdx.x == 0){
    float s = 0.f;
    for(int i=0;i<nb;i++) s += part[i];
    out[0] = -s / (float)ntrain;
  }
}

extern "C" void kernel_launch(void* const* d_in, const int* in_sizes, int n_in,
                              void* d_out, int out_size, void* d_ws, size_t ws_size,
                              hipStream_t stream){
  const float* feature = (const float*)d_in[0];
  const int*   label   = (const int*)d_in[1];
  const int*   train   = (const int*)d_in[2];
  const int*   src     = (const int*)d_in[3];
  const int*   dst     = (const int*)d_in[4];
  const float* W0   = (const float*)d_in[5];
  const float* al0  = (const float*)d_in[6];
  const float* ar0  = (const float*)d_in[7];
  const float* b0   = (const float*)d_in[8];
  const float* W1   = (const float*)d_in[9];
  const float* al1  = (const float*)d_in[10];
  const float* ar1  = (const float*)d_in[11];
  const float* b1   = (const float*)d_in[12];
  const float* Wout = (const float*)d_in[13];
  const float* bout = (const float*)d_in[14];
  const float* Wfc  = (const float*)d_in[15];
  const float* bfc  = (const float*)d_in[16];
  const float* gamma= (const float*)d_in[17];
  const float* beta = (const float*)d_in[18];

  const int N  = in_sizes[1];
  const int NT = in_sizes[2];
  const int E  = in_sizes[3];

  const int nbuck  = (N + (1<<NBUCK_SH) - 1) >> NBUCK_SH;
  const int ntiles = (E + CSR_TILE - 1) / CSR_TILE;

  size_t off = 0;
  auto alloc = [&](size_t bytes)->void*{
    void* pp = (char*)d_ws + off;
    off += (bytes + 255) & ~(size_t)255;
    return pp;
  };
  unsigned* featb16 = (unsigned*)alloc((size_t)N*64*4);
  unsigned* hbuf2   = (unsigned*)alloc((size_t)N*64*4);
  float* el      = (float*)alloc((size_t)N*2*4);
  float* er      = (float*)alloc((size_t)N*2*4);
  int*   rowptr  = (int*)alloc((size_t)(N+1)*4);
  int*   esrc    = (int*)alloc((size_t)E*4);
  int*   thist   = (int*)alloc((size_t)ntiles*nbuck*4);
  int*   offarr  = (int*)alloc((size_t)nbuck*ntiles*4);
  int*   btotal  = (int*)alloc((size_t)nbuck*4);
  int*   bbase   = (int*)alloc((size_t)(nbuck+1)*4);
  unsigned* Wt0  = (unsigned*)alloc((size_t)128*128*4);
  unsigned* Wt1  = (unsigned*)alloc((size_t)128*64*4);
  float* psum    = (float*)alloc((size_t)256*64*4);
  float* psum2   = (float*)alloc((size_t)256*64*4);
  float* scsh    = (float*)alloc(128*4);
  float* lpart   = (float*)alloc(256*4);
  float* hfc     = (float*)featb16;
  unsigned* tmp  = hbuf2;

  float* p_out   = (float*)d_out;
  float* loss_out= (float*)d_out + (size_t)N*64;

  const int nwaveblk = (N + 3) / 4;

  // ---- weight prep (bf16, transposed) — single launch
  wtrans2<<<96, 256, 0, stream>>>(W0, W1, Wt0, Wt1);

  // ---- CSR build (two-level counting sort)
  csrA<<<ntiles, 256, 0, stream>>>(dst, thist, E, nbuck, ntiles);
  csrB1<<<nbuck, 512, 0, stream>>>(thist, offarr, btotal, nbuck, ntiles);
  csrB2<<<1, 256, 0, stream>>>(btotal, bbase, nbuck, E);
  csrC<<<ntiles, 256, 0, stream>>>(src, dst, offarr, bbase, tmp, E, nbuck, ntiles);
  csrD<<<nbuck, 512, 0, stream>>>(tmp, bbase, rowptr, esrc, N, E, nbuck);

  // ---- layer 0 (gemm fuses el/er epilogue)
  gemm_mfma<1><<<(N+63)/64, 256, 0, stream>>>(feature, Wt0, featb16, al0, ar0, el, er, N, 256);
  agg_kernel<<<nwaveblk, 256, 0, stream>>>(featb16, el, er, rowptr, esrc, b0, hbuf2, N);

  // ---- layer 1
  gemm_mfma<0><<<(N+63)/64, 256, 0, stream>>>(hbuf2, Wt1, featb16, al1, ar1, el, er, N, 128);
  agg_kernel<<<nwaveblk, 256, 0, stream>>>(featb16, el, er, rowptr, esrc, b1, hbuf2, N);

  // ---- dense head
  head_kernel<<<(N+63)/64, 256, 0, stream>>>(hbuf2, Wout, bout, Wfc, bfc, hfc, N);

  // ---- batchnorm
  bn_stats<<<256, 256, 0, stream>>>(hfc, psum, psum2, N);
  bn_fin<<<1, 64, 0, stream>>>(psum, psum2, gamma, beta, scsh, N, 256);
  bn_softmax<<<nwaveblk, 256, 0, stream>>>(hfc, scsh, p_out, N);

  // ---- loss
  loss1<<<40, 256, 0, stream>>>(p_out, train, label, lpart, NT);
  loss2<<<1, 64, 0, stream>>>(lpart, loss_out, 40, NT);
}